// Round 1
// baseline (1043.194 us; speedup 1.0000x reference)
//
#include <hip/hip_runtime.h>
#include <hip/hip_bf16.h>
#include <math.h>

// ---------------- constants ----------------
#define TB 8
#define TT 64000
#define NFRAMES 251
#define NROWS (TB*NFRAMES)      // 2008
#define NBINS 513
#define NNODE 250
#define NODE_DIM 4116
#define H1DIM 512

// ---------------- small prep kernels ----------------

__global__ void k_fold(const float* __restrict__ c1w, const float* __restrict__ c1b,
                       const float* __restrict__ g1bn, const float* __restrict__ b1bn,
                       const float* __restrict__ c2w, const float* __restrict__ c2b,
                       const float* __restrict__ g2bn, const float* __restrict__ b2bn,
                       float* __restrict__ w1f, float* __restrict__ b1f,
                       float* __restrict__ w2f, float* __restrict__ b2f) {
    int idx = blockIdx.x * 256 + threadIdx.x;
    float inv = rsqrtf(1.0f + 1e-5f);
    if (idx < 9216) {
        int co = idx / 288;
        w2f[idx] = c2w[idx] * (g2bn[co] * inv);
    } else if (idx < 9216 + 288) {
        int r = idx - 9216;
        w1f[r] = c1w[r] * (g1bn[r / 9] * inv);
    } else if (idx < 9216 + 288 + 32) {
        int c = idx - 9504;
        b1f[c] = c1b[c] * (g1bn[c] * inv) + b1bn[c];
    } else if (idx < 9216 + 288 + 64) {
        int c = idx - 9536;
        b2f[c] = c2b[c] * (g2bn[c] * inv) + b2bn[c];
    }
}

// wbar[m][c] = 0.25 * sum_{d=0..3} sinc_w[c][m-d]  (m in 0..1026)
__global__ void k_wbar(const float* __restrict__ sw, float* __restrict__ wbar) {
    int idx = blockIdx.x * 256 + threadIdx.x;
    if (idx >= 1027 * 20) return;
    int m = idx / 20, c = idx % 20;
    float s = 0.f;
    #pragma unroll
    for (int d = 0; d < 4; d++) {
        int k = m - d;
        if (k >= 0 && k < 1024) s += sw[c * 1024 + k];
    }
    wbar[idx] = 0.25f * s;
}

// DFT basis: Wc[k][n]=cos(2*pi*k*n/1024), Wsin likewise
__global__ void k_basis(float* __restrict__ Wc, float* __restrict__ Wsin) {
    int idx = blockIdx.x * 256 + threadIdx.x;
    if (idx >= NBINS * 1024) return;
    int k = idx >> 10, n = idx & 1023;
    int mm = (k * n) & 1023;
    float s, c;
    sincospif((float)mm * (1.0f / 512.0f), &s, &c);
    Wc[idx] = c;
    Wsin[idx] = s;
}

// frames[m][n] = reflect-padded x
__global__ void k_frames(const float* __restrict__ x, float* __restrict__ frames) {
    int idx = blockIdx.x * 256 + threadIdx.x;
    if (idx >= NROWS * 1024) return;
    int m = idx >> 10, n = idx & 1023;
    int b = m / NFRAMES, i = m - b * NFRAMES;
    int j = i * 256 + n - 512;
    if (j < 0) j = -j;
    if (j >= TT) j = 2 * TT - 2 - j;
    frames[idx] = x[b * TT + j];
}

// sinc features -> nodes[b][u][0..19]
__global__ __launch_bounds__(64) void k_sinc(const float* __restrict__ x,
                                             const float* __restrict__ wbar,
                                             float* __restrict__ nodes) {
    int u = blockIdx.x, b = blockIdx.y;
    int c = threadIdx.x;
    if (c >= 20) return;
    const float* xb = x + b * TT;
    int base = 4 * u - 512;
    float acc = 0.f;
    for (int m = 0; m < 1027; m++) {
        int g = base + m;
        float xv = (g >= 0) ? xb[g] : 0.f;  // upper bound never exceeded for u<250
        acc = fmaf(wbar[m * 20 + c], xv, acc);
    }
    nodes[(b * NNODE + u) * NODE_DIM + c] = acc;
}

// ---------------- DFT GEMM: S0[b][k][i] = log(|rfft|+1e-9) ----------------
__global__ __launch_bounds__(256) void k_dft_gemm(const float* __restrict__ frames,
                                                  const float* __restrict__ Wc,
                                                  const float* __restrict__ Wsin,
                                                  float* __restrict__ S0) {
    __shared__ __align__(16) float As[32][36];
    __shared__ __align__(16) float Bc[32][68];
    __shared__ __align__(16) float Bs[32][68];
    int tid = threadIdx.x;
    int tx = tid & 15, ty = tid >> 4;
    int N0 = blockIdx.x * 64, M0 = blockIdx.y * 32;
    float accR[2][4] = {{0.f}}, accI[2][4] = {{0.f}};
    int ldr = tid >> 3, ldk = (tid & 7) << 2;
    for (int K0 = 0; K0 < 1024; K0 += 32) {
        {
            int m = M0 + ldr;
            float4 v = make_float4(0.f, 0.f, 0.f, 0.f);
            if (m < NROWS) v = *(const float4*)&frames[m * 1024 + K0 + ldk];
            As[ldk + 0][ldr] = v.x; As[ldk + 1][ldr] = v.y;
            As[ldk + 2][ldr] = v.z; As[ldk + 3][ldr] = v.w;
        }
        #pragma unroll
        for (int rr = 0; rr < 2; rr++) {
            int n = N0 + ldr + rr * 32;
            float4 vc = make_float4(0.f, 0.f, 0.f, 0.f);
            float4 vs = make_float4(0.f, 0.f, 0.f, 0.f);
            if (n < NBINS) {
                vc = *(const float4*)&Wc[n * 1024 + K0 + ldk];
                vs = *(const float4*)&Wsin[n * 1024 + K0 + ldk];
            }
            Bc[ldk + 0][ldr + rr * 32] = vc.x; Bc[ldk + 1][ldr + rr * 32] = vc.y;
            Bc[ldk + 2][ldr + rr * 32] = vc.z; Bc[ldk + 3][ldr + rr * 32] = vc.w;
            Bs[ldk + 0][ldr + rr * 32] = vs.x; Bs[ldk + 1][ldr + rr * 32] = vs.y;
            Bs[ldk + 2][ldr + rr * 32] = vs.z; Bs[ldk + 3][ldr + rr * 32] = vs.w;
        }
        __syncthreads();
        for (int kk = 0; kk < 32; kk++) {
            float2 a = *(const float2*)&As[kk][ty * 2];
            float4 c4 = *(const float4*)&Bc[kk][tx * 4];
            float4 s4 = *(const float4*)&Bs[kk][tx * 4];
            float av[2] = {a.x, a.y};
            float cv[4] = {c4.x, c4.y, c4.z, c4.w};
            float sv[4] = {s4.x, s4.y, s4.z, s4.w};
            #pragma unroll
            for (int mi = 0; mi < 2; mi++)
                #pragma unroll
                for (int ni = 0; ni < 4; ni++) {
                    accR[mi][ni] = fmaf(av[mi], cv[ni], accR[mi][ni]);
                    accI[mi][ni] = fmaf(av[mi], sv[ni], accI[mi][ni]);
                }
        }
        __syncthreads();
    }
    #pragma unroll
    for (int mi = 0; mi < 2; mi++) {
        int m = M0 + ty * 2 + mi;
        if (m >= NROWS) continue;
        int b = m / NFRAMES, i = m - b * NFRAMES;
        #pragma unroll
        for (int ni = 0; ni < 4; ni++) {
            int n = N0 + tx * 4 + ni;
            if (n < NBINS) {
                float re = accR[mi][ni], im = accI[mi][ni];
                S0[(b * NBINS + n) * NFRAMES + i] = logf(sqrtf(fmaf(re, re, im * im)) + 1e-9f);
            }
        }
    }
}

// ---------------- fused conv1+BN+ReLU -> conv2+BN+ReLU -> 2x2 maxpool -> nodes ----------------
__global__ __launch_bounds__(256) void k_conv_fused(const float* __restrict__ S0,
                                                    const float* __restrict__ w1f,
                                                    const float* __restrict__ b1f,
                                                    const float* __restrict__ w2f,
                                                    const float* __restrict__ b2f,
                                                    float* __restrict__ nodes) {
    __shared__ __align__(16) float s0t[20][21];
    __shared__ __align__(16) float o1[16][18][20];
    __shared__ __align__(16) float w2s[32][192];   // [c_out][ci*12 + k], k<9 valid
    __shared__ float w1s[144];
    __shared__ float b1s[16];
    __shared__ float b2s[32];
    int tid = threadIdx.x;
    int b = blockIdx.z;
    int F0 = blockIdx.y * 8;   // pooled freq base (0..248)
    int T0 = blockIdx.x * 8;   // pooled time base (0..120)

    for (int idx = tid; idx < 400; idx += 256) {
        int i = idx / 20, j = idx % 20;
        int fr = 2 * F0 - 2 + i, tc = 2 * T0 - 2 + j;
        float v = 0.f;
        if (fr >= 0 && fr < 513 && tc >= 0 && tc < 251) v = S0[(b * 513 + fr) * 251 + tc];
        s0t[i][j] = v;
    }
    if (tid < 32) b2s[tid] = b2f[tid];

    int lane = tid & 63, wv = tid >> 6;
    int fo = lane >> 3, to = lane & 7;
    float acc2[8][4];

    for (int hh = 0; hh < 2; hh++) {
        for (int idx = tid; idx < 144; idx += 256) w1s[idx] = w1f[hh * 144 + idx];
        if (tid < 16) b1s[tid] = b1f[hh * 16 + tid];
        for (int idx = tid; idx < 32 * 192; idx += 256) {
            int co = idx / 192, r = idx - co * 192;
            int ci = r / 12, k = r - ci * 12;
            w2s[co][r] = (k < 9) ? w2f[(co * 32 + hh * 16 + ci) * 9 + k] : 0.f;
        }
        __syncthreads();

        // phase B: out1 tile for 16 channels of this half
        for (int idx = tid; idx < 16 * 324; idx += 256) {
            int cl = idx / 324, rem = idx - cl * 324;
            int lr = rem / 18, lc = rem - lr * 18;
            int r1 = 2 * F0 - 1 + lr, t1 = 2 * T0 - 1 + lc;
            float v = 0.f;
            if (r1 >= 0 && r1 < 513 && t1 >= 0 && t1 < 251) {
                float a = b1s[cl];
                const float* wp = &w1s[cl * 9];
                #pragma unroll
                for (int di = 0; di < 3; di++)
                    #pragma unroll
                    for (int dj = 0; dj < 3; dj++)
                        a = fmaf(s0t[lr + di][lc + dj], wp[di * 3 + dj], a);
                v = fmaxf(a, 0.f);
            }
            o1[cl][lr][lc] = v;
        }
        __syncthreads();

        if (hh == 0) {
            #pragma unroll
            for (int co = 0; co < 8; co++) {
                float bb = b2s[wv * 8 + co];
                acc2[co][0] = bb; acc2[co][1] = bb; acc2[co][2] = bb; acc2[co][3] = bb;
            }
        }
        for (int ci = 0; ci < 16; ci++) {
            float p[4][4];
            #pragma unroll
            for (int a = 0; a < 4; a++) {
                float2 q0 = *(const float2*)&o1[ci][2 * fo + a][2 * to];
                float2 q1 = *(const float2*)&o1[ci][2 * fo + a][2 * to + 2];
                p[a][0] = q0.x; p[a][1] = q0.y; p[a][2] = q1.x; p[a][3] = q1.y;
            }
            #pragma unroll
            for (int co = 0; co < 8; co++) {
                const float4 wa = *(const float4*)&w2s[wv * 8 + co][ci * 12];
                const float4 wb = *(const float4*)&w2s[wv * 8 + co][ci * 12 + 4];
                const float w8 = w2s[wv * 8 + co][ci * 12 + 8];
                #pragma unroll
                for (int pr = 0; pr < 2; pr++)
                    #pragma unroll
                    for (int pc = 0; pc < 2; pc++) {
                        float s = acc2[co][pr * 2 + pc];
                        s = fmaf(p[pr + 0][pc + 0], wa.x, s);
                        s = fmaf(p[pr + 0][pc + 1], wa.y, s);
                        s = fmaf(p[pr + 0][pc + 2], wa.z, s);
                        s = fmaf(p[pr + 1][pc + 0], wa.w, s);
                        s = fmaf(p[pr + 1][pc + 1], wb.x, s);
                        s = fmaf(p[pr + 1][pc + 2], wb.y, s);
                        s = fmaf(p[pr + 2][pc + 0], wb.z, s);
                        s = fmaf(p[pr + 2][pc + 1], wb.w, s);
                        s = fmaf(p[pr + 2][pc + 2], w8, s);
                        acc2[co][pr * 2 + pc] = s;
                    }
            }
        }
        __syncthreads();
    }

    int t = T0 + to;
    if (t < 125) {
        int f = F0 + fo;
        #pragma unroll
        for (int co = 0; co < 8; co++) {
            int c_out = wv * 8 + co;
            float m = fmaxf(fmaxf(acc2[co][0], acc2[co][1]), fmaxf(acc2[co][2], acc2[co][3]));
            m = fmaxf(m, 0.f);
            int node = 2 * t + (c_out >= 16 ? 1 : 0);
            nodes[(b * NNODE + node) * NODE_DIM + 20 + (c_out & 15) * 256 + f] = m;
        }
    }
}

// ---------------- GAT1 GEMM: h1[2000x512] = nodes[2000x4116] @ W[4116x512] ----------------
__global__ __launch_bounds__(256) void k_gat1(const float* __restrict__ A,
                                              const float* __restrict__ B,
                                              float* __restrict__ C) {
    __shared__ __align__(16) float As[32][36];
    __shared__ __align__(16) float Bsm[32][68];
    int tid = threadIdx.x, tx = tid & 15, ty = tid >> 4;
    int N0 = blockIdx.x * 64, M0 = blockIdx.y * 32;
    float acc[2][4] = {{0.f}};
    int ldr = tid >> 3, ldk = (tid & 7) << 2;
    for (int K0 = 0; K0 < NODE_DIM; K0 += 32) {
        {
            int m = M0 + ldr, k = K0 + ldk;
            float4 v = make_float4(0.f, 0.f, 0.f, 0.f);
            if (m < 2000 && k < NODE_DIM) v = *(const float4*)&A[m * NODE_DIM + k];
            As[ldk + 0][ldr] = v.x; As[ldk + 1][ldr] = v.y;
            As[ldk + 2][ldr] = v.z; As[ldk + 3][ldr] = v.w;
        }
        #pragma unroll
        for (int rr = 0; rr < 2; rr++) {
            int k = K0 + ldr;
            int n = N0 + ldk + rr * 32;
            float4 v = make_float4(0.f, 0.f, 0.f, 0.f);
            if (k < NODE_DIM) v = *(const float4*)&B[k * 512 + n];
            *(float4*)&Bsm[ldr][ldk + rr * 32] = v;
        }
        __syncthreads();
        for (int kk = 0; kk < 32; kk++) {
            float2 a = *(const float2*)&As[kk][ty * 2];
            float4 b4 = *(const float4*)&Bsm[kk][tx * 4];
            float av[2] = {a.x, a.y};
            float bv[4] = {b4.x, b4.y, b4.z, b4.w};
            #pragma unroll
            for (int mi = 0; mi < 2; mi++)
                #pragma unroll
                for (int ni = 0; ni < 4; ni++)
                    acc[mi][ni] = fmaf(av[mi], bv[ni], acc[mi][ni]);
        }
        __syncthreads();
    }
    #pragma unroll
    for (int mi = 0; mi < 2; mi++) {
        int m = M0 + ty * 2 + mi;
        if (m < 2000)
            *(float4*)&C[m * 512 + N0 + tx * 4] =
                make_float4(acc[mi][0], acc[mi][1], acc[mi][2], acc[mi][3]);
    }
}

// ---------------- GAT1 scores / max / attention ----------------
__global__ __launch_bounds__(256) void k_scores1(const float* __restrict__ h1,
                                                 const float* __restrict__ asrc,
                                                 const float* __restrict__ adst,
                                                 float* __restrict__ ssrc,
                                                 float* __restrict__ sdst) {
    int row = blockIdx.x * 4 + (threadIdx.x >> 6);
    int lane = threadIdx.x & 63;
    if (row >= 2000) return;
    for (int h = 0; h < 8; h++) {
        float v = h1[row * 512 + h * 64 + lane];
        float ps = v * asrc[h * 64 + lane];
        float pd = v * adst[h * 64 + lane];
        for (int off = 32; off > 0; off >>= 1) {
            ps += __shfl_down(ps, off);
            pd += __shfl_down(pd, off);
        }
        if (lane == 0) { ssrc[row * 8 + h] = ps; sdst[row * 8 + h] = pd; }
    }
}

__global__ __launch_bounds__(64) void k_smax1(const float* __restrict__ ssrc,
                                              float* __restrict__ smax) {
    int bh = blockIdx.x;
    int b = bh >> 3, h = bh & 7;
    int lane = threadIdx.x;
    float m = -1e30f;
    for (int n = lane; n < NNODE; n += 64) m = fmaxf(m, ssrc[(b * NNODE + n) * 8 + h]);
    for (int off = 32; off > 0; off >>= 1) m = fmaxf(m, __shfl_down(m, off));
    if (lane == 0) smax[bh] = m;
}

__global__ __launch_bounds__(64) void k_attn1(const float* __restrict__ h1,
                                              const float* __restrict__ ssrc,
                                              const float* __restrict__ sdst,
                                              const float* __restrict__ smax,
                                              const float* __restrict__ bias,
                                              float* __restrict__ g1) {
    int it = blockIdx.x, h = blockIdx.y, b = blockIdx.z;
    int f = threadIdx.x;
    __shared__ float ss[NNODE];
    for (int n = f; n < NNODE; n += 64) ss[n] = ssrc[(b * NNODE + n) * 8 + h];
    __syncthreads();
    float mxs = smax[b * 8 + h];
    int i0 = it * 4;
    float d[4], mx[4], acc[4] = {0.f, 0.f, 0.f, 0.f}, den[4] = {0.f, 0.f, 0.f, 0.f};
    #pragma unroll
    for (int ii = 0; ii < 4; ii++) {
        int i = i0 + ii;
        d[ii] = (i < NNODE) ? sdst[(b * NNODE + i) * 8 + h] : 0.f;
        float e = d[ii] + mxs;
        mx[ii] = e > 0.f ? e : 0.2f * e;
    }
    for (int j = 0; j < NNODE; j++) {
        float sj = ss[j];
        float hv = h1[(b * NNODE + j) * 512 + h * 64 + f];
        #pragma unroll
        for (int ii = 0; ii < 4; ii++) {
            float e = d[ii] + sj;
            e = e > 0.f ? e : 0.2f * e;
            float w = __expf(e - mx[ii]);
            den[ii] += w;
            acc[ii] = fmaf(w, hv, acc[ii]);
        }
    }
    float bb = bias[h * 64 + f];
    #pragma unroll
    for (int ii = 0; ii < 4; ii++) {
        int i = i0 + ii;
        if (i < NNODE)
            g1[(b * NNODE + i) * 512 + h * 64 + f] = fmaxf(acc[ii] / den[ii] + bb, 0.f);
    }
}

// ---------------- GAT2 ----------------
__global__ __launch_bounds__(256) void k_h2(const float* __restrict__ g1,
                                            const float* __restrict__ W2,
                                            const float* __restrict__ a2src,
                                            const float* __restrict__ a2dst,
                                            float* __restrict__ h2,
                                            float* __restrict__ s2src,
                                            float* __restrict__ s2dst) {
    int row = blockIdx.x * 4 + (threadIdx.x >> 6);
    if (row >= 2000) return;
    int lane = threadIdx.x & 63;
    int o = lane & 31, half = lane >> 5;
    const float* gr = &g1[row * 512 + half * 256];
    float acc = 0.f;
    for (int k = 0; k < 256; k++) acc = fmaf(gr[k], W2[(half * 256 + k) * 32 + o], acc);
    acc += __shfl_down(acc, 32);
    float ps = acc * a2src[o], pd = acc * a2dst[o];
    for (int off = 16; off > 0; off >>= 1) {
        ps += __shfl_down(ps, off, 32);
        pd += __shfl_down(pd, off, 32);
    }
    if (lane == 0) { s2src[row] = ps; s2dst[row] = pd; }
    if (lane < 32) h2[row * 32 + o] = acc;
}

__global__ __launch_bounds__(64) void k_smax2(const float* __restrict__ s2src,
                                              float* __restrict__ smax2) {
    int b = blockIdx.x, lane = threadIdx.x;
    float m = -1e30f;
    for (int n = lane; n < NNODE; n += 64) m = fmaxf(m, s2src[b * NNODE + n]);
    for (int off = 32; off > 0; off >>= 1) m = fmaxf(m, __shfl_down(m, off));
    if (lane == 0) smax2[b] = m;
}

__global__ __launch_bounds__(256) void k_attn2(const float* __restrict__ h2,
                                               const float* __restrict__ s2src,
                                               const float* __restrict__ s2dst,
                                               const float* __restrict__ smax2,
                                               const float* __restrict__ bias2,
                                               float* __restrict__ g2) {
    int it = blockIdx.x, b = blockIdx.y;
    int tid = threadIdx.x, lane = tid & 63, wv = tid >> 6;
    __shared__ float ss[NNODE];
    for (int n = tid; n < NNODE; n += 256) ss[n] = s2src[b * NNODE + n];
    __syncthreads();
    int i = it * 4 + wv;
    if (i >= NNODE) return;
    int f = lane & 31, half = lane >> 5;
    float d = s2dst[b * NNODE + i];
    float e0 = d + smax2[b];
    float mx = e0 > 0.f ? e0 : 0.2f * e0;
    float acc = 0.f, den = 0.f;
    for (int j = half; j < NNODE; j += 2) {
        float e = d + ss[j];
        e = e > 0.f ? e : 0.2f * e;
        float w = __expf(e - mx);
        den += w;
        acc = fmaf(w, h2[(b * NNODE + j) * 32 + f], acc);
    }
    acc += __shfl_down(acc, 32);
    den += __shfl_down(den, 32);
    if (lane < 32) g2[(b * NNODE + i) * 32 + f] = acc / den + bias2[f];
}

__global__ __launch_bounds__(256) void k_emb(const float* __restrict__ g2,
                                             float* __restrict__ emb,
                                             float* __restrict__ dout) {
    int b = blockIdx.x;
    int f = threadIdx.x & 31, g = threadIdx.x >> 5;
    __shared__ float red[8][32];
    float s = 0.f;
    for (int i = g; i < NNODE; i += 8) s += g2[(b * NNODE + i) * 32 + f];
    red[g][f] = s;
    __syncthreads();
    if (threadIdx.x < 32) {
        float t = 0.f;
        #pragma unroll
        for (int gg = 0; gg < 8; gg++) t += red[gg][f];
        t *= (1.0f / 250.0f);
        emb[b * 32 + f] = t;
        dout[16 + b * 32 + f] = t;
    }
}

__global__ __launch_bounds__(256) void k_fc(const float* __restrict__ emb,
                                            const float* __restrict__ fc1w,
                                            const float* __restrict__ fc1b,
                                            const float* __restrict__ bnfg,
                                            const float* __restrict__ bnfb,
                                            const float* __restrict__ fc2w,
                                            const float* __restrict__ fc2b,
                                            float* __restrict__ dout) {
    __shared__ float es[256];
    __shared__ float zs[1024];
    int tid = threadIdx.x;
    es[tid] = emb[tid];
    __syncthreads();
    float inv = rsqrtf(1.0f + 1e-5f);
    #pragma unroll
    for (int rep = 0; rep < 4; rep++) {
        int idx = tid + rep * 256;
        int b = idx >> 7, j = idx & 127;
        float a = fc1b[j];
        #pragma unroll
        for (int k = 0; k < 32; k++) a = fmaf(es[b * 32 + k], fc1w[k * 128 + j], a);
        a = a * (bnfg[j] * inv) + bnfb[j];
        zs[idx] = fmaxf(a, 0.f);
    }
    __syncthreads();
    if (tid < 16) {
        int b = tid >> 1, o = tid & 1;
        float a = fc2b[o];
        for (int k = 0; k < 128; k++) a = fmaf(zs[b * 128 + k], fc2w[k * 2 + o], a);
        dout[b * 2 + o] = a;
    }
}

// ---------------- launch ----------------
extern "C" void kernel_launch(void* const* d_in, const int* in_sizes, int n_in,
                              void* d_out, int out_size, void* d_ws, size_t ws_size,
                              hipStream_t stream) {
    (void)in_sizes; (void)n_in; (void)out_size; (void)ws_size;
    const float* x       = (const float*)d_in[0];
    const float* sinc_w  = (const float*)d_in[1];
    const float* conv1_w = (const float*)d_in[2];
    const float* conv1_b = (const float*)d_in[3];
    const float* bn1_g   = (const float*)d_in[4];
    const float* bn1_b   = (const float*)d_in[5];
    const float* conv2_w = (const float*)d_in[6];
    const float* conv2_b = (const float*)d_in[7];
    const float* bn2_g   = (const float*)d_in[8];
    const float* bn2_b   = (const float*)d_in[9];
    const float* gat1_W  = (const float*)d_in[10];
    const float* gat1_as = (const float*)d_in[11];
    const float* gat1_ad = (const float*)d_in[12];
    const float* gat1_bi = (const float*)d_in[13];
    const float* gat2_W  = (const float*)d_in[14];
    const float* gat2_as = (const float*)d_in[15];
    const float* gat2_ad = (const float*)d_in[16];
    const float* gat2_bi = (const float*)d_in[17];
    const float* fc1_w   = (const float*)d_in[18];
    const float* fc1_b   = (const float*)d_in[19];
    const float* bnf_g   = (const float*)d_in[20];
    const float* bnf_b   = (const float*)d_in[21];
    const float* fc2_w   = (const float*)d_in[22];
    const float* fc2_b   = (const float*)d_in[23];
    float* dout = (float*)d_out;

    float* ws      = (float*)d_ws;
    float* frames  = ws;                    // 2,056,192
    float* Wc      = frames + 2056192;      // 525,312
    float* Wsin    = Wc + 525312;           // 525,312
    float* S0      = Wsin + 525312;         // 1,030,104
    float* wbar    = S0 + 1030104;          // 20,540
    float* w1f     = wbar + 20540;          // 288
    float* b1f     = w1f + 288;             // 32
    float* w2f     = b1f + 32;              // 9,216
    float* b2f     = w2f + 9216;            // 32
    float* nodes   = b2f + 32;              // 8,232,000
    float* h1      = nodes + 8232000;       // 1,024,000
    float* ssrc1   = h1 + 1024000;          // 16,000
    float* sdst1   = ssrc1 + 16000;         // 16,000
    float* smax1   = sdst1 + 16000;         // 64
    float* g1      = smax1 + 64;            // 1,024,000
    float* h2      = g1 + 1024000;          // 64,000
    float* s2src   = h2 + 64000;            // 2,000
    float* s2dst   = s2src + 2000;          // 2,000
    float* smax2   = s2dst + 2000;          // 8
    float* g2      = smax2 + 8;             // 64,000
    float* embp    = g2 + 64000;            // 256

    hipLaunchKernelGGL(k_fold, dim3(38), dim3(256), 0, stream,
                       conv1_w, conv1_b, bn1_g, bn1_b, conv2_w, conv2_b, bn2_g, bn2_b,
                       w1f, b1f, w2f, b2f);
    hipLaunchKernelGGL(k_wbar, dim3((1027 * 20 + 255) / 256), dim3(256), 0, stream, sinc_w, wbar);
    hipLaunchKernelGGL(k_basis, dim3((NBINS * 1024 + 255) / 256), dim3(256), 0, stream, Wc, Wsin);
    hipLaunchKernelGGL(k_frames, dim3((NROWS * 1024 + 255) / 256), dim3(256), 0, stream, x, frames);
    hipLaunchKernelGGL(k_dft_gemm, dim3(9, 63), dim3(256), 0, stream, frames, Wc, Wsin, S0);
    hipLaunchKernelGGL(k_sinc, dim3(250, 8), dim3(64), 0, stream, x, wbar, nodes);
    hipLaunchKernelGGL(k_conv_fused, dim3(16, 32, 8), dim3(256), 0, stream,
                       S0, w1f, b1f, w2f, b2f, nodes);
    hipLaunchKernelGGL(k_gat1, dim3(8, 63), dim3(256), 0, stream, nodes, gat1_W, h1);
    hipLaunchKernelGGL(k_scores1, dim3(500), dim3(256), 0, stream, h1, gat1_as, gat1_ad, ssrc1, sdst1);
    hipLaunchKernelGGL(k_smax1, dim3(64), dim3(64), 0, stream, ssrc1, smax1);
    hipLaunchKernelGGL(k_attn1, dim3(63, 8, 8), dim3(64), 0, stream,
                       h1, ssrc1, sdst1, smax1, gat1_bi, g1);
    hipLaunchKernelGGL(k_h2, dim3(500), dim3(256), 0, stream,
                       g1, gat2_W, gat2_as, gat2_ad, h2, s2src, s2dst);
    hipLaunchKernelGGL(k_smax2, dim3(8), dim3(64), 0, stream, s2src, smax2);
    hipLaunchKernelGGL(k_attn2, dim3(63, 8), dim3(256), 0, stream,
                       h2, s2src, s2dst, smax2, gat2_bi, g2);
    hipLaunchKernelGGL(k_emb, dim3(8), dim3(256), 0, stream, g2, embp, dout);
    hipLaunchKernelGGL(k_fc, dim3(1), dim3(256), 0, stream,
                       embp, fc1_w, fc1_b, bnf_g, bnf_b, fc2_w, fc2_b, dout);
}

// Round 3
// 773.857 us; speedup vs baseline: 1.3480x; 1.3480x over previous
//
#include <hip/hip_runtime.h>
#include <hip/hip_bf16.h>
#include <math.h>

// ---------------- constants ----------------
#define TB 8
#define TT 64000
#define NFRAMES 251
#define NROWS (TB*NFRAMES)      // 2008
#define NBINS 513
#define NNODE 250
#define NODE_DIM 4116

typedef __attribute__((ext_vector_type(8))) short short8;
typedef __attribute__((ext_vector_type(4))) float floatx4;

// ---------------- small prep kernels ----------------

__global__ void k_fold(const float* __restrict__ c1w, const float* __restrict__ c1b,
                       const float* __restrict__ g1bn, const float* __restrict__ b1bn,
                       const float* __restrict__ c2w, const float* __restrict__ c2b,
                       const float* __restrict__ g2bn, const float* __restrict__ b2bn,
                       float* __restrict__ w1f, float* __restrict__ b1f,
                       float* __restrict__ w2f, float* __restrict__ b2f) {
    int idx = blockIdx.x * 256 + threadIdx.x;
    float inv = rsqrtf(1.0f + 1e-5f);
    if (idx < 9216) {
        int co = idx / 288;
        w2f[idx] = c2w[idx] * (g2bn[co] * inv);
    } else if (idx < 9216 + 288) {
        int r = idx - 9216;
        w1f[r] = c1w[r] * (g1bn[r / 9] * inv);
    } else if (idx < 9216 + 288 + 32) {
        int c = idx - 9504;
        b1f[c] = c1b[c] * (g1bn[c] * inv) + b1bn[c];
    } else if (idx < 9216 + 288 + 64) {
        int c = idx - 9536;
        b2f[c] = c2b[c] * (g2bn[c] * inv) + b2bn[c];
    }
}

// pack conv2 weights into MFMA B-fragment order, bf16.
// Bp[((s*2+ct)*64+lane)*8+j] = w2f[co=ct*16+(lane&15)][ci=(lane>>4)*8+j] tap s
__global__ void k_pack(const float* __restrict__ w2f, unsigned short* __restrict__ Bp) {
    int idx = blockIdx.x * 256 + threadIdx.x;
    if (idx >= 9216) return;
    int j = idx & 7, lane = (idx >> 3) & 63, ct = (idx >> 9) & 1, s = idx >> 10;
    int co = ct * 16 + (lane & 15);
    int ci = (lane >> 4) * 8 + j;
    __hip_bfloat16 h = __float2bfloat16(w2f[co * 288 + ci * 9 + s]);
    Bp[idx] = *(unsigned short*)&h;
}

// wbar[m][c] = 0.25 * sum_{d=0..3} sinc_w[c][m-d]  (m in 0..1026)
__global__ void k_wbar(const float* __restrict__ sw, float* __restrict__ wbar) {
    int idx = blockIdx.x * 256 + threadIdx.x;
    if (idx >= 1027 * 20) return;
    int m = idx / 20, c = idx % 20;
    float s = 0.f;
    #pragma unroll
    for (int d = 0; d < 4; d++) {
        int k = m - d;
        if (k >= 0 && k < 1024) s += sw[c * 1024 + k];
    }
    wbar[idx] = 0.25f * s;
}

// DFT basis
__global__ void k_basis(float* __restrict__ Wc, float* __restrict__ Wsin) {
    int idx = blockIdx.x * 256 + threadIdx.x;
    if (idx >= NBINS * 1024) return;
    int k = idx >> 10, n = idx & 1023;
    int mm = (k * n) & 1023;
    float s, c;
    sincospif((float)mm * (1.0f / 512.0f), &s, &c);
    Wc[idx] = c;
    Wsin[idx] = s;
}

// frames[m][n] = reflect-padded x
__global__ void k_frames(const float* __restrict__ x, float* __restrict__ frames) {
    int idx = blockIdx.x * 256 + threadIdx.x;
    if (idx >= NROWS * 1024) return;
    int m = idx >> 10, n = idx & 1023;
    int b = m / NFRAMES, i = m - b * NFRAMES;
    int j = i * 256 + n - 512;
    if (j < 0) j = -j;
    if (j >= TT) j = 2 * TT - 2 - j;
    frames[idx] = x[b * TT + j];
}

// sinc features -> nodes[b][u][0..19]
__global__ __launch_bounds__(64) void k_sinc(const float* __restrict__ x,
                                             const float* __restrict__ wbar,
                                             float* __restrict__ nodes) {
    int u = blockIdx.x, b = blockIdx.y;
    int c = threadIdx.x;
    if (c >= 20) return;
    const float* xb = x + b * TT;
    int base = 4 * u - 512;
    float acc = 0.f;
    for (int m = 0; m < 1027; m++) {
        int g = base + m;
        float xv = (g >= 0) ? xb[g] : 0.f;
        acc = fmaf(wbar[m * 20 + c], xv, acc);
    }
    nodes[(b * NNODE + u) * NODE_DIM + c] = acc;
}

// ---------------- DFT GEMM: S0[b][k][i] = log(|rfft|+1e-9) ----------------
__global__ __launch_bounds__(256) void k_dft_gemm(const float* __restrict__ frames,
                                                  const float* __restrict__ Wc,
                                                  const float* __restrict__ Wsin,
                                                  float* __restrict__ S0) {
    __shared__ __align__(16) float As[32][36];
    __shared__ __align__(16) float Bc[32][68];
    __shared__ __align__(16) float Bs[32][68];
    int tid = threadIdx.x;
    int tx = tid & 15, ty = tid >> 4;
    int N0 = blockIdx.x * 64, M0 = blockIdx.y * 32;
    float accR[2][4] = {{0.f}}, accI[2][4] = {{0.f}};
    int ldr = tid >> 3, ldk = (tid & 7) << 2;
    for (int K0 = 0; K0 < 1024; K0 += 32) {
        {
            int m = M0 + ldr;
            float4 v = make_float4(0.f, 0.f, 0.f, 0.f);
            if (m < NROWS) v = *(const float4*)&frames[m * 1024 + K0 + ldk];
            As[ldk + 0][ldr] = v.x; As[ldk + 1][ldr] = v.y;
            As[ldk + 2][ldr] = v.z; As[ldk + 3][ldr] = v.w;
        }
        #pragma unroll
        for (int rr = 0; rr < 2; rr++) {
            int n = N0 + ldr + rr * 32;
            float4 vc = make_float4(0.f, 0.f, 0.f, 0.f);
            float4 vs = make_float4(0.f, 0.f, 0.f, 0.f);
            if (n < NBINS) {
                vc = *(const float4*)&Wc[n * 1024 + K0 + ldk];
                vs = *(const float4*)&Wsin[n * 1024 + K0 + ldk];
            }
            Bc[ldk + 0][ldr + rr * 32] = vc.x; Bc[ldk + 1][ldr + rr * 32] = vc.y;
            Bc[ldk + 2][ldr + rr * 32] = vc.z; Bc[ldk + 3][ldr + rr * 32] = vc.w;
            Bs[ldk + 0][ldr + rr * 32] = vs.x; Bs[ldk + 1][ldr + rr * 32] = vs.y;
            Bs[ldk + 2][ldr + rr * 32] = vs.z; Bs[ldk + 3][ldr + rr * 32] = vs.w;
        }
        __syncthreads();
        for (int kk = 0; kk < 32; kk++) {
            float2 a = *(const float2*)&As[kk][ty * 2];
            float4 c4 = *(const float4*)&Bc[kk][tx * 4];
            float4 s4 = *(const float4*)&Bs[kk][tx * 4];
            float av[2] = {a.x, a.y};
            float cv[4] = {c4.x, c4.y, c4.z, c4.w};
            float sv[4] = {s4.x, s4.y, s4.z, s4.w};
            #pragma unroll
            for (int mi = 0; mi < 2; mi++)
                #pragma unroll
                for (int ni = 0; ni < 4; ni++) {
                    accR[mi][ni] = fmaf(av[mi], cv[ni], accR[mi][ni]);
                    accI[mi][ni] = fmaf(av[mi], sv[ni], accI[mi][ni]);
                }
        }
        __syncthreads();
    }
    #pragma unroll
    for (int mi = 0; mi < 2; mi++) {
        int m = M0 + ty * 2 + mi;
        if (m >= NROWS) continue;
        int b = m / NFRAMES, i = m - b * NFRAMES;
        #pragma unroll
        for (int ni = 0; ni < 4; ni++) {
            int n = N0 + tx * 4 + ni;
            if (n < NBINS) {
                float re = accR[mi][ni], im = accI[mi][ni];
                S0[(b * NBINS + n) * NFRAMES + i] = logf(sqrtf(fmaf(re, re, im * im)) + 1e-9f);
            }
        }
    }
}

// ---------------- fused conv1(f32 VALU) -> conv2 (bf16 MFMA implicit GEMM) -> maxpool ----------------
__global__ __launch_bounds__(256) void k_conv_mfma(const float* __restrict__ S0,
                                                   const float* __restrict__ w1f,
                                                   const float* __restrict__ b1f,
                                                   const unsigned short* __restrict__ Bp,
                                                   const float* __restrict__ b2f,
                                                   float* __restrict__ nodes) {
    __shared__ __align__(16) float s0t[20][21];
    __shared__ __align__(16) unsigned short o1bf[18 * 18 * 32];  // [lf][lt][ci]
    __shared__ __align__(16) unsigned short BpL[9216];
    __shared__ float w1s[288];
    __shared__ float b1s[32];
    __shared__ float b2s[32];
    int tid = threadIdx.x;
    int b = blockIdx.z;
    int F0 = blockIdx.y * 8;   // pooled freq base
    int T0 = blockIdx.x * 8;   // pooled time base

    for (int idx = tid; idx < 400; idx += 256) {
        int i = idx / 20, j = idx % 20;
        int fr = 2 * F0 - 2 + i, tc = 2 * T0 - 2 + j;
        float v = 0.f;
        if (fr >= 0 && fr < 513 && tc >= 0 && tc < 251) v = S0[(b * 513 + fr) * 251 + tc];
        s0t[i][j] = v;
    }
    for (int idx = tid; idx < 4608; idx += 256)
        ((unsigned int*)BpL)[idx] = ((const unsigned int*)Bp)[idx];
    for (int idx = tid; idx < 288; idx += 256) w1s[idx] = w1f[idx];
    if (tid < 32) { b1s[tid] = b1f[tid]; b2s[tid] = b2f[tid]; }
    __syncthreads();

    // conv1 + BN + ReLU -> bf16 tile (18x18x32), zero outside valid range
    for (int idx = tid; idx < 10368; idx += 256) {
        int ci = idx & 31, pos = idx >> 5;
        int lf = pos / 18, lt = pos - lf * 18;
        int r1 = 2 * F0 - 1 + lf, t1 = 2 * T0 - 1 + lt;
        float v = 0.f;
        if (r1 >= 0 && r1 < 513 && t1 >= 0 && t1 < 251) {
            float a = b1s[ci];
            const float* wp = &w1s[ci * 9];
            #pragma unroll
            for (int di = 0; di < 3; di++)
                #pragma unroll
                for (int dj = 0; dj < 3; dj++)
                    a = fmaf(s0t[lf + di][lt + dj], wp[di * 3 + dj], a);
            v = fmaxf(a, 0.f);
        }
        __hip_bfloat16 hv = __float2bfloat16(v);
        o1bf[pos * 32 + ci] = *(unsigned short*)&hv;
    }
    __syncthreads();

    int lane = tid & 63, w = tid >> 6;
    int q = lane >> 4, col = lane & 15;
    floatx4 acc[4][2];
    #pragma unroll
    for (int rt = 0; rt < 4; rt++)
        #pragma unroll
        for (int ct = 0; ct < 2; ct++)
            acc[rt][ct] = (floatx4){0.f, 0.f, 0.f, 0.f};

    #pragma unroll
    for (int s = 0; s < 9; s++) {
        const int di = s / 3, dj = s % 3;
        short8 bf0 = *(const short8*)&BpL[(s * 2 + 0) * 512 + lane * 8];
        short8 bf1 = *(const short8*)&BpL[(s * 2 + 1) * 512 + lane * 8];
        #pragma unroll
        for (int rt = 0; rt < 4; rt++) {
            int r = w * 4 + rt;
            short8 af = *(const short8*)&o1bf[(((r + di) * 18) + (col + dj)) * 32 + q * 8];
            acc[rt][0] = __builtin_amdgcn_mfma_f32_16x16x32_bf16(af, bf0, acc[rt][0], 0, 0, 0);
            acc[rt][1] = __builtin_amdgcn_mfma_f32_16x16x32_bf16(af, bf1, acc[rt][1], 0, 0, 0);
        }
    }

    // maxpool 2x2 entirely in-lane: t-pairs = adjacent regs, f-pairs = adjacent rt accs
    #pragma unroll
    for (int ct = 0; ct < 2; ct++) {
        int co = ct * 16 + col;
        float bb = b2s[co];
        #pragma unroll
        for (int fp2 = 0; fp2 < 2; fp2++) {
            #pragma unroll
            for (int tc2 = 0; tc2 < 2; tc2++) {
                float m0 = fmaxf(fmaxf(acc[2 * fp2][ct][2 * tc2], acc[2 * fp2][ct][2 * tc2 + 1]),
                                 fmaxf(acc[2 * fp2 + 1][ct][2 * tc2], acc[2 * fp2 + 1][ct][2 * tc2 + 1]));
                float v = fmaxf(m0 + bb, 0.f);
                int tp = T0 + 2 * q + tc2;
                if (tp < 125) {
                    int fg = F0 + 2 * w + fp2;
                    int node = 2 * tp + (co >= 16 ? 1 : 0);
                    nodes[(b * NNODE + node) * NODE_DIM + 20 + (co & 15) * 256 + fg] = v;
                }
            }
        }
    }
}

// ---------------- GAT1 GEMM: h1[2000x512] = nodes[2000x4116] @ W[4116x512] ----------------
__global__ __launch_bounds__(256) void k_gat1(const float* __restrict__ A,
                                              const float* __restrict__ B,
                                              float* __restrict__ C) {
    __shared__ __align__(16) float As[32][36];
    __shared__ __align__(16) float Bsm[32][68];
    int tid = threadIdx.x, tx = tid & 15, ty = tid >> 4;
    int N0 = blockIdx.x * 64, M0 = blockIdx.y * 32;
    float acc[2][4] = {{0.f}};
    int ldr = tid >> 3, ldk = (tid & 7) << 2;
    for (int K0 = 0; K0 < NODE_DIM; K0 += 32) {
        {
            int m = M0 + ldr, k = K0 + ldk;
            float4 v = make_float4(0.f, 0.f, 0.f, 0.f);
            if (m < 2000 && k < NODE_DIM) v = *(const float4*)&A[m * NODE_DIM + k];
            As[ldk + 0][ldr] = v.x; As[ldk + 1][ldr] = v.y;
            As[ldk + 2][ldr] = v.z; As[ldk + 3][ldr] = v.w;
        }
        #pragma unroll
        for (int rr = 0; rr < 2; rr++) {
            int k = K0 + ldr;
            int n = N0 + ldk + rr * 32;
            float4 v = make_float4(0.f, 0.f, 0.f, 0.f);
            if (k < NODE_DIM) v = *(const float4*)&B[k * 512 + n];
            *(float4*)&Bsm[ldr][ldk + rr * 32] = v;
        }
        __syncthreads();
        for (int kk = 0; kk < 32; kk++) {
            float2 a = *(const float2*)&As[kk][ty * 2];
            float4 b4 = *(const float4*)&Bsm[kk][tx * 4];
            float av[2] = {a.x, a.y};
            float bv[4] = {b4.x, b4.y, b4.z, b4.w};
            #pragma unroll
            for (int mi = 0; mi < 2; mi++)
                #pragma unroll
                for (int ni = 0; ni < 4; ni++)
                    acc[mi][ni] = fmaf(av[mi], bv[ni], acc[mi][ni]);
        }
        __syncthreads();
    }
    #pragma unroll
    for (int mi = 0; mi < 2; mi++) {
        int m = M0 + ty * 2 + mi;
        if (m < 2000)
            *(float4*)&C[m * 512 + N0 + tx * 4] =
                make_float4(acc[mi][0], acc[mi][1], acc[mi][2], acc[mi][3]);
    }
}

// ---------------- GAT1 scores / max / attention ----------------
__global__ __launch_bounds__(256) void k_scores1(const float* __restrict__ h1,
                                                 const float* __restrict__ asrc,
                                                 const float* __restrict__ adst,
                                                 float* __restrict__ ssrc,
                                                 float* __restrict__ sdst) {
    int row = blockIdx.x * 4 + (threadIdx.x >> 6);
    int lane = threadIdx.x & 63;
    if (row >= 2000) return;
    for (int h = 0; h < 8; h++) {
        float v = h1[row * 512 + h * 64 + lane];
        float ps = v * asrc[h * 64 + lane];
        float pd = v * adst[h * 64 + lane];
        for (int off = 32; off > 0; off >>= 1) {
            ps += __shfl_down(ps, off);
            pd += __shfl_down(pd, off);
        }
        if (lane == 0) { ssrc[row * 8 + h] = ps; sdst[row * 8 + h] = pd; }
    }
}

__global__ __launch_bounds__(64) void k_smax1(const float* __restrict__ ssrc,
                                              float* __restrict__ smax) {
    int bh = blockIdx.x;
    int b = bh >> 3, h = bh & 7;
    int lane = threadIdx.x;
    float m = -1e30f;
    for (int n = lane; n < NNODE; n += 64) m = fmaxf(m, ssrc[(b * NNODE + n) * 8 + h]);
    for (int off = 32; off > 0; off >>= 1) m = fmaxf(m, __shfl_down(m, off));
    if (lane == 0) smax[bh] = m;
}

__global__ __launch_bounds__(64) void k_attn1(const float* __restrict__ h1,
                                              const float* __restrict__ ssrc,
                                              const float* __restrict__ sdst,
                                              const float* __restrict__ smax,
                                              const float* __restrict__ bias,
                                              float* __restrict__ g1) {
    int it = blockIdx.x, h = blockIdx.y, b = blockIdx.z;
    int f = threadIdx.x;
    __shared__ float ss[NNODE];
    for (int n = f; n < NNODE; n += 64) ss[n] = ssrc[(b * NNODE + n) * 8 + h];
    __syncthreads();
    float mxs = smax[b * 8 + h];
    int i0 = it * 4;
    float d[4], mx[4], acc[4] = {0.f, 0.f, 0.f, 0.f}, den[4] = {0.f, 0.f, 0.f, 0.f};
    #pragma unroll
    for (int ii = 0; ii < 4; ii++) {
        int i = i0 + ii;
        d[ii] = (i < NNODE) ? sdst[(b * NNODE + i) * 8 + h] : 0.f;
        float e = d[ii] + mxs;
        mx[ii] = e > 0.f ? e : 0.2f * e;
    }
    for (int j = 0; j < NNODE; j++) {
        float sj = ss[j];
        float hv = h1[(b * NNODE + j) * 512 + h * 64 + f];
        #pragma unroll
        for (int ii = 0; ii < 4; ii++) {
            float e = d[ii] + sj;
            e = e > 0.f ? e : 0.2f * e;
            float w = __expf(e - mx[ii]);
            den[ii] += w;
            acc[ii] = fmaf(w, hv, acc[ii]);
        }
    }
    float bb = bias[h * 64 + f];
    #pragma unroll
    for (int ii = 0; ii < 4; ii++) {
        int i = i0 + ii;
        if (i < NNODE)
            g1[(b * NNODE + i) * 512 + h * 64 + f] = fmaxf(acc[ii] / den[ii] + bb, 0.f);
    }
}

// ---------------- GAT2 ----------------
__global__ __launch_bounds__(256) void k_h2(const float* __restrict__ g1,
                                            const float* __restrict__ W2,
                                            const float* __restrict__ a2src,
                                            const float* __restrict__ a2dst,
                                            float* __restrict__ h2,
                                            float* __restrict__ s2src,
                                            float* __restrict__ s2dst) {
    int row = blockIdx.x * 4 + (threadIdx.x >> 6);
    if (row >= 2000) return;
    int lane = threadIdx.x & 63;
    int o = lane & 31, half = lane >> 5;
    const float* gr = &g1[row * 512 + half * 256];
    float acc = 0.f;
    for (int k = 0; k < 256; k++) acc = fmaf(gr[k], W2[(half * 256 + k) * 32 + o], acc);
    acc += __shfl_down(acc, 32);
    float ps = acc * a2src[o], pd = acc * a2dst[o];
    for (int off = 16; off > 0; off >>= 1) {
        ps += __shfl_down(ps, off, 32);
        pd += __shfl_down(pd, off, 32);
    }
    if (lane == 0) { s2src[row] = ps; s2dst[row] = pd; }
    if (lane < 32) h2[row * 32 + o] = acc;
}

__global__ __launch_bounds__(64) void k_smax2(const float* __restrict__ s2src,
                                              float* __restrict__ smax2) {
    int b = blockIdx.x, lane = threadIdx.x;
    float m = -1e30f;
    for (int n = lane; n < NNODE; n += 64) m = fmaxf(m, s2src[b * NNODE + n]);
    for (int off = 32; off > 0; off >>= 1) m = fmaxf(m, __shfl_down(m, off));
    if (lane == 0) smax2[b] = m;
}

__global__ __launch_bounds__(256) void k_attn2(const float* __restrict__ h2,
                                               const float* __restrict__ s2src,
                                               const float* __restrict__ s2dst,
                                               const float* __restrict__ smax2,
                                               const float* __restrict__ bias2,
                                               float* __restrict__ g2) {
    int it = blockIdx.x, b = blockIdx.y;
    int tid = threadIdx.x, lane = tid & 63, wv = tid >> 6;
    __shared__ float ss[NNODE];
    for (int n = tid; n < NNODE; n += 256) ss[n] = s2src[b * NNODE + n];
    __syncthreads();
    int i = it * 4 + wv;
    if (i >= NNODE) return;
    int f = lane & 31, half = lane >> 5;
    float d = s2dst[b * NNODE + i];
    float e0 = d + smax2[b];
    float mx = e0 > 0.f ? e0 : 0.2f * e0;
    float acc = 0.f, den = 0.f;
    for (int j = half; j < NNODE; j += 2) {
        float e = d + ss[j];
        e = e > 0.f ? e : 0.2f * e;
        float w = __expf(e - mx);
        den += w;
        acc = fmaf(w, h2[(b * NNODE + j) * 32 + f], acc);
    }
    acc += __shfl_down(acc, 32);
    den += __shfl_down(den, 32);
    if (lane < 32) g2[(b * NNODE + i) * 32 + f] = acc / den + bias2[f];
}

__global__ __launch_bounds__(256) void k_emb(const float* __restrict__ g2,
                                             float* __restrict__ emb,
                                             float* __restrict__ dout) {
    int b = blockIdx.x;
    int f = threadIdx.x & 31, g = threadIdx.x >> 5;
    __shared__ float red[8][32];
    float s = 0.f;
    for (int i = g; i < NNODE; i += 8) s += g2[(b * NNODE + i) * 32 + f];
    red[g][f] = s;
    __syncthreads();
    if (threadIdx.x < 32) {
        float t = 0.f;
        #pragma unroll
        for (int gg = 0; gg < 8; gg++) t += red[gg][f];
        t *= (1.0f / 250.0f);
        emb[b * 32 + f] = t;
        dout[16 + b * 32 + f] = t;
    }
}

__global__ __launch_bounds__(256) void k_fc(const float* __restrict__ emb,
                                            const float* __restrict__ fc1w,
                                            const float* __restrict__ fc1b,
                                            const float* __restrict__ bnfg,
                                            const float* __restrict__ bnfb,
                                            const float* __restrict__ fc2w,
                                            const float* __restrict__ fc2b,
                                            float* __restrict__ dout) {
    __shared__ float es[256];
    __shared__ float zs[1024];
    int tid = threadIdx.x;
    es[tid] = emb[tid];
    __syncthreads();
    float inv = rsqrtf(1.0f + 1e-5f);
    #pragma unroll
    for (int rep = 0; rep < 4; rep++) {
        int idx = tid + rep * 256;
        int b = idx >> 7, j = idx & 127;
        float a = fc1b[j];
        #pragma unroll
        for (int k = 0; k < 32; k++) a = fmaf(es[b * 32 + k], fc1w[k * 128 + j], a);
        a = a * (bnfg[j] * inv) + bnfb[j];
        zs[idx] = fmaxf(a, 0.f);
    }
    __syncthreads();
    if (tid < 16) {
        int b = tid >> 1, o = tid & 1;
        float a = fc2b[o];
        for (int k = 0; k < 128; k++) a = fmaf(zs[b * 128 + k], fc2w[k * 2 + o], a);
        dout[b * 2 + o] = a;
    }
}

// ---------------- launch ----------------
extern "C" void kernel_launch(void* const* d_in, const int* in_sizes, int n_in,
                              void* d_out, int out_size, void* d_ws, size_t ws_size,
                              hipStream_t stream) {
    (void)in_sizes; (void)n_in; (void)out_size; (void)ws_size;
    const float* x       = (const float*)d_in[0];
    const float* sinc_w  = (const float*)d_in[1];
    const float* conv1_w = (const float*)d_in[2];
    const float* conv1_b = (const float*)d_in[3];
    const float* bn1_g   = (const float*)d_in[4];
    const float* bn1_b   = (const float*)d_in[5];
    const float* conv2_w = (const float*)d_in[6];
    const float* conv2_b = (const float*)d_in[7];
    const float* bn2_g   = (const float*)d_in[8];
    const float* bn2_b   = (const float*)d_in[9];
    const float* gat1_W  = (const float*)d_in[10];
    const float* gat1_as = (const float*)d_in[11];
    const float* gat1_ad = (const float*)d_in[12];
    const float* gat1_bi = (const float*)d_in[13];
    const float* gat2_W  = (const float*)d_in[14];
    const float* gat2_as = (const float*)d_in[15];
    const float* gat2_ad = (const float*)d_in[16];
    const float* gat2_bi = (const float*)d_in[17];
    const float* fc1_w   = (const float*)d_in[18];
    const float* fc1_b   = (const float*)d_in[19];
    const float* bnf_g   = (const float*)d_in[20];
    const float* bnf_b   = (const float*)d_in[21];
    const float* fc2_w   = (const float*)d_in[22];
    const float* fc2_b   = (const float*)d_in[23];
    float* dout = (float*)d_out;

    float* ws      = (float*)d_ws;
    float* frames  = ws;                    // 2,056,192
    float* Wc      = frames + 2056192;      // 525,312
    float* Wsin    = Wc + 525312;           // 525,312
    float* S0      = Wsin + 525312;         // 1,030,104
    float* wbar    = S0 + 1030104;          // 20,540
    float* w1f     = wbar + 20540;          // 288
    float* b1f     = w1f + 288;             // 32
    float* w2f     = b1f + 32;              // 9,216
    float* b2f     = w2f + 9216;            // 32
    unsigned short* bpk = (unsigned short*)(b2f + 32);  // 9,216 ushort = 4,608 floats
    float* nodes   = b2f + 32 + 4608;       // 8,232,000
    float* h1      = nodes + 8232000;       // 1,024,000
    float* ssrc1   = h1 + 1024000;          // 16,000
    float* sdst1   = ssrc1 + 16000;         // 16,000
    float* smax1   = sdst1 + 16000;         // 64
    float* g1      = smax1 + 64;            // 1,024,000
    float* h2      = g1 + 1024000;          // 64,000
    float* s2src   = h2 + 64000;            // 2,000
    float* s2dst   = s2src + 2000;          // 2,000
    float* smax2   = s2dst + 2000;          // 8
    float* g2      = smax2 + 8;             // 64,000
    float* embp    = g2 + 64000;            // 256

    hipLaunchKernelGGL(k_fold, dim3(38), dim3(256), 0, stream,
                       conv1_w, conv1_b, bn1_g, bn1_b, conv2_w, conv2_b, bn2_g, bn2_b,
                       w1f, b1f, w2f, b2f);
    hipLaunchKernelGGL(k_pack, dim3(36), dim3(256), 0, stream, w2f, bpk);
    hipLaunchKernelGGL(k_wbar, dim3((1027 * 20 + 255) / 256), dim3(256), 0, stream, sinc_w, wbar);
    hipLaunchKernelGGL(k_basis, dim3((NBINS * 1024 + 255) / 256), dim3(256), 0, stream, Wc, Wsin);
    hipLaunchKernelGGL(k_frames, dim3((NROWS * 1024 + 255) / 256), dim3(256), 0, stream, x, frames);
    hipLaunchKernelGGL(k_dft_gemm, dim3(9, 63), dim3(256), 0, stream, frames, Wc, Wsin, S0);
    hipLaunchKernelGGL(k_sinc, dim3(250, 8), dim3(64), 0, stream, x, wbar, nodes);
    hipLaunchKernelGGL(k_conv_mfma, dim3(16, 32, 8), dim3(256), 0, stream,
                       S0, w1f, b1f, bpk, b2f, nodes);
    hipLaunchKernelGGL(k_gat1, dim3(8, 63), dim3(256), 0, stream, nodes, gat1_W, h1);
    hipLaunchKernelGGL(k_scores1, dim3(500), dim3(256), 0, stream, h1, gat1_as, gat1_ad, ssrc1, sdst1);
    hipLaunchKernelGGL(k_smax1, dim3(64), dim3(64), 0, stream, ssrc1, smax1);
    hipLaunchKernelGGL(k_attn1, dim3(63, 8, 8), dim3(64), 0, stream,
                       h1, ssrc1, sdst1, smax1, gat1_bi, g1);
    hipLaunchKernelGGL(k_h2, dim3(500), dim3(256), 0, stream,
                       g1, gat2_W, gat2_as, gat2_ad, h2, s2src, s2dst);
    hipLaunchKernelGGL(k_smax2, dim3(8), dim3(64), 0, stream, s2src, smax2);
    hipLaunchKernelGGL(k_attn2, dim3(63, 8), dim3(256), 0, stream,
                       h2, s2src, s2dst, smax2, gat2_bi, g2);
    hipLaunchKernelGGL(k_emb, dim3(8), dim3(256), 0, stream, g2, embp, dout);
    hipLaunchKernelGGL(k_fc, dim3(1), dim3(256), 0, stream,
                       embp, fc1_w, fc1_b, bnf_g, bnf_b, fc2_w, fc2_b, dout);
}

// Round 4
// 643.242 us; speedup vs baseline: 1.6218x; 1.2031x over previous
//
#include <hip/hip_runtime.h>
#include <hip/hip_bf16.h>
#include <math.h>

// ---------------- constants ----------------
#define TB 8
#define TT 64000
#define NFRAMES 251
#define NROWS (TB*NFRAMES)      // 2008
#define NBINS 513
#define NNODE 250
#define NODE_DIM 4116
#define KPAD 4128

typedef __attribute__((ext_vector_type(8))) short short8;
typedef __attribute__((ext_vector_type(4))) float floatx4;

static __device__ __forceinline__ unsigned short f2bf(float x) {
    __hip_bfloat16 h = __float2bfloat16(x);
    return *(unsigned short*)&h;
}

// ---------------- small prep kernels ----------------

__global__ void k_fold(const float* __restrict__ c1w, const float* __restrict__ c1b,
                       const float* __restrict__ g1bn, const float* __restrict__ b1bn,
                       const float* __restrict__ c2w, const float* __restrict__ c2b,
                       const float* __restrict__ g2bn, const float* __restrict__ b2bn,
                       float* __restrict__ w1f, float* __restrict__ b1f,
                       float* __restrict__ w2f, float* __restrict__ b2f) {
    int idx = blockIdx.x * 256 + threadIdx.x;
    float inv = rsqrtf(1.0f + 1e-5f);
    if (idx < 9216) {
        int co = idx / 288;
        w2f[idx] = c2w[idx] * (g2bn[co] * inv);
    } else if (idx < 9216 + 288) {
        int r = idx - 9216;
        w1f[r] = c1w[r] * (g1bn[r / 9] * inv);
    } else if (idx < 9216 + 288 + 32) {
        int c = idx - 9504;
        b1f[c] = c1b[c] * (g1bn[c] * inv) + b1bn[c];
    } else if (idx < 9216 + 288 + 64) {
        int c = idx - 9536;
        b2f[c] = c2b[c] * (g2bn[c] * inv) + b2bn[c];
    }
}

// pack conv2 weights into MFMA B-fragment order, bf16.
__global__ void k_pack(const float* __restrict__ w2f, unsigned short* __restrict__ Bp) {
    int idx = blockIdx.x * 256 + threadIdx.x;
    if (idx >= 9216) return;
    int j = idx & 7, lane = (idx >> 3) & 63, ct = (idx >> 9) & 1, s = idx >> 10;
    int co = ct * 16 + (lane & 15);
    int ci = (lane >> 4) * 8 + j;
    Bp[idx] = f2bf(w2f[co * 288 + ci * 9 + s]);
}

// transpose gat1_W [4116x512] f32 -> Wt [512][KPAD] bf16 (pad rows zero)
__global__ __launch_bounds__(256) void k_wt(const float* __restrict__ W,
                                            unsigned short* __restrict__ Wt) {
    __shared__ unsigned short tile[64][65];
    int kt = blockIdx.x, nt = blockIdx.y;
    int tid = threadIdx.x;
    for (int idx = tid; idx < 4096; idx += 256) {
        int r = idx >> 6, c = idx & 63;        // r = k-local, c = n-local
        int k = kt * 64 + r;
        float v = (k < NODE_DIM) ? W[k * 512 + nt * 64 + c] : 0.f;
        tile[r][c] = f2bf(v);
    }
    __syncthreads();
    for (int idx = tid; idx < 4096; idx += 256) {
        int nl = idx >> 6, kl = idx & 63;
        int k = kt * 64 + kl;
        if (k < KPAD)
            Wt[(size_t)(nt * 64 + nl) * KPAD + k] = tile[kl][nl];
    }
}

// wbar[m][c] = 0.25 * sum_{d=0..3} sinc_w[c][m-d]  (m in 0..1026)
__global__ void k_wbar(const float* __restrict__ sw, float* __restrict__ wbar) {
    int idx = blockIdx.x * 256 + threadIdx.x;
    if (idx >= 1027 * 20) return;
    int m = idx / 20, c = idx % 20;
    float s = 0.f;
    #pragma unroll
    for (int d = 0; d < 4; d++) {
        int k = m - d;
        if (k >= 0 && k < 1024) s += sw[c * 1024 + k];
    }
    wbar[idx] = 0.25f * s;
}

// DFT basis
__global__ void k_basis(float* __restrict__ Wc, float* __restrict__ Wsin) {
    int idx = blockIdx.x * 256 + threadIdx.x;
    if (idx >= NBINS * 1024) return;
    int k = idx >> 10, n = idx & 1023;
    int mm = (k * n) & 1023;
    float s, c;
    sincospif((float)mm * (1.0f / 512.0f), &s, &c);
    Wc[idx] = c;
    Wsin[idx] = s;
}

// frames[m][n] = reflect-padded x
__global__ void k_frames(const float* __restrict__ x, float* __restrict__ frames) {
    int idx = blockIdx.x * 256 + threadIdx.x;
    if (idx >= NROWS * 1024) return;
    int m = idx >> 10, n = idx & 1023;
    int b = m / NFRAMES, i = m - b * NFRAMES;
    int j = i * 256 + n - 512;
    if (j < 0) j = -j;
    if (j >= TT) j = 2 * TT - 2 - j;
    frames[idx] = x[b * TT + j];
}

// sinc features -> nodesb[b][u][0..19] (bf16)
__global__ __launch_bounds__(64) void k_sinc(const float* __restrict__ x,
                                             const float* __restrict__ wbar,
                                             unsigned short* __restrict__ nodesb) {
    int u = blockIdx.x, b = blockIdx.y;
    int c = threadIdx.x;
    if (c >= 20) return;
    const float* xb = x + b * TT;
    int base = 4 * u - 512;
    float acc = 0.f;
    for (int m = 0; m < 1027; m++) {
        int g = base + m;
        float xv = (g >= 0) ? xb[g] : 0.f;
        acc = fmaf(wbar[m * 20 + c], xv, acc);
    }
    nodesb[(size_t)(b * NNODE + u) * KPAD + c] = f2bf(acc);
}

// ---------------- DFT GEMM: S0[b][k][i] = log(|rfft|+1e-9) ----------------
__global__ __launch_bounds__(256) void k_dft_gemm(const float* __restrict__ frames,
                                                  const float* __restrict__ Wc,
                                                  const float* __restrict__ Wsin,
                                                  float* __restrict__ S0) {
    __shared__ __align__(16) float As[32][36];
    __shared__ __align__(16) float Bc[32][68];
    __shared__ __align__(16) float Bs[32][68];
    int tid = threadIdx.x;
    int tx = tid & 15, ty = tid >> 4;
    int N0 = blockIdx.x * 64, M0 = blockIdx.y * 32;
    float accR[2][4] = {{0.f}}, accI[2][4] = {{0.f}};
    int ldr = tid >> 3, ldk = (tid & 7) << 2;
    for (int K0 = 0; K0 < 1024; K0 += 32) {
        {
            int m = M0 + ldr;
            float4 v = make_float4(0.f, 0.f, 0.f, 0.f);
            if (m < NROWS) v = *(const float4*)&frames[m * 1024 + K0 + ldk];
            As[ldk + 0][ldr] = v.x; As[ldk + 1][ldr] = v.y;
            As[ldk + 2][ldr] = v.z; As[ldk + 3][ldr] = v.w;
        }
        #pragma unroll
        for (int rr = 0; rr < 2; rr++) {
            int n = N0 + ldr + rr * 32;
            float4 vc = make_float4(0.f, 0.f, 0.f, 0.f);
            float4 vs = make_float4(0.f, 0.f, 0.f, 0.f);
            if (n < NBINS) {
                vc = *(const float4*)&Wc[n * 1024 + K0 + ldk];
                vs = *(const float4*)&Wsin[n * 1024 + K0 + ldk];
            }
            Bc[ldk + 0][ldr + rr * 32] = vc.x; Bc[ldk + 1][ldr + rr * 32] = vc.y;
            Bc[ldk + 2][ldr + rr * 32] = vc.z; Bc[ldk + 3][ldr + rr * 32] = vc.w;
            Bs[ldk + 0][ldr + rr * 32] = vs.x; Bs[ldk + 1][ldr + rr * 32] = vs.y;
            Bs[ldk + 2][ldr + rr * 32] = vs.z; Bs[ldk + 3][ldr + rr * 32] = vs.w;
        }
        __syncthreads();
        for (int kk = 0; kk < 32; kk++) {
            float2 a = *(const float2*)&As[kk][ty * 2];
            float4 c4 = *(const float4*)&Bc[kk][tx * 4];
            float4 s4 = *(const float4*)&Bs[kk][tx * 4];
            float av[2] = {a.x, a.y};
            float cv[4] = {c4.x, c4.y, c4.z, c4.w};
            float sv[4] = {s4.x, s4.y, s4.z, s4.w};
            #pragma unroll
            for (int mi = 0; mi < 2; mi++)
                #pragma unroll
                for (int ni = 0; ni < 4; ni++) {
                    accR[mi][ni] = fmaf(av[mi], cv[ni], accR[mi][ni]);
                    accI[mi][ni] = fmaf(av[mi], sv[ni], accI[mi][ni]);
                }
        }
        __syncthreads();
    }
    #pragma unroll
    for (int mi = 0; mi < 2; mi++) {
        int m = M0 + ty * 2 + mi;
        if (m >= NROWS) continue;
        int b = m / NFRAMES, i = m - b * NFRAMES;
        #pragma unroll
        for (int ni = 0; ni < 4; ni++) {
            int n = N0 + tx * 4 + ni;
            if (n < NBINS) {
                float re = accR[mi][ni], im = accI[mi][ni];
                S0[(b * NBINS + n) * NFRAMES + i] = logf(sqrtf(fmaf(re, re, im * im)) + 1e-9f);
            }
        }
    }
}

// ---------------- fused conv1(f32 VALU) -> conv2 (bf16 MFMA) -> maxpool -> nodesb ----------------
__global__ __launch_bounds__(256) void k_conv_mfma(const float* __restrict__ S0,
                                                   const float* __restrict__ w1f,
                                                   const float* __restrict__ b1f,
                                                   const unsigned short* __restrict__ Bp,
                                                   const float* __restrict__ b2f,
                                                   unsigned short* __restrict__ nodesb) {
    __shared__ __align__(16) float s0t[20][21];
    __shared__ __align__(16) unsigned short o1bf[18 * 18 * 32];  // [lf][lt][ci]
    __shared__ __align__(16) unsigned short BpL[9216];
    __shared__ float w1s[288];
    __shared__ float b1s[32];
    __shared__ float b2s[32];
    int tid = threadIdx.x;
    int b = blockIdx.z;
    int F0 = blockIdx.y * 8;
    int T0 = blockIdx.x * 8;

    for (int idx = tid; idx < 400; idx += 256) {
        int i = idx / 20, j = idx % 20;
        int fr = 2 * F0 - 2 + i, tc = 2 * T0 - 2 + j;
        float v = 0.f;
        if (fr >= 0 && fr < 513 && tc >= 0 && tc < 251) v = S0[(b * 513 + fr) * 251 + tc];
        s0t[i][j] = v;
    }
    for (int idx = tid; idx < 4608; idx += 256)
        ((unsigned int*)BpL)[idx] = ((const unsigned int*)Bp)[idx];
    for (int idx = tid; idx < 288; idx += 256) w1s[idx] = w1f[idx];
    if (tid < 32) { b1s[tid] = b1f[tid]; b2s[tid] = b2f[tid]; }
    __syncthreads();

    for (int idx = tid; idx < 10368; idx += 256) {
        int ci = idx & 31, pos = idx >> 5;
        int lf = pos / 18, lt = pos - lf * 18;
        int r1 = 2 * F0 - 1 + lf, t1 = 2 * T0 - 1 + lt;
        float v = 0.f;
        if (r1 >= 0 && r1 < 513 && t1 >= 0 && t1 < 251) {
            float a = b1s[ci];
            const float* wp = &w1s[ci * 9];
            #pragma unroll
            for (int di = 0; di < 3; di++)
                #pragma unroll
                for (int dj = 0; dj < 3; dj++)
                    a = fmaf(s0t[lf + di][lt + dj], wp[di * 3 + dj], a);
            v = fmaxf(a, 0.f);
        }
        o1bf[pos * 32 + ci] = f2bf(v);
    }
    __syncthreads();

    int lane = tid & 63, w = tid >> 6;
    int q = lane >> 4, col = lane & 15;
    floatx4 acc[4][2];
    #pragma unroll
    for (int rt = 0; rt < 4; rt++)
        #pragma unroll
        for (int ct = 0; ct < 2; ct++)
            acc[rt][ct] = (floatx4){0.f, 0.f, 0.f, 0.f};

    #pragma unroll
    for (int s = 0; s < 9; s++) {
        const int di = s / 3, dj = s % 3;
        short8 bf0 = *(const short8*)&BpL[(s * 2 + 0) * 512 + lane * 8];
        short8 bf1 = *(const short8*)&BpL[(s * 2 + 1) * 512 + lane * 8];
        #pragma unroll
        for (int rt = 0; rt < 4; rt++) {
            int r = w * 4 + rt;
            short8 af = *(const short8*)&o1bf[(((r + di) * 18) + (col + dj)) * 32 + q * 8];
            acc[rt][0] = __builtin_amdgcn_mfma_f32_16x16x32_bf16(af, bf0, acc[rt][0], 0, 0, 0);
            acc[rt][1] = __builtin_amdgcn_mfma_f32_16x16x32_bf16(af, bf1, acc[rt][1], 0, 0, 0);
        }
    }

    #pragma unroll
    for (int ct = 0; ct < 2; ct++) {
        int co = ct * 16 + col;
        float bb = b2s[co];
        #pragma unroll
        for (int fp2 = 0; fp2 < 2; fp2++) {
            #pragma unroll
            for (int tc2 = 0; tc2 < 2; tc2++) {
                float m0 = fmaxf(fmaxf(acc[2 * fp2][ct][2 * tc2], acc[2 * fp2][ct][2 * tc2 + 1]),
                                 fmaxf(acc[2 * fp2 + 1][ct][2 * tc2], acc[2 * fp2 + 1][ct][2 * tc2 + 1]));
                float v = fmaxf(m0 + bb, 0.f);
                int tp = T0 + 2 * q + tc2;
                if (tp < 125) {
                    int fg = F0 + 2 * w + fp2;
                    int node = 2 * tp + (co >= 16 ? 1 : 0);
                    nodesb[(size_t)(b * NNODE + node) * KPAD + 20 + (co & 15) * 256 + fg] = f2bf(v);
                }
            }
        }
    }
}

// ---------------- GAT1 GEMM (bf16 MFMA): h1[2000x512] = nodesb @ Wt^T ----------------
__global__ __launch_bounds__(256) void k_gat1b(const unsigned short* __restrict__ A,
                                               const unsigned short* __restrict__ Bt,
                                               float* __restrict__ C) {
    __shared__ __align__(16) unsigned short As[64 * 40];
    __shared__ __align__(16) unsigned short Bs[64 * 40];
    int tid = threadIdx.x;
    int N0 = blockIdx.x * 64, M0 = blockIdx.y * 64;
    int sr = tid >> 2, sc = (tid & 3) * 8;
    int w = tid >> 6, lane = tid & 63;
    int q = lane >> 4, col = lane & 15;
    int mb = (w >> 1) * 32, nb = (w & 1) * 32;
    floatx4 acc[2][2];
    acc[0][0] = acc[0][1] = acc[1][0] = acc[1][1] = (floatx4){0.f, 0.f, 0.f, 0.f};
    short8 z8 = {0, 0, 0, 0, 0, 0, 0, 0};
    int mA = M0 + sr;
    bool mv = mA < 2000;
    const unsigned short* pa = A + (size_t)mA * KPAD + sc;
    const unsigned short* pb = Bt + (size_t)(N0 + sr) * KPAD + sc;

    for (int K0 = 0; K0 < KPAD; K0 += 32) {
        short8 va = mv ? *(const short8*)(pa + K0) : z8;
        short8 vb = *(const short8*)(pb + K0);
        *(short8*)&As[sr * 40 + sc] = va;
        *(short8*)&Bs[sr * 40 + sc] = vb;
        __syncthreads();
        short8 a0 = *(const short8*)&As[(mb + col) * 40 + q * 8];
        short8 a1 = *(const short8*)&As[(mb + 16 + col) * 40 + q * 8];
        short8 b0 = *(const short8*)&Bs[(nb + col) * 40 + q * 8];
        short8 b1 = *(const short8*)&Bs[(nb + 16 + col) * 40 + q * 8];
        acc[0][0] = __builtin_amdgcn_mfma_f32_16x16x32_bf16(a0, b0, acc[0][0], 0, 0, 0);
        acc[0][1] = __builtin_amdgcn_mfma_f32_16x16x32_bf16(a0, b1, acc[0][1], 0, 0, 0);
        acc[1][0] = __builtin_amdgcn_mfma_f32_16x16x32_bf16(a1, b0, acc[1][0], 0, 0, 0);
        acc[1][1] = __builtin_amdgcn_mfma_f32_16x16x32_bf16(a1, b1, acc[1][1], 0, 0, 0);
        __syncthreads();
    }
    #pragma unroll
    for (int mi = 0; mi < 2; mi++)
        #pragma unroll
        for (int ni = 0; ni < 2; ni++)
            #pragma unroll
            for (int rr = 0; rr < 4; rr++) {
                int m = M0 + mb + mi * 16 + q * 4 + rr;
                if (m < 2000)
                    C[m * 512 + N0 + nb + ni * 16 + col] = acc[mi][ni][rr];
            }
}

// ---------------- GAT1 scores / max / attention ----------------
__global__ __launch_bounds__(256) void k_scores1(const float* __restrict__ h1,
                                                 const float* __restrict__ asrc,
                                                 const float* __restrict__ adst,
                                                 float* __restrict__ ssrc,
                                                 float* __restrict__ sdst) {
    int row = blockIdx.x * 4 + (threadIdx.x >> 6);
    int lane = threadIdx.x & 63;
    if (row >= 2000) return;
    for (int h = 0; h < 8; h++) {
        float v = h1[row * 512 + h * 64 + lane];
        float ps = v * asrc[h * 64 + lane];
        float pd = v * adst[h * 64 + lane];
        for (int off = 32; off > 0; off >>= 1) {
            ps += __shfl_down(ps, off);
            pd += __shfl_down(pd, off);
        }
        if (lane == 0) { ssrc[row * 8 + h] = ps; sdst[row * 8 + h] = pd; }
    }
}

__global__ __launch_bounds__(64) void k_smax1(const float* __restrict__ ssrc,
                                              float* __restrict__ smax) {
    int bh = blockIdx.x;
    int b = bh >> 3, h = bh & 7;
    int lane = threadIdx.x;
    float m = -1e30f;
    for (int n = lane; n < NNODE; n += 64) m = fmaxf(m, ssrc[(b * NNODE + n) * 8 + h]);
    for (int off = 32; off > 0; off >>= 1) m = fmaxf(m, __shfl_down(m, off));
    if (lane == 0) smax[bh] = m;
}

__global__ __launch_bounds__(64) void k_attn1(const float* __restrict__ h1,
                                              const float* __restrict__ ssrc,
                                              const float* __restrict__ sdst,
                                              const float* __restrict__ smax,
                                              const float* __restrict__ bias,
                                              float* __restrict__ g1) {
    int it = blockIdx.x, h = blockIdx.y, b = blockIdx.z;
    int f = threadIdx.x;
    __shared__ float ss[NNODE];
    for (int n = f; n < NNODE; n += 64) ss[n] = ssrc[(b * NNODE + n) * 8 + h];
    __syncthreads();
    float mxs = smax[b * 8 + h];
    int i0 = it * 4;
    float d[4], mx[4], acc[4] = {0.f, 0.f, 0.f, 0.f}, den[4] = {0.f, 0.f, 0.f, 0.f};
    #pragma unroll
    for (int ii = 0; ii < 4; ii++) {
        int i = i0 + ii;
        d[ii] = (i < NNODE) ? sdst[(b * NNODE + i) * 8 + h] : 0.f;
        float e = d[ii] + mxs;
        mx[ii] = e > 0.f ? e : 0.2f * e;
    }
    for (int j = 0; j < NNODE; j++) {
        float sj = ss[j];
        float hv = h1[(b * NNODE + j) * 512 + h * 64 + f];
        #pragma unroll
        for (int ii = 0; ii < 4; ii++) {
            float e = d[ii] + sj;
            e = e > 0.f ? e : 0.2f * e;
            float w = __expf(e - mx[ii]);
            den[ii] += w;
            acc[ii] = fmaf(w, hv, acc[ii]);
        }
    }
    float bb = bias[h * 64 + f];
    #pragma unroll
    for (int ii = 0; ii < 4; ii++) {
        int i = i0 + ii;
        if (i < NNODE)
            g1[(b * NNODE + i) * 512 + h * 64 + f] = fmaxf(acc[ii] / den[ii] + bb, 0.f);
    }
}

// ---------------- GAT2 ----------------
__global__ __launch_bounds__(256) void k_h2(const float* __restrict__ g1,
                                            const float* __restrict__ W2,
                                            const float* __restrict__ a2src,
                                            const float* __restrict__ a2dst,
                                            float* __restrict__ h2,
                                            float* __restrict__ s2src,
                                            float* __restrict__ s2dst) {
    int row = blockIdx.x * 4 + (threadIdx.x >> 6);
    if (row >= 2000) return;
    int lane = threadIdx.x & 63;
    int o = lane & 31, half = lane >> 5;
    const float* gr = &g1[row * 512 + half * 256];
    float acc = 0.f;
    for (int k = 0; k < 256; k++) acc = fmaf(gr[k], W2[(half * 256 + k) * 32 + o], acc);
    acc += __shfl_down(acc, 32);
    float ps = acc * a2src[o], pd = acc * a2dst[o];
    for (int off = 16; off > 0; off >>= 1) {
        ps += __shfl_down(ps, off, 32);
        pd += __shfl_down(pd, off, 32);
    }
    if (lane == 0) { s2src[row] = ps; s2dst[row] = pd; }
    if (lane < 32) h2[row * 32 + o] = acc;
}

__global__ __launch_bounds__(64) void k_smax2(const float* __restrict__ s2src,
                                              float* __restrict__ smax2) {
    int b = blockIdx.x, lane = threadIdx.x;
    float m = -1e30f;
    for (int n = lane; n < NNODE; n += 64) m = fmaxf(m, s2src[b * NNODE + n]);
    for (int off = 32; off > 0; off >>= 1) m = fmaxf(m, __shfl_down(m, off));
    if (lane == 0) smax2[b] = m;
}

__global__ __launch_bounds__(256) void k_attn2(const float* __restrict__ h2,
                                               const float* __restrict__ s2src,
                                               const float* __restrict__ s2dst,
                                               const float* __restrict__ smax2,
                                               const float* __restrict__ bias2,
                                               float* __restrict__ g2) {
    int it = blockIdx.x, b = blockIdx.y;
    int tid = threadIdx.x, lane = tid & 63, wv = tid >> 6;
    __shared__ float ss[NNODE];
    for (int n = tid; n < NNODE; n += 256) ss[n] = s2src[b * NNODE + n];
    __syncthreads();
    int i = it * 4 + wv;
    if (i >= NNODE) return;
    int f = lane & 31, half = lane >> 5;
    float d = s2dst[b * NNODE + i];
    float e0 = d + smax2[b];
    float mx = e0 > 0.f ? e0 : 0.2f * e0;
    float acc = 0.f, den = 0.f;
    for (int j = half; j < NNODE; j += 2) {
        float e = d + ss[j];
        e = e > 0.f ? e : 0.2f * e;
        float w = __expf(e - mx);
        den += w;
        acc = fmaf(w, h2[(b * NNODE + j) * 32 + f], acc);
    }
    acc += __shfl_down(acc, 32);
    den += __shfl_down(den, 32);
    if (lane < 32) g2[(b * NNODE + i) * 32 + f] = acc / den + bias2[f];
}

__global__ __launch_bounds__(256) void k_emb(const float* __restrict__ g2,
                                             float* __restrict__ emb,
                                             float* __restrict__ dout) {
    int b = blockIdx.x;
    int f = threadIdx.x & 31, g = threadIdx.x >> 5;
    __shared__ float red[8][32];
    float s = 0.f;
    for (int i = g; i < NNODE; i += 8) s += g2[(b * NNODE + i) * 32 + f];
    red[g][f] = s;
    __syncthreads();
    if (threadIdx.x < 32) {
        float t = 0.f;
        #pragma unroll
        for (int gg = 0; gg < 8; gg++) t += red[gg][f];
        t *= (1.0f / 250.0f);
        emb[b * 32 + f] = t;
        dout[16 + b * 32 + f] = t;
    }
}

__global__ __launch_bounds__(256) void k_fc(const float* __restrict__ emb,
                                            const float* __restrict__ fc1w,
                                            const float* __restrict__ fc1b,
                                            const float* __restrict__ bnfg,
                                            const float* __restrict__ bnfb,
                                            const float* __restrict__ fc2w,
                                            const float* __restrict__ fc2b,
                                            float* __restrict__ dout) {
    __shared__ float es[256];
    __shared__ float zs[1024];
    int tid = threadIdx.x;
    es[tid] = emb[tid];
    __syncthreads();
    float inv = rsqrtf(1.0f + 1e-5f);
    #pragma unroll
    for (int rep = 0; rep < 4; rep++) {
        int idx = tid + rep * 256;
        int b = idx >> 7, j = idx & 127;
        float a = fc1b[j];
        #pragma unroll
        for (int k = 0; k < 32; k++) a = fmaf(es[b * 32 + k], fc1w[k * 128 + j], a);
        a = a * (bnfg[j] * inv) + bnfb[j];
        zs[idx] = fmaxf(a, 0.f);
    }
    __syncthreads();
    if (tid < 16) {
        int b = tid >> 1, o = tid & 1;
        float a = fc2b[o];
        for (int k = 0; k < 128; k++) a = fmaf(zs[b * 128 + k], fc2w[k * 2 + o], a);
        dout[b * 2 + o] = a;
    }
}

// ---------------- launch ----------------
extern "C" void kernel_launch(void* const* d_in, const int* in_sizes, int n_in,
                              void* d_out, int out_size, void* d_ws, size_t ws_size,
                              hipStream_t stream) {
    (void)in_sizes; (void)n_in; (void)out_size; (void)ws_size;
    const float* x       = (const float*)d_in[0];
    const float* sinc_w  = (const float*)d_in[1];
    const float* conv1_w = (const float*)d_in[2];
    const float* conv1_b = (const float*)d_in[3];
    const float* bn1_g   = (const float*)d_in[4];
    const float* bn1_b   = (const float*)d_in[5];
    const float* conv2_w = (const float*)d_in[6];
    const float* conv2_b = (const float*)d_in[7];
    const float* bn2_g   = (const float*)d_in[8];
    const float* bn2_b   = (const float*)d_in[9];
    const float* gat1_W  = (const float*)d_in[10];
    const float* gat1_as = (const float*)d_in[11];
    const float* gat1_ad = (const float*)d_in[12];
    const float* gat1_bi = (const float*)d_in[13];
    const float* gat2_W  = (const float*)d_in[14];
    const float* gat2_as = (const float*)d_in[15];
    const float* gat2_ad = (const float*)d_in[16];
    const float* gat2_bi = (const float*)d_in[17];
    const float* fc1_w   = (const float*)d_in[18];
    const float* fc1_b   = (const float*)d_in[19];
    const float* bnf_g   = (const float*)d_in[20];
    const float* bnf_b   = (const float*)d_in[21];
    const float* fc2_w   = (const float*)d_in[22];
    const float* fc2_b   = (const float*)d_in[23];
    float* dout = (float*)d_out;

    float* ws      = (float*)d_ws;
    float* frames  = ws;                    // 2,056,192
    float* Wc      = frames + 2056192;      // 525,312
    float* Wsin    = Wc + 525312;           // 525,312
    float* S0      = Wsin + 525312;         // 1,030,104
    float* wbar    = S0 + 1030104;          // 20,540
    float* w1f     = wbar + 20540;          // 288
    float* b1f     = w1f + 288;             // 32
    float* w2f     = b1f + 32;              // 9,216
    float* b2f     = w2f + 9216;            // 32
    unsigned short* bpk = (unsigned short*)(b2f + 32);        // 9,216 ushort = 4,608 f
    unsigned short* Wt  = (unsigned short*)(b2f + 32 + 4608); // 512*4128 ushort = 1,056,768 f
    unsigned short* nodesb = Wt + (size_t)512 * KPAD;         // 2000*4128 ushort = 4,128,000 f
    float* h1      = (float*)(nodesb + (size_t)2000 * KPAD);  // 1,024,000
    float* ssrc1   = h1 + 1024000;          // 16,000
    float* sdst1   = ssrc1 + 16000;         // 16,000
    float* smax1   = sdst1 + 16000;         // 64
    float* g1      = smax1 + 64;            // 1,024,000
    float* h2      = g1 + 1024000;          // 64,000
    float* s2src   = h2 + 64000;            // 2,000
    float* s2dst   = s2src + 2000;          // 2,000
    float* smax2   = s2dst + 2000;          // 8
    float* g2      = smax2 + 8;             // 64,000
    float* embp    = g2 + 64000;            // 256

    hipLaunchKernelGGL(k_fold, dim3(38), dim3(256), 0, stream,
                       conv1_w, conv1_b, bn1_g, bn1_b, conv2_w, conv2_b, bn2_g, bn2_b,
                       w1f, b1f, w2f, b2f);
    hipLaunchKernelGGL(k_pack, dim3(36), dim3(256), 0, stream, w2f, bpk);
    hipLaunchKernelGGL(k_wt, dim3(65, 8), dim3(256), 0, stream, gat1_W, Wt);
    hipLaunchKernelGGL(k_wbar, dim3((1027 * 20 + 255) / 256), dim3(256), 0, stream, sinc_w, wbar);
    hipLaunchKernelGGL(k_basis, dim3((NBINS * 1024 + 255) / 256), dim3(256), 0, stream, Wc, Wsin);
    hipLaunchKernelGGL(k_frames, dim3((NROWS * 1024 + 255) / 256), dim3(256), 0, stream, x, frames);
    hipLaunchKernelGGL(k_dft_gemm, dim3(9, 63), dim3(256), 0, stream, frames, Wc, Wsin, S0);
    hipLaunchKernelGGL(k_sinc, dim3(250, 8), dim3(64), 0, stream, x, wbar, nodesb);
    hipLaunchKernelGGL(k_conv_mfma, dim3(16, 32, 8), dim3(256), 0, stream,
                       S0, w1f, b1f, bpk, b2f, nodesb);
    hipLaunchKernelGGL(k_gat1b, dim3(8, 32), dim3(256), 0, stream, nodesb, Wt, h1);
    hipLaunchKernelGGL(k_scores1, dim3(500), dim3(256), 0, stream, h1, gat1_as, gat1_ad, ssrc1, sdst1);
    hipLaunchKernelGGL(k_smax1, dim3(64), dim3(64), 0, stream, ssrc1, smax1);
    hipLaunchKernelGGL(k_attn1, dim3(63, 8, 8), dim3(64), 0, stream,
                       h1, ssrc1, sdst1, smax1, gat1_bi, g1);
    hipLaunchKernelGGL(k_h2, dim3(500), dim3(256), 0, stream,
                       g1, gat2_W, gat2_as, gat2_ad, h2, s2src, s2dst);
    hipLaunchKernelGGL(k_smax2, dim3(8), dim3(64), 0, stream, s2src, smax2);
    hipLaunchKernelGGL(k_attn2, dim3(63, 8), dim3(256), 0, stream,
                       h2, s2src, s2dst, smax2, gat2_bi, g2);
    hipLaunchKernelGGL(k_emb, dim3(8), dim3(256), 0, stream, g2, embp, dout);
    hipLaunchKernelGGL(k_fc, dim3(1), dim3(256), 0, stream,
                       embp, fc1_w, fc1_b, bnf_g, bnf_b, fc2_w, fc2_b, dout);
}

// Round 5
// 564.967 us; speedup vs baseline: 1.8465x; 1.1385x over previous
//
#include <hip/hip_runtime.h>
#include <hip/hip_bf16.h>
#include <math.h>

// ---------------- constants ----------------
#define TB 8
#define TT 64000
#define NFRAMES 251
#define NROWS (TB*NFRAMES)      // 2008
#define MPAD 2048
#define NBINS 513
#define NBPAD 576
#define NNODE 250
#define NODE_DIM 4116
#define KPAD 4128

typedef __attribute__((ext_vector_type(8))) short short8;
typedef __attribute__((ext_vector_type(4))) float floatx4;

static __device__ __forceinline__ unsigned short f2bf(float x) {
    __hip_bfloat16 h = __float2bfloat16(x);
    return *(unsigned short*)&h;
}
static __device__ __forceinline__ float bf2f(unsigned short u) {
    __hip_bfloat16 h = *(__hip_bfloat16*)&u;
    return __bfloat162float(h);
}

// ---------------- small prep kernels ----------------

__global__ void k_fold(const float* __restrict__ c1w, const float* __restrict__ c1b,
                       const float* __restrict__ g1bn, const float* __restrict__ b1bn,
                       const float* __restrict__ c2w, const float* __restrict__ c2b,
                       const float* __restrict__ g2bn, const float* __restrict__ b2bn,
                       float* __restrict__ w1f, float* __restrict__ b1f,
                       float* __restrict__ w2f, float* __restrict__ b2f) {
    int idx = blockIdx.x * 256 + threadIdx.x;
    float inv = rsqrtf(1.0f + 1e-5f);
    if (idx < 9216) {
        int co = idx / 288;
        w2f[idx] = c2w[idx] * (g2bn[co] * inv);
    } else if (idx < 9216 + 288) {
        int r = idx - 9216;
        w1f[r] = c1w[r] * (g1bn[r / 9] * inv);
    } else if (idx < 9216 + 288 + 32) {
        int c = idx - 9504;
        b1f[c] = c1b[c] * (g1bn[c] * inv) + b1bn[c];
    } else if (idx < 9216 + 288 + 64) {
        int c = idx - 9536;
        b2f[c] = c2b[c] * (g2bn[c] * inv) + b2bn[c];
    }
}

// pack conv2 weights into MFMA B-fragment order, bf16.
__global__ void k_pack(const float* __restrict__ w2f, unsigned short* __restrict__ Bp) {
    int idx = blockIdx.x * 256 + threadIdx.x;
    if (idx >= 9216) return;
    int j = idx & 7, lane = (idx >> 3) & 63, ct = (idx >> 9) & 1, s = idx >> 10;
    int co = ct * 16 + (lane & 15);
    int ci = (lane >> 4) * 8 + j;
    Bp[idx] = f2bf(w2f[co * 288 + ci * 9 + s]);
}

// transpose gat1_W [4116x512] f32 -> Wt [512][KPAD] bf16 (pad rows zero)
__global__ __launch_bounds__(256) void k_wt(const float* __restrict__ W,
                                            unsigned short* __restrict__ Wt) {
    __shared__ unsigned short tile[64][65];
    int kt = blockIdx.x, nt = blockIdx.y;
    int tid = threadIdx.x;
    for (int idx = tid; idx < 4096; idx += 256) {
        int r = idx >> 6, c = idx & 63;
        int k = kt * 64 + r;
        float v = (k < NODE_DIM) ? W[k * 512 + nt * 64 + c] : 0.f;
        tile[r][c] = f2bf(v);
    }
    __syncthreads();
    for (int idx = tid; idx < 4096; idx += 256) {
        int nl = idx >> 6, kl = idx & 63;
        int k = kt * 64 + kl;
        if (k < KPAD)
            Wt[(size_t)(nt * 64 + nl) * KPAD + k] = tile[kl][nl];
    }
}

// wbar[m][c] = 0.25 * sum_{d=0..3} sinc_w[c][m-d]  (m in 0..1026)
__global__ void k_wbar(const float* __restrict__ sw, float* __restrict__ wbar) {
    int idx = blockIdx.x * 256 + threadIdx.x;
    if (idx >= 1027 * 20) return;
    int m = idx / 20, c = idx % 20;
    float s = 0.f;
    #pragma unroll
    for (int d = 0; d < 4; d++) {
        int k = m - d;
        if (k >= 0 && k < 1024) s += sw[c * 1024 + k];
    }
    wbar[idx] = 0.25f * s;
}

// DFT basis, bf16 hi/lo split; rows [NBINS..NBPAD) zero
__global__ void k_basis_bf(unsigned short* __restrict__ ch, unsigned short* __restrict__ cl,
                           unsigned short* __restrict__ sh, unsigned short* __restrict__ sl) {
    int idx = blockIdx.x * 256 + threadIdx.x;
    if (idx >= NBPAD * 1024) return;
    int k = idx >> 10, n = idx & 1023;
    float s = 0.f, c = 0.f;
    if (k < NBINS) {
        int mm = (k * n) & 1023;
        sincospif((float)mm * (1.0f / 512.0f), &s, &c);
    }
    unsigned short chv = f2bf(c), shv = f2bf(s);
    ch[idx] = chv; cl[idx] = f2bf(c - bf2f(chv));
    sh[idx] = shv; sl[idx] = f2bf(s - bf2f(shv));
}

// frames (reflect-padded) -> bf16 hi/lo, rows [NROWS..MPAD) zero
__global__ void k_frames_bf(const float* __restrict__ x,
                            unsigned short* __restrict__ fh, unsigned short* __restrict__ fl) {
    int idx = blockIdx.x * 256 + threadIdx.x;
    if (idx >= MPAD * 1024) return;
    int m = idx >> 10, n = idx & 1023;
    float v = 0.f;
    if (m < NROWS) {
        int b = m / NFRAMES, i = m - b * NFRAMES;
        int j = i * 256 + n - 512;
        if (j < 0) j = -j;
        if (j >= TT) j = 2 * TT - 2 - j;
        v = x[b * TT + j];
    }
    unsigned short h = f2bf(v);
    fh[idx] = h;
    fl[idx] = f2bf(v - bf2f(h));
}

// sinc features -> nodesb[b][u][0..19] (bf16)
__global__ __launch_bounds__(64) void k_sinc(const float* __restrict__ x,
                                             const float* __restrict__ wbar,
                                             unsigned short* __restrict__ nodesb) {
    int u = blockIdx.x, b = blockIdx.y;
    int c = threadIdx.x;
    if (c >= 20) return;
    const float* xb = x + b * TT;
    int base = 4 * u - 512;
    float acc = 0.f;
    for (int m = 0; m < 1027; m++) {
        int g = base + m;
        float xv = (g >= 0) ? xb[g] : 0.f;
        acc = fmaf(wbar[m * 20 + c], xv, acc);
    }
    nodesb[(size_t)(b * NNODE + u) * KPAD + c] = f2bf(acc);
}

// ---------------- DFT via bf16 MFMA with hi/lo split ----------------
// S0[b][bin][i] = log(|rfft|+1e-9); x*c ~= xh*ch + xh*cl + xl*ch
__global__ __launch_bounds__(256) void k_dft_mfma(const unsigned short* __restrict__ fh,
                                                  const unsigned short* __restrict__ fl,
                                                  const unsigned short* __restrict__ ch,
                                                  const unsigned short* __restrict__ cl,
                                                  const unsigned short* __restrict__ sh,
                                                  const unsigned short* __restrict__ sl,
                                                  float* __restrict__ S0) {
    __shared__ __align__(16) unsigned short Ah[64 * 40];
    __shared__ __align__(16) unsigned short Al[64 * 40];
    __shared__ __align__(16) unsigned short Bch[64 * 40];
    __shared__ __align__(16) unsigned short Bcl[64 * 40];
    __shared__ __align__(16) unsigned short Bsh[64 * 40];
    __shared__ __align__(16) unsigned short Bsl[64 * 40];
    int tid = threadIdx.x;
    int N0 = blockIdx.x * 64, M0 = blockIdx.y * 64;
    int sr = tid >> 2, sc = (tid & 3) * 8;
    size_t aoff = (size_t)(M0 + sr) * 1024 + sc;
    size_t boff = (size_t)(N0 + sr) * 1024 + sc;
    int w = tid >> 6, lane = tid & 63;
    int q = lane >> 4, col = lane & 15;
    int mb = (w >> 1) * 32, nb = (w & 1) * 32;
    floatx4 aR[2][2], aI[2][2];
    #pragma unroll
    for (int mi = 0; mi < 2; mi++)
        #pragma unroll
        for (int ni = 0; ni < 2; ni++) {
            aR[mi][ni] = (floatx4){0.f, 0.f, 0.f, 0.f};
            aI[mi][ni] = (floatx4){0.f, 0.f, 0.f, 0.f};
        }

    for (int K0 = 0; K0 < 1024; K0 += 32) {
        *(short8*)&Ah[sr * 40 + sc]  = *(const short8*)(fh + aoff + K0);
        *(short8*)&Al[sr * 40 + sc]  = *(const short8*)(fl + aoff + K0);
        *(short8*)&Bch[sr * 40 + sc] = *(const short8*)(ch + boff + K0);
        *(short8*)&Bcl[sr * 40 + sc] = *(const short8*)(cl + boff + K0);
        *(short8*)&Bsh[sr * 40 + sc] = *(const short8*)(sh + boff + K0);
        *(short8*)&Bsl[sr * 40 + sc] = *(const short8*)(sl + boff + K0);
        __syncthreads();
        short8 ahv[2], alv[2], chv[2], clv[2], shv[2], slv[2];
        #pragma unroll
        for (int mi = 0; mi < 2; mi++) {
            ahv[mi] = *(const short8*)&Ah[(mb + mi * 16 + col) * 40 + q * 8];
            alv[mi] = *(const short8*)&Al[(mb + mi * 16 + col) * 40 + q * 8];
        }
        #pragma unroll
        for (int ni = 0; ni < 2; ni++) {
            chv[ni] = *(const short8*)&Bch[(nb + ni * 16 + col) * 40 + q * 8];
            clv[ni] = *(const short8*)&Bcl[(nb + ni * 16 + col) * 40 + q * 8];
            shv[ni] = *(const short8*)&Bsh[(nb + ni * 16 + col) * 40 + q * 8];
            slv[ni] = *(const short8*)&Bsl[(nb + ni * 16 + col) * 40 + q * 8];
        }
        #pragma unroll
        for (int mi = 0; mi < 2; mi++)
            #pragma unroll
            for (int ni = 0; ni < 2; ni++) {
                aR[mi][ni] = __builtin_amdgcn_mfma_f32_16x16x32_bf16(ahv[mi], chv[ni], aR[mi][ni], 0, 0, 0);
                aR[mi][ni] = __builtin_amdgcn_mfma_f32_16x16x32_bf16(ahv[mi], clv[ni], aR[mi][ni], 0, 0, 0);
                aR[mi][ni] = __builtin_amdgcn_mfma_f32_16x16x32_bf16(alv[mi], chv[ni], aR[mi][ni], 0, 0, 0);
                aI[mi][ni] = __builtin_amdgcn_mfma_f32_16x16x32_bf16(ahv[mi], shv[ni], aI[mi][ni], 0, 0, 0);
                aI[mi][ni] = __builtin_amdgcn_mfma_f32_16x16x32_bf16(ahv[mi], slv[ni], aI[mi][ni], 0, 0, 0);
                aI[mi][ni] = __builtin_amdgcn_mfma_f32_16x16x32_bf16(alv[mi], shv[ni], aI[mi][ni], 0, 0, 0);
            }
        __syncthreads();
    }
    #pragma unroll
    for (int mi = 0; mi < 2; mi++)
        #pragma unroll
        for (int ni = 0; ni < 2; ni++)
            #pragma unroll
            for (int rr = 0; rr < 4; rr++) {
                int m = M0 + mb + mi * 16 + q * 4 + rr;
                int bin = N0 + nb + ni * 16 + col;
                if (m < NROWS && bin < NBINS) {
                    float re = aR[mi][ni][rr], im = aI[mi][ni][rr];
                    int b = m / NFRAMES, i = m - b * NFRAMES;
                    S0[(b * NBINS + bin) * NFRAMES + i] =
                        logf(sqrtf(fmaf(re, re, im * im)) + 1e-9f);
                }
            }
}

// ---------------- fused conv1(f32 VALU) -> conv2 (bf16 MFMA) -> maxpool -> nodesb ----------------
__global__ __launch_bounds__(256) void k_conv_mfma(const float* __restrict__ S0,
                                                   const float* __restrict__ w1f,
                                                   const float* __restrict__ b1f,
                                                   const unsigned short* __restrict__ Bp,
                                                   const float* __restrict__ b2f,
                                                   unsigned short* __restrict__ nodesb) {
    __shared__ __align__(16) float s0t[20][21];
    __shared__ __align__(16) unsigned short o1bf[18 * 18 * 32];  // [lf][lt][ci]
    __shared__ __align__(16) unsigned short BpL[9216];
    __shared__ float w1s[288];
    __shared__ float b1s[32];
    __shared__ float b2s[32];
    int tid = threadIdx.x;
    int b = blockIdx.z;
    int F0 = blockIdx.y * 8;
    int T0 = blockIdx.x * 8;

    for (int idx = tid; idx < 400; idx += 256) {
        int i = idx / 20, j = idx % 20;
        int fr = 2 * F0 - 2 + i, tc = 2 * T0 - 2 + j;
        float v = 0.f;
        if (fr >= 0 && fr < 513 && tc >= 0 && tc < 251) v = S0[(b * 513 + fr) * 251 + tc];
        s0t[i][j] = v;
    }
    for (int idx = tid; idx < 4608; idx += 256)
        ((unsigned int*)BpL)[idx] = ((const unsigned int*)Bp)[idx];
    for (int idx = tid; idx < 288; idx += 256) w1s[idx] = w1f[idx];
    if (tid < 32) { b1s[tid] = b1f[tid]; b2s[tid] = b2f[tid]; }
    __syncthreads();

    for (int idx = tid; idx < 10368; idx += 256) {
        int ci = idx & 31, pos = idx >> 5;
        int lf = pos / 18, lt = pos - lf * 18;
        int r1 = 2 * F0 - 1 + lf, t1 = 2 * T0 - 1 + lt;
        float v = 0.f;
        if (r1 >= 0 && r1 < 513 && t1 >= 0 && t1 < 251) {
            float a = b1s[ci];
            const float* wp = &w1s[ci * 9];
            #pragma unroll
            for (int di = 0; di < 3; di++)
                #pragma unroll
                for (int dj = 0; dj < 3; dj++)
                    a = fmaf(s0t[lf + di][lt + dj], wp[di * 3 + dj], a);
            v = fmaxf(a, 0.f);
        }
        o1bf[pos * 32 + ci] = f2bf(v);
    }
    __syncthreads();

    int lane = tid & 63, w = tid >> 6;
    int q = lane >> 4, col = lane & 15;
    floatx4 acc[4][2];
    #pragma unroll
    for (int rt = 0; rt < 4; rt++)
        #pragma unroll
        for (int ct = 0; ct < 2; ct++)
            acc[rt][ct] = (floatx4){0.f, 0.f, 0.f, 0.f};

    #pragma unroll
    for (int s = 0; s < 9; s++) {
        const int di = s / 3, dj = s % 3;
        short8 bf0 = *(const short8*)&BpL[(s * 2 + 0) * 512 + lane * 8];
        short8 bf1 = *(const short8*)&BpL[(s * 2 + 1) * 512 + lane * 8];
        #pragma unroll
        for (int rt = 0; rt < 4; rt++) {
            int r = w * 4 + rt;
            short8 af = *(const short8*)&o1bf[(((r + di) * 18) + (col + dj)) * 32 + q * 8];
            acc[rt][0] = __builtin_amdgcn_mfma_f32_16x16x32_bf16(af, bf0, acc[rt][0], 0, 0, 0);
            acc[rt][1] = __builtin_amdgcn_mfma_f32_16x16x32_bf16(af, bf1, acc[rt][1], 0, 0, 0);
        }
    }

    #pragma unroll
    for (int ct = 0; ct < 2; ct++) {
        int co = ct * 16 + col;
        float bb = b2s[co];
        #pragma unroll
        for (int fp2 = 0; fp2 < 2; fp2++) {
            #pragma unroll
            for (int tc2 = 0; tc2 < 2; tc2++) {
                float m0 = fmaxf(fmaxf(acc[2 * fp2][ct][2 * tc2], acc[2 * fp2][ct][2 * tc2 + 1]),
                                 fmaxf(acc[2 * fp2 + 1][ct][2 * tc2], acc[2 * fp2 + 1][ct][2 * tc2 + 1]));
                float v = fmaxf(m0 + bb, 0.f);
                int tp = T0 + 2 * q + tc2;
                if (tp < 125) {
                    int fg = F0 + 2 * w + fp2;
                    int node = 2 * tp + (co >= 16 ? 1 : 0);
                    nodesb[(size_t)(b * NNODE + node) * KPAD + 20 + (co & 15) * 256 + fg] = f2bf(v);
                }
            }
        }
    }
}

// ---------------- GAT1 GEMM (bf16 MFMA): h1[2000x512] = nodesb @ Wt^T ----------------
__global__ __launch_bounds__(256) void k_gat1b(const unsigned short* __restrict__ A,
                                               const unsigned short* __restrict__ Bt,
                                               float* __restrict__ C) {
    __shared__ __align__(16) unsigned short As[64 * 40];
    __shared__ __align__(16) unsigned short Bs[64 * 40];
    int tid = threadIdx.x;
    int N0 = blockIdx.x * 64, M0 = blockIdx.y * 64;
    int sr = tid >> 2, sc = (tid & 3) * 8;
    int w = tid >> 6, lane = tid & 63;
    int q = lane >> 4, col = lane & 15;
    int mb = (w >> 1) * 32, nb = (w & 1) * 32;
    floatx4 acc[2][2];
    acc[0][0] = acc[0][1] = acc[1][0] = acc[1][1] = (floatx4){0.f, 0.f, 0.f, 0.f};
    short8 z8 = {0, 0, 0, 0, 0, 0, 0, 0};
    int mA = M0 + sr;
    bool mv = mA < 2000;
    const unsigned short* pa = A + (size_t)mA * KPAD + sc;
    const unsigned short* pb = Bt + (size_t)(N0 + sr) * KPAD + sc;

    for (int K0 = 0; K0 < KPAD; K0 += 32) {
        short8 va = mv ? *(const short8*)(pa + K0) : z8;
        short8 vb = *(const short8*)(pb + K0);
        *(short8*)&As[sr * 40 + sc] = va;
        *(short8*)&Bs[sr * 40 + sc] = vb;
        __syncthreads();
        short8 a0 = *(const short8*)&As[(mb + col) * 40 + q * 8];
        short8 a1 = *(const short8*)&As[(mb + 16 + col) * 40 + q * 8];
        short8 b0 = *(const short8*)&Bs[(nb + col) * 40 + q * 8];
        short8 b1 = *(const short8*)&Bs[(nb + 16 + col) * 40 + q * 8];
        acc[0][0] = __builtin_amdgcn_mfma_f32_16x16x32_bf16(a0, b0, acc[0][0], 0, 0, 0);
        acc[0][1] = __builtin_amdgcn_mfma_f32_16x16x32_bf16(a0, b1, acc[0][1], 0, 0, 0);
        acc[1][0] = __builtin_amdgcn_mfma_f32_16x16x32_bf16(a1, b0, acc[1][0], 0, 0, 0);
        acc[1][1] = __builtin_amdgcn_mfma_f32_16x16x32_bf16(a1, b1, acc[1][1], 0, 0, 0);
        __syncthreads();
    }
    #pragma unroll
    for (int mi = 0; mi < 2; mi++)
        #pragma unroll
        for (int ni = 0; ni < 2; ni++)
            #pragma unroll
            for (int rr = 0; rr < 4; rr++) {
                int m = M0 + mb + mi * 16 + q * 4 + rr;
                if (m < 2000)
                    C[m * 512 + N0 + nb + ni * 16 + col] = acc[mi][ni][rr];
            }
}

// ---------------- GAT1 scores / max / attention ----------------
__global__ __launch_bounds__(256) void k_scores1(const float* __restrict__ h1,
                                                 const float* __restrict__ asrc,
                                                 const float* __restrict__ adst,
                                                 float* __restrict__ ssrc,
                                                 float* __restrict__ sdst) {
    int row = blockIdx.x * 4 + (threadIdx.x >> 6);
    int lane = threadIdx.x & 63;
    if (row >= 2000) return;
    for (int h = 0; h < 8; h++) {
        float v = h1[row * 512 + h * 64 + lane];
        float ps = v * asrc[h * 64 + lane];
        float pd = v * adst[h * 64 + lane];
        for (int off = 32; off > 0; off >>= 1) {
            ps += __shfl_down(ps, off);
            pd += __shfl_down(pd, off);
        }
        if (lane == 0) { ssrc[row * 8 + h] = ps; sdst[row * 8 + h] = pd; }
    }
}

__global__ __launch_bounds__(64) void k_smax1(const float* __restrict__ ssrc,
                                              float* __restrict__ smax) {
    int bh = blockIdx.x;
    int b = bh >> 3, h = bh & 7;
    int lane = threadIdx.x;
    float m = -1e30f;
    for (int n = lane; n < NNODE; n += 64) m = fmaxf(m, ssrc[(b * NNODE + n) * 8 + h]);
    for (int off = 32; off > 0; off >>= 1) m = fmaxf(m, __shfl_down(m, off));
    if (lane == 0) smax[bh] = m;
}

__global__ __launch_bounds__(64) void k_attn1(const float* __restrict__ h1,
                                              const float* __restrict__ ssrc,
                                              const float* __restrict__ sdst,
                                              const float* __restrict__ smax,
                                              const float* __restrict__ bias,
                                              float* __restrict__ g1) {
    int it = blockIdx.x, h = blockIdx.y, b = blockIdx.z;
    int f = threadIdx.x;
    __shared__ float ss[NNODE];
    for (int n = f; n < NNODE; n += 64) ss[n] = ssrc[(b * NNODE + n) * 8 + h];
    __syncthreads();
    float mxs = smax[b * 8 + h];
    int i0 = it * 4;
    float d[4], mx[4], acc[4] = {0.f, 0.f, 0.f, 0.f}, den[4] = {0.f, 0.f, 0.f, 0.f};
    #pragma unroll
    for (int ii = 0; ii < 4; ii++) {
        int i = i0 + ii;
        d[ii] = (i < NNODE) ? sdst[(b * NNODE + i) * 8 + h] : 0.f;
        float e = d[ii] + mxs;
        mx[ii] = e > 0.f ? e : 0.2f * e;
    }
    for (int j = 0; j < NNODE; j++) {
        float sj = ss[j];
        float hv = h1[(b * NNODE + j) * 512 + h * 64 + f];
        #pragma unroll
        for (int ii = 0; ii < 4; ii++) {
            float e = d[ii] + sj;
            e = e > 0.f ? e : 0.2f * e;
            float w = __expf(e - mx[ii]);
            den[ii] += w;
            acc[ii] = fmaf(w, hv, acc[ii]);
        }
    }
    float bb = bias[h * 64 + f];
    #pragma unroll
    for (int ii = 0; ii < 4; ii++) {
        int i = i0 + ii;
        if (i < NNODE)
            g1[(b * NNODE + i) * 512 + h * 64 + f] = fmaxf(acc[ii] / den[ii] + bb, 0.f);
    }
}

// ---------------- GAT2 ----------------
__global__ __launch_bounds__(256) void k_h2(const float* __restrict__ g1,
                                            const float* __restrict__ W2,
                                            const float* __restrict__ a2src,
                                            const float* __restrict__ a2dst,
                                            float* __restrict__ h2,
                                            float* __restrict__ s2src,
                                            float* __restrict__ s2dst) {
    int row = blockIdx.x * 4 + (threadIdx.x >> 6);
    if (row >= 2000) return;
    int lane = threadIdx.x & 63;
    int o = lane & 31, half = lane >> 5;
    const float* gr = &g1[row * 512 + half * 256];
    float acc = 0.f;
    for (int k = 0; k < 256; k++) acc = fmaf(gr[k], W2[(half * 256 + k) * 32 + o], acc);
    acc += __shfl_down(acc, 32);
    float ps = acc * a2src[o], pd = acc * a2dst[o];
    for (int off = 16; off > 0; off >>= 1) {
        ps += __shfl_down(ps, off, 32);
        pd += __shfl_down(pd, off, 32);
    }
    if (lane == 0) { s2src[row] = ps; s2dst[row] = pd; }
    if (lane < 32) h2[row * 32 + o] = acc;
}

__global__ __launch_bounds__(64) void k_smax2(const float* __restrict__ s2src,
                                              float* __restrict__ smax2) {
    int b = blockIdx.x, lane = threadIdx.x;
    float m = -1e30f;
    for (int n = lane; n < NNODE; n += 64) m = fmaxf(m, s2src[b * NNODE + n]);
    for (int off = 32; off > 0; off >>= 1) m = fmaxf(m, __shfl_down(m, off));
    if (lane == 0) smax2[b] = m;
}

__global__ __launch_bounds__(256) void k_attn2(const float* __restrict__ h2,
                                               const float* __restrict__ s2src,
                                               const float* __restrict__ s2dst,
                                               const float* __restrict__ smax2,
                                               const float* __restrict__ bias2,
                                               float* __restrict__ g2) {
    int it = blockIdx.x, b = blockIdx.y;
    int tid = threadIdx.x, lane = tid & 63, wv = tid >> 6;
    __shared__ float ss[NNODE];
    for (int n = tid; n < NNODE; n += 256) ss[n] = s2src[b * NNODE + n];
    __syncthreads();
    int i = it * 4 + wv;
    if (i >= NNODE) return;
    int f = lane & 31, half = lane >> 5;
    float d = s2dst[b * NNODE + i];
    float e0 = d + smax2[b];
    float mx = e0 > 0.f ? e0 : 0.2f * e0;
    float acc = 0.f, den = 0.f;
    for (int j = half; j < NNODE; j += 2) {
        float e = d + ss[j];
        e = e > 0.f ? e : 0.2f * e;
        float w = __expf(e - mx);
        den += w;
        acc = fmaf(w, h2[(b * NNODE + j) * 32 + f], acc);
    }
    acc += __shfl_down(acc, 32);
    den += __shfl_down(den, 32);
    if (lane < 32) g2[(b * NNODE + i) * 32 + f] = acc / den + bias2[f];
}

__global__ __launch_bounds__(256) void k_emb(const float* __restrict__ g2,
                                             float* __restrict__ emb,
                                             float* __restrict__ dout) {
    int b = blockIdx.x;
    int f = threadIdx.x & 31, g = threadIdx.x >> 5;
    __shared__ float red[8][32];
    float s = 0.f;
    for (int i = g; i < NNODE; i += 8) s += g2[(b * NNODE + i) * 32 + f];
    red[g][f] = s;
    __syncthreads();
    if (threadIdx.x < 32) {
        float t = 0.f;
        #pragma unroll
        for (int gg = 0; gg < 8; gg++) t += red[gg][f];
        t *= (1.0f / 250.0f);
        emb[b * 32 + f] = t;
        dout[16 + b * 32 + f] = t;
    }
}

__global__ __launch_bounds__(256) void k_fc(const float* __restrict__ emb,
                                            const float* __restrict__ fc1w,
                                            const float* __restrict__ fc1b,
                                            const float* __restrict__ bnfg,
                                            const float* __restrict__ bnfb,
                                            const float* __restrict__ fc2w,
                                            const float* __restrict__ fc2b,
                                            float* __restrict__ dout) {
    __shared__ float es[256];
    __shared__ float zs[1024];
    int tid = threadIdx.x;
    es[tid] = emb[tid];
    __syncthreads();
    float inv = rsqrtf(1.0f + 1e-5f);
    #pragma unroll
    for (int rep = 0; rep < 4; rep++) {
        int idx = tid + rep * 256;
        int b = idx >> 7, j = idx & 127;
        float a = fc1b[j];
        #pragma unroll
        for (int k = 0; k < 32; k++) a = fmaf(es[b * 32 + k], fc1w[k * 128 + j], a);
        a = a * (bnfg[j] * inv) + bnfb[j];
        zs[idx] = fmaxf(a, 0.f);
    }
    __syncthreads();
    if (tid < 16) {
        int b = tid >> 1, o = tid & 1;
        float a = fc2b[o];
        for (int k = 0; k < 128; k++) a = fmaf(zs[b * 128 + k], fc2w[k * 2 + o], a);
        dout[b * 2 + o] = a;
    }
}

// ---------------- launch ----------------
extern "C" void kernel_launch(void* const* d_in, const int* in_sizes, int n_in,
                              void* d_out, int out_size, void* d_ws, size_t ws_size,
                              hipStream_t stream) {
    (void)in_sizes; (void)n_in; (void)out_size; (void)ws_size;
    const float* x       = (const float*)d_in[0];
    const float* sinc_w  = (const float*)d_in[1];
    const float* conv1_w = (const float*)d_in[2];
    const float* conv1_b = (const float*)d_in[3];
    const float* bn1_g   = (const float*)d_in[4];
    const float* bn1_b   = (const float*)d_in[5];
    const float* conv2_w = (const float*)d_in[6];
    const float* conv2_b = (const float*)d_in[7];
    const float* bn2_g   = (const float*)d_in[8];
    const float* bn2_b   = (const float*)d_in[9];
    const float* gat1_W  = (const float*)d_in[10];
    const float* gat1_as = (const float*)d_in[11];
    const float* gat1_ad = (const float*)d_in[12];
    const float* gat1_bi = (const float*)d_in[13];
    const float* gat2_W  = (const float*)d_in[14];
    const float* gat2_as = (const float*)d_in[15];
    const float* gat2_ad = (const float*)d_in[16];
    const float* gat2_bi = (const float*)d_in[17];
    const float* fc1_w   = (const float*)d_in[18];
    const float* fc1_b   = (const float*)d_in[19];
    const float* bnf_g   = (const float*)d_in[20];
    const float* bnf_b   = (const float*)d_in[21];
    const float* fc2_w   = (const float*)d_in[22];
    const float* fc2_b   = (const float*)d_in[23];
    float* dout = (float*)d_out;

    float* ws = (float*)d_ws;
    unsigned short* fh  = (unsigned short*)ws;                 // 2048*1024 ush
    unsigned short* fl  = fh + (size_t)MPAD * 1024;            // 2048*1024 ush
    unsigned short* bch = fl + (size_t)MPAD * 1024;            // 576*1024 ush
    unsigned short* bcl = bch + (size_t)NBPAD * 1024;
    unsigned short* bsh = bcl + (size_t)NBPAD * 1024;
    unsigned short* bsl = bsh + (size_t)NBPAD * 1024;
    float* S0   = (float*)(bsl + (size_t)NBPAD * 1024);        // 1,030,104 f
    float* wbar = S0 + 1030104;                                // 20,540
    float* w1f  = wbar + 20540;                                // 288
    float* b1f  = w1f + 288;                                   // 32
    float* w2f  = b1f + 32;                                    // 9,216
    float* b2f  = w2f + 9216;                                  // 32
    unsigned short* bpk = (unsigned short*)(b2f + 32);         // 9,216 ush = 4,608 f
    unsigned short* Wt  = (unsigned short*)(b2f + 32 + 4608);  // 512*KPAD ush
    unsigned short* nodesb = Wt + (size_t)512 * KPAD;          // 2000*KPAD ush
    float* h1    = (float*)(nodesb + (size_t)2000 * KPAD);     // 1,024,000
    float* ssrc1 = h1 + 1024000;
    float* sdst1 = ssrc1 + 16000;
    float* smax1 = sdst1 + 16000;
    float* g1    = smax1 + 64;
    float* h2    = g1 + 1024000;
    float* s2src = h2 + 64000;
    float* s2dst = s2src + 2000;
    float* smax2 = s2dst + 2000;
    float* g2    = smax2 + 8;
    float* embp  = g2 + 64000;

    hipLaunchKernelGGL(k_fold, dim3(38), dim3(256), 0, stream,
                       conv1_w, conv1_b, bn1_g, bn1_b, conv2_w, conv2_b, bn2_g, bn2_b,
                       w1f, b1f, w2f, b2f);
    hipLaunchKernelGGL(k_pack, dim3(36), dim3(256), 0, stream, w2f, bpk);
    hipLaunchKernelGGL(k_wt, dim3(65, 8), dim3(256), 0, stream, gat1_W, Wt);
    hipLaunchKernelGGL(k_wbar, dim3((1027 * 20 + 255) / 256), dim3(256), 0, stream, sinc_w, wbar);
    hipLaunchKernelGGL(k_basis_bf, dim3(NBPAD * 1024 / 256), dim3(256), 0, stream,
                       bch, bcl, bsh, bsl);
    hipLaunchKernelGGL(k_frames_bf, dim3(MPAD * 1024 / 256), dim3(256), 0, stream, x, fh, fl);
    hipLaunchKernelGGL(k_dft_mfma, dim3(9, 32), dim3(256), 0, stream,
                       fh, fl, bch, bcl, bsh, bsl, S0);
    hipLaunchKernelGGL(k_sinc, dim3(250, 8), dim3(64), 0, stream, x, wbar, nodesb);
    hipLaunchKernelGGL(k_conv_mfma, dim3(16, 32, 8), dim3(256), 0, stream,
                       S0, w1f, b1f, bpk, b2f, nodesb);
    hipLaunchKernelGGL(k_gat1b, dim3(8, 32), dim3(256), 0, stream, nodesb, Wt, h1);
    hipLaunchKernelGGL(k_scores1, dim3(500), dim3(256), 0, stream, h1, gat1_as, gat1_ad, ssrc1, sdst1);
    hipLaunchKernelGGL(k_smax1, dim3(64), dim3(64), 0, stream, ssrc1, smax1);
    hipLaunchKernelGGL(k_attn1, dim3(63, 8, 8), dim3(64), 0, stream,
                       h1, ssrc1, sdst1, smax1, gat1_bi, g1);
    hipLaunchKernelGGL(k_h2, dim3(500), dim3(256), 0, stream,
                       g1, gat2_W, gat2_as, gat2_ad, h2, s2src, s2dst);
    hipLaunchKernelGGL(k_smax2, dim3(8), dim3(64), 0, stream, s2src, smax2);
    hipLaunchKernelGGL(k_attn2, dim3(63, 8), dim3(256), 0, stream,
                       h2, s2src, s2dst, smax2, gat2_bi, g2);
    hipLaunchKernelGGL(k_emb, dim3(8), dim3(256), 0, stream, g2, embp, dout);
    hipLaunchKernelGGL(k_fc, dim3(1), dim3(256), 0, stream,
                       embp, fc1_w, fc1_b, bnf_g, bnf_b, fc2_w, fc2_b, dout);
}

// Round 6
// 550.411 us; speedup vs baseline: 1.8953x; 1.0264x over previous
//
#include <hip/hip_runtime.h>
#include <hip/hip_bf16.h>
#include <math.h>

// ---------------- constants ----------------
#define TB 8
#define TT 64000
#define NFRAMES 251
#define NROWS (TB*NFRAMES)      // 2008
#define MPAD 2048
#define NBINS 513
#define NBPAD 576
#define NNODE 250
#define NODE_DIM 4116
#define KPAD 4128

typedef __attribute__((ext_vector_type(8))) short short8;
typedef __attribute__((ext_vector_type(4))) float floatx4;

static __device__ __forceinline__ unsigned short f2bf(float x) {
    __hip_bfloat16 h = __float2bfloat16(x);
    return *(unsigned short*)&h;
}
static __device__ __forceinline__ float bf2f(unsigned short u) {
    __hip_bfloat16 h = *(__hip_bfloat16*)&u;
    return __bfloat162float(h);
}

// ---------------- small prep kernels ----------------

__global__ void k_fold(const float* __restrict__ c1w, const float* __restrict__ c1b,
                       const float* __restrict__ g1bn, const float* __restrict__ b1bn,
                       const float* __restrict__ c2w, const float* __restrict__ c2b,
                       const float* __restrict__ g2bn, const float* __restrict__ b2bn,
                       float* __restrict__ w1f, float* __restrict__ b1f,
                       float* __restrict__ w2f, float* __restrict__ b2f) {
    int idx = blockIdx.x * 256 + threadIdx.x;
    float inv = rsqrtf(1.0f + 1e-5f);
    if (idx < 9216) {
        int co = idx / 288;
        w2f[idx] = c2w[idx] * (g2bn[co] * inv);
    } else if (idx < 9216 + 288) {
        int r = idx - 9216;
        w1f[r] = c1w[r] * (g1bn[r / 9] * inv);
    } else if (idx < 9216 + 288 + 32) {
        int c = idx - 9504;
        b1f[c] = c1b[c] * (g1bn[c] * inv) + b1bn[c];
    } else if (idx < 9216 + 288 + 64) {
        int c = idx - 9536;
        b2f[c] = c2b[c] * (g2bn[c] * inv) + b2bn[c];
    }
}

// pack conv2 weights into MFMA B-fragment order, bf16.
__global__ void k_pack(const float* __restrict__ w2f, unsigned short* __restrict__ Bp) {
    int idx = blockIdx.x * 256 + threadIdx.x;
    if (idx >= 9216) return;
    int j = idx & 7, lane = (idx >> 3) & 63, ct = (idx >> 9) & 1, s = idx >> 10;
    int co = ct * 16 + (lane & 15);
    int ci = (lane >> 4) * 8 + j;
    Bp[idx] = f2bf(w2f[co * 288 + ci * 9 + s]);
}

// transpose gat1_W [4116x512] f32 -> Wt [512][KPAD] bf16 (pad rows zero)
__global__ __launch_bounds__(256) void k_wt(const float* __restrict__ W,
                                            unsigned short* __restrict__ Wt) {
    __shared__ unsigned short tile[64][65];
    int kt = blockIdx.x, nt = blockIdx.y;
    int tid = threadIdx.x;
    for (int idx = tid; idx < 4096; idx += 256) {
        int r = idx >> 6, c = idx & 63;
        int k = kt * 64 + r;
        float v = (k < NODE_DIM) ? W[k * 512 + nt * 64 + c] : 0.f;
        tile[r][c] = f2bf(v);
    }
    __syncthreads();
    for (int idx = tid; idx < 4096; idx += 256) {
        int nl = idx >> 6, kl = idx & 63;
        int k = kt * 64 + kl;
        if (k < KPAD)
            Wt[(size_t)(nt * 64 + nl) * KPAD + k] = tile[kl][nl];
    }
}

// wbar[m][c] = 0.25 * sum_{d=0..3} sinc_w[c][m-d]  (m in 0..1026)
__global__ void k_wbar(const float* __restrict__ sw, float* __restrict__ wbar) {
    int idx = blockIdx.x * 256 + threadIdx.x;
    if (idx >= 1027 * 20) return;
    int m = idx / 20, c = idx % 20;
    float s = 0.f;
    #pragma unroll
    for (int d = 0; d < 4; d++) {
        int k = m - d;
        if (k >= 0 && k < 1024) s += sw[c * 1024 + k];
    }
    wbar[idx] = 0.25f * s;
}

// DFT basis, bf16 hi/lo split; rows [NBINS..NBPAD) zero
__global__ void k_basis_bf(unsigned short* __restrict__ ch, unsigned short* __restrict__ cl,
                           unsigned short* __restrict__ sh, unsigned short* __restrict__ sl) {
    int idx = blockIdx.x * 256 + threadIdx.x;
    if (idx >= NBPAD * 1024) return;
    int k = idx >> 10, n = idx & 1023;
    float s = 0.f, c = 0.f;
    if (k < NBINS) {
        int mm = (k * n) & 1023;
        sincospif((float)mm * (1.0f / 512.0f), &s, &c);
    }
    unsigned short chv = f2bf(c), shv = f2bf(s);
    ch[idx] = chv; cl[idx] = f2bf(c - bf2f(chv));
    sh[idx] = shv; sl[idx] = f2bf(s - bf2f(shv));
}

// frames (reflect-padded) -> bf16 hi/lo, rows [NROWS..MPAD) zero
__global__ void k_frames_bf(const float* __restrict__ x,
                            unsigned short* __restrict__ fh, unsigned short* __restrict__ fl) {
    int idx = blockIdx.x * 256 + threadIdx.x;
    if (idx >= MPAD * 1024) return;
    int m = idx >> 10, n = idx & 1023;
    float v = 0.f;
    if (m < NROWS) {
        int b = m / NFRAMES, i = m - b * NFRAMES;
        int j = i * 256 + n - 512;
        if (j < 0) j = -j;
        if (j >= TT) j = 2 * TT - 2 - j;
        v = x[b * TT + j];
    }
    unsigned short h = f2bf(v);
    fh[idx] = h;
    fl[idx] = f2bf(v - bf2f(h));
}

// sinc features -> nodesb[b][u][0..19] (bf16)
__global__ __launch_bounds__(64) void k_sinc(const float* __restrict__ x,
                                             const float* __restrict__ wbar,
                                             unsigned short* __restrict__ nodesb) {
    int u = blockIdx.x, b = blockIdx.y;
    int c = threadIdx.x;
    if (c >= 20) return;
    const float* xb = x + b * TT;
    int base = 4 * u - 512;
    float acc = 0.f;
    for (int m = 0; m < 1027; m++) {
        int g = base + m;
        float xv = (g >= 0) ? xb[g] : 0.f;
        acc = fmaf(wbar[m * 20 + c], xv, acc);
    }
    nodesb[(size_t)(b * NNODE + u) * KPAD + c] = f2bf(acc);
}

// ---------------- DFT via bf16 MFMA with hi/lo split ----------------
__global__ __launch_bounds__(256) void k_dft_mfma(const unsigned short* __restrict__ fh,
                                                  const unsigned short* __restrict__ fl,
                                                  const unsigned short* __restrict__ ch,
                                                  const unsigned short* __restrict__ cl,
                                                  const unsigned short* __restrict__ sh,
                                                  const unsigned short* __restrict__ sl,
                                                  float* __restrict__ S0) {
    __shared__ __align__(16) unsigned short Ah[64 * 40];
    __shared__ __align__(16) unsigned short Al[64 * 40];
    __shared__ __align__(16) unsigned short Bch[64 * 40];
    __shared__ __align__(16) unsigned short Bcl[64 * 40];
    __shared__ __align__(16) unsigned short Bsh[64 * 40];
    __shared__ __align__(16) unsigned short Bsl[64 * 40];
    int tid = threadIdx.x;
    int N0 = blockIdx.x * 64, M0 = blockIdx.y * 64;
    int sr = tid >> 2, sc = (tid & 3) * 8;
    size_t aoff = (size_t)(M0 + sr) * 1024 + sc;
    size_t boff = (size_t)(N0 + sr) * 1024 + sc;
    int w = tid >> 6, lane = tid & 63;
    int q = lane >> 4, col = lane & 15;
    int mb = (w >> 1) * 32, nb = (w & 1) * 32;
    floatx4 aR[2][2], aI[2][2];
    #pragma unroll
    for (int mi = 0; mi < 2; mi++)
        #pragma unroll
        for (int ni = 0; ni < 2; ni++) {
            aR[mi][ni] = (floatx4){0.f, 0.f, 0.f, 0.f};
            aI[mi][ni] = (floatx4){0.f, 0.f, 0.f, 0.f};
        }

    for (int K0 = 0; K0 < 1024; K0 += 32) {
        *(short8*)&Ah[sr * 40 + sc]  = *(const short8*)(fh + aoff + K0);
        *(short8*)&Al[sr * 40 + sc]  = *(const short8*)(fl + aoff + K0);
        *(short8*)&Bch[sr * 40 + sc] = *(const short8*)(ch + boff + K0);
        *(short8*)&Bcl[sr * 40 + sc] = *(const short8*)(cl + boff + K0);
        *(short8*)&Bsh[sr * 40 + sc] = *(const short8*)(sh + boff + K0);
        *(short8*)&Bsl[sr * 40 + sc] = *(const short8*)(sl + boff + K0);
        __syncthreads();
        short8 ahv[2], alv[2], chv[2], clv[2], shv[2], slv[2];
        #pragma unroll
        for (int mi = 0; mi < 2; mi++) {
            ahv[mi] = *(const short8*)&Ah[(mb + mi * 16 + col) * 40 + q * 8];
            alv[mi] = *(const short8*)&Al[(mb + mi * 16 + col) * 40 + q * 8];
        }
        #pragma unroll
        for (int ni = 0; ni < 2; ni++) {
            chv[ni] = *(const short8*)&Bch[(nb + ni * 16 + col) * 40 + q * 8];
            clv[ni] = *(const short8*)&Bcl[(nb + ni * 16 + col) * 40 + q * 8];
            shv[ni] = *(const short8*)&Bsh[(nb + ni * 16 + col) * 40 + q * 8];
            slv[ni] = *(const short8*)&Bsl[(nb + ni * 16 + col) * 40 + q * 8];
        }
        #pragma unroll
        for (int mi = 0; mi < 2; mi++)
            #pragma unroll
            for (int ni = 0; ni < 2; ni++) {
                aR[mi][ni] = __builtin_amdgcn_mfma_f32_16x16x32_bf16(ahv[mi], chv[ni], aR[mi][ni], 0, 0, 0);
                aR[mi][ni] = __builtin_amdgcn_mfma_f32_16x16x32_bf16(ahv[mi], clv[ni], aR[mi][ni], 0, 0, 0);
                aR[mi][ni] = __builtin_amdgcn_mfma_f32_16x16x32_bf16(alv[mi], chv[ni], aR[mi][ni], 0, 0, 0);
                aI[mi][ni] = __builtin_amdgcn_mfma_f32_16x16x32_bf16(ahv[mi], shv[ni], aI[mi][ni], 0, 0, 0);
                aI[mi][ni] = __builtin_amdgcn_mfma_f32_16x16x32_bf16(ahv[mi], slv[ni], aI[mi][ni], 0, 0, 0);
                aI[mi][ni] = __builtin_amdgcn_mfma_f32_16x16x32_bf16(alv[mi], shv[ni], aI[mi][ni], 0, 0, 0);
            }
        __syncthreads();
    }
    #pragma unroll
    for (int mi = 0; mi < 2; mi++)
        #pragma unroll
        for (int ni = 0; ni < 2; ni++)
            #pragma unroll
            for (int rr = 0; rr < 4; rr++) {
                int m = M0 + mb + mi * 16 + q * 4 + rr;
                int bin = N0 + nb + ni * 16 + col;
                if (m < NROWS && bin < NBINS) {
                    float re = aR[mi][ni][rr], im = aI[mi][ni][rr];
                    int b = m / NFRAMES, i = m - b * NFRAMES;
                    S0[(b * NBINS + bin) * NFRAMES + i] =
                        logf(sqrtf(fmaf(re, re, im * im)) + 1e-9f);
                }
            }
}

// ---------------- conv1+BN+ReLU -> o1g[b][513][251][32] bf16 channels-last ----------------
__global__ __launch_bounds__(256) void k_conv1(const float* __restrict__ S0,
                                               const float* __restrict__ w1f,
                                               const float* __restrict__ b1f,
                                               unsigned short* __restrict__ o1g) {
    __shared__ float w1s[288];
    __shared__ float b1s[32];
    int tid = threadIdx.x;
    for (int i = tid; i < 288; i += 256) w1s[i] = w1f[i];
    if (tid < 32) b1s[tid] = b1f[tid];
    __syncthreads();
    int r = blockIdx.x;      // 0..512
    int b = blockIdx.y;      // 0..7
    int t = tid;
    if (t >= 251) return;
    float sv[9];
    #pragma unroll
    for (int di = 0; di < 3; di++) {
        int rr = r - 1 + di;
        #pragma unroll
        for (int dj = 0; dj < 3; dj++) {
            int tt = t - 1 + dj;
            float v = 0.f;
            if (rr >= 0 && rr < 513 && tt >= 0 && tt < 251)
                v = S0[(b * 513 + rr) * 251 + tt];
            sv[di * 3 + dj] = v;
        }
    }
    unsigned short ov[32];
    #pragma unroll
    for (int ci = 0; ci < 32; ci++) {
        float a = b1s[ci];
        const float* wp = &w1s[ci * 9];
        #pragma unroll
        for (int k = 0; k < 9; k++) a = fmaf(sv[k], wp[k], a);
        ov[ci] = f2bf(fmaxf(a, 0.f));
    }
    unsigned short* dst = o1g + ((size_t)(b * 513 + r) * 251 + t) * 32;
    #pragma unroll
    for (int i = 0; i < 4; i++)
        *(short8*)(dst + i * 8) = *(const short8*)&ov[i * 8];
}

// ---------------- conv2 (bf16 MFMA) + maxpool -> nodesb ----------------
__global__ __launch_bounds__(256) void k_conv2m(const unsigned short* __restrict__ o1g,
                                                const unsigned short* __restrict__ Bp,
                                                const float* __restrict__ b2f,
                                                unsigned short* __restrict__ nodesb) {
    __shared__ __align__(16) unsigned short o1s[18 * 18 * 32];  // 20.7 KB
    __shared__ float b2s[32];
    int tid = threadIdx.x;
    int b = blockIdx.z;
    int F0 = blockIdx.y * 8;
    int T0 = blockIdx.x * 8;
    if (tid < 32) b2s[tid] = b2f[tid];
    short8 z8 = {0, 0, 0, 0, 0, 0, 0, 0};
    for (int c = tid; c < 1296; c += 256) {
        int o = c & 3, pos = c >> 2;
        int lf = pos / 18, lt = pos - lf * 18;
        int r1 = 2 * F0 - 1 + lf, t1 = 2 * T0 - 1 + lt;
        short8 v = z8;
        if (r1 >= 0 && r1 < 513 && t1 >= 0 && t1 < 251)
            v = *(const short8*)(o1g + ((size_t)(b * 513 + r1) * 251 + t1) * 32 + o * 8);
        *(short8*)&o1s[pos * 32 + o * 8] = v;
    }
    __syncthreads();

    int lane = tid & 63, w = tid >> 6;
    int q = lane >> 4, col = lane & 15;
    floatx4 acc[4][2];
    #pragma unroll
    for (int rt = 0; rt < 4; rt++)
        #pragma unroll
        for (int ct = 0; ct < 2; ct++)
            acc[rt][ct] = (floatx4){0.f, 0.f, 0.f, 0.f};

    #pragma unroll
    for (int s = 0; s < 9; s++) {
        const int di = s / 3, dj = s % 3;
        short8 bf0 = *(const short8*)&Bp[(s * 2 + 0) * 512 + lane * 8];
        short8 bf1 = *(const short8*)&Bp[(s * 2 + 1) * 512 + lane * 8];
        #pragma unroll
        for (int rt = 0; rt < 4; rt++) {
            int r = w * 4 + rt;
            short8 af = *(const short8*)&o1s[(((r + di) * 18) + (col + dj)) * 32 + q * 8];
            acc[rt][0] = __builtin_amdgcn_mfma_f32_16x16x32_bf16(af, bf0, acc[rt][0], 0, 0, 0);
            acc[rt][1] = __builtin_amdgcn_mfma_f32_16x16x32_bf16(af, bf1, acc[rt][1], 0, 0, 0);
        }
    }

    #pragma unroll
    for (int ct = 0; ct < 2; ct++) {
        int co = ct * 16 + col;
        float bb = b2s[co];
        #pragma unroll
        for (int fp2 = 0; fp2 < 2; fp2++) {
            #pragma unroll
            for (int tc2 = 0; tc2 < 2; tc2++) {
                float m0 = fmaxf(fmaxf(acc[2 * fp2][ct][2 * tc2], acc[2 * fp2][ct][2 * tc2 + 1]),
                                 fmaxf(acc[2 * fp2 + 1][ct][2 * tc2], acc[2 * fp2 + 1][ct][2 * tc2 + 1]));
                float v = fmaxf(m0 + bb, 0.f);
                int tp = T0 + 2 * q + tc2;
                if (tp < 125) {
                    int fg = F0 + 2 * w + fp2;
                    int node = 2 * tp + (co >= 16 ? 1 : 0);
                    nodesb[(size_t)(b * NNODE + node) * KPAD + 20 + (co & 15) * 256 + fg] = f2bf(v);
                }
            }
        }
    }
}

// ---------------- GAT1 GEMM (bf16 MFMA): h1[2000x512] = nodesb @ Wt^T ----------------
__global__ __launch_bounds__(256) void k_gat1b(const unsigned short* __restrict__ A,
                                               const unsigned short* __restrict__ Bt,
                                               float* __restrict__ C) {
    __shared__ __align__(16) unsigned short As[64 * 40];
    __shared__ __align__(16) unsigned short Bs[64 * 40];
    int tid = threadIdx.x;
    int N0 = blockIdx.x * 64, M0 = blockIdx.y * 64;
    int sr = tid >> 2, sc = (tid & 3) * 8;
    int w = tid >> 6, lane = tid & 63;
    int q = lane >> 4, col = lane & 15;
    int mb = (w >> 1) * 32, nb = (w & 1) * 32;
    floatx4 acc[2][2];
    acc[0][0] = acc[0][1] = acc[1][0] = acc[1][1] = (floatx4){0.f, 0.f, 0.f, 0.f};
    short8 z8 = {0, 0, 0, 0, 0, 0, 0, 0};
    int mA = M0 + sr;
    bool mv = mA < 2000;
    const unsigned short* pa = A + (size_t)mA * KPAD + sc;
    const unsigned short* pb = Bt + (size_t)(N0 + sr) * KPAD + sc;

    for (int K0 = 0; K0 < KPAD; K0 += 32) {
        short8 va = mv ? *(const short8*)(pa + K0) : z8;
        short8 vb = *(const short8*)(pb + K0);
        *(short8*)&As[sr * 40 + sc] = va;
        *(short8*)&Bs[sr * 40 + sc] = vb;
        __syncthreads();
        short8 a0 = *(const short8*)&As[(mb + col) * 40 + q * 8];
        short8 a1 = *(const short8*)&As[(mb + 16 + col) * 40 + q * 8];
        short8 b0 = *(const short8*)&Bs[(nb + col) * 40 + q * 8];
        short8 b1 = *(const short8*)&Bs[(nb + 16 + col) * 40 + q * 8];
        acc[0][0] = __builtin_amdgcn_mfma_f32_16x16x32_bf16(a0, b0, acc[0][0], 0, 0, 0);
        acc[0][1] = __builtin_amdgcn_mfma_f32_16x16x32_bf16(a0, b1, acc[0][1], 0, 0, 0);
        acc[1][0] = __builtin_amdgcn_mfma_f32_16x16x32_bf16(a1, b0, acc[1][0], 0, 0, 0);
        acc[1][1] = __builtin_amdgcn_mfma_f32_16x16x32_bf16(a1, b1, acc[1][1], 0, 0, 0);
        __syncthreads();
    }
    #pragma unroll
    for (int mi = 0; mi < 2; mi++)
        #pragma unroll
        for (int ni = 0; ni < 2; ni++)
            #pragma unroll
            for (int rr = 0; rr < 4; rr++) {
                int m = M0 + mb + mi * 16 + q * 4 + rr;
                if (m < 2000)
                    C[m * 512 + N0 + nb + ni * 16 + col] = acc[mi][ni][rr];
            }
}

// ---------------- GAT1 scores / max / attention ----------------
__global__ __launch_bounds__(256) void k_scores1(const float* __restrict__ h1,
                                                 const float* __restrict__ asrc,
                                                 const float* __restrict__ adst,
                                                 float* __restrict__ ssrc,
                                                 float* __restrict__ sdst) {
    int row = blockIdx.x * 4 + (threadIdx.x >> 6);
    int lane = threadIdx.x & 63;
    if (row >= 2000) return;
    for (int h = 0; h < 8; h++) {
        float v = h1[row * 512 + h * 64 + lane];
        float ps = v * asrc[h * 64 + lane];
        float pd = v * adst[h * 64 + lane];
        for (int off = 32; off > 0; off >>= 1) {
            ps += __shfl_down(ps, off);
            pd += __shfl_down(pd, off);
        }
        if (lane == 0) { ssrc[row * 8 + h] = ps; sdst[row * 8 + h] = pd; }
    }
}

__global__ __launch_bounds__(64) void k_smax1(const float* __restrict__ ssrc,
                                              float* __restrict__ smax) {
    int bh = blockIdx.x;
    int b = bh >> 3, h = bh & 7;
    int lane = threadIdx.x;
    float m = -1e30f;
    for (int n = lane; n < NNODE; n += 64) m = fmaxf(m, ssrc[(b * NNODE + n) * 8 + h]);
    for (int off = 32; off > 0; off >>= 1) m = fmaxf(m, __shfl_down(m, off));
    if (lane == 0) smax[bh] = m;
}

__global__ __launch_bounds__(64) void k_attn1(const float* __restrict__ h1,
                                              const float* __restrict__ ssrc,
                                              const float* __restrict__ sdst,
                                              const float* __restrict__ smax,
                                              const float* __restrict__ bias,
                                              float* __restrict__ g1) {
    int it = blockIdx.x, h = blockIdx.y, b = blockIdx.z;
    int f = threadIdx.x;
    __shared__ float ss[NNODE];
    for (int n = f; n < NNODE; n += 64) ss[n] = ssrc[(b * NNODE + n) * 8 + h];
    __syncthreads();
    float mxs = smax[b * 8 + h];
    int i0 = it * 4;
    float d[4], mx[4], acc[4] = {0.f, 0.f, 0.f, 0.f}, den[4] = {0.f, 0.f, 0.f, 0.f};
    #pragma unroll
    for (int ii = 0; ii < 4; ii++) {
        int i = i0 + ii;
        d[ii] = (i < NNODE) ? sdst[(b * NNODE + i) * 8 + h] : 0.f;
        float e = d[ii] + mxs;
        mx[ii] = e > 0.f ? e : 0.2f * e;
    }
    for (int j = 0; j < NNODE; j++) {
        float sj = ss[j];
        float hv = h1[(b * NNODE + j) * 512 + h * 64 + f];
        #pragma unroll
        for (int ii = 0; ii < 4; ii++) {
            float e = d[ii] + sj;
            e = e > 0.f ? e : 0.2f * e;
            float w = __expf(e - mx[ii]);
            den[ii] += w;
            acc[ii] = fmaf(w, hv, acc[ii]);
        }
    }
    float bb = bias[h * 64 + f];
    #pragma unroll
    for (int ii = 0; ii < 4; ii++) {
        int i = i0 + ii;
        if (i < NNODE)
            g1[(b * NNODE + i) * 512 + h * 64 + f] = fmaxf(acc[ii] / den[ii] + bb, 0.f);
    }
}

// ---------------- GAT2 ----------------
__global__ __launch_bounds__(256) void k_h2(const float* __restrict__ g1,
                                            const float* __restrict__ W2,
                                            const float* __restrict__ a2src,
                                            const float* __restrict__ a2dst,
                                            float* __restrict__ h2,
                                            float* __restrict__ s2src,
                                            float* __restrict__ s2dst) {
    int row = blockIdx.x * 4 + (threadIdx.x >> 6);
    if (row >= 2000) return;
    int lane = threadIdx.x & 63;
    int o = lane & 31, half = lane >> 5;
    const float* gr = &g1[row * 512 + half * 256];
    float acc = 0.f;
    for (int k = 0; k < 256; k++) acc = fmaf(gr[k], W2[(half * 256 + k) * 32 + o], acc);
    acc += __shfl_down(acc, 32);
    float ps = acc * a2src[o], pd = acc * a2dst[o];
    for (int off = 16; off > 0; off >>= 1) {
        ps += __shfl_down(ps, off, 32);
        pd += __shfl_down(pd, off, 32);
    }
    if (lane == 0) { s2src[row] = ps; s2dst[row] = pd; }
    if (lane < 32) h2[row * 32 + o] = acc;
}

__global__ __launch_bounds__(64) void k_smax2(const float* __restrict__ s2src,
                                              float* __restrict__ smax2) {
    int b = blockIdx.x, lane = threadIdx.x;
    float m = -1e30f;
    for (int n = lane; n < NNODE; n += 64) m = fmaxf(m, s2src[b * NNODE + n]);
    for (int off = 32; off > 0; off >>= 1) m = fmaxf(m, __shfl_down(m, off));
    if (lane == 0) smax2[b] = m;
}

__global__ __launch_bounds__(256) void k_attn2(const float* __restrict__ h2,
                                               const float* __restrict__ s2src,
                                               const float* __restrict__ s2dst,
                                               const float* __restrict__ smax2,
                                               const float* __restrict__ bias2,
                                               float* __restrict__ g2) {
    int it = blockIdx.x, b = blockIdx.y;
    int tid = threadIdx.x, lane = tid & 63, wv = tid >> 6;
    __shared__ float ss[NNODE];
    for (int n = tid; n < NNODE; n += 256) ss[n] = s2src[b * NNODE + n];
    __syncthreads();
    int i = it * 4 + wv;
    if (i >= NNODE) return;
    int f = lane & 31, half = lane >> 5;
    float d = s2dst[b * NNODE + i];
    float e0 = d + smax2[b];
    float mx = e0 > 0.f ? e0 : 0.2f * e0;
    float acc = 0.f, den = 0.f;
    for (int j = half; j < NNODE; j += 2) {
        float e = d + ss[j];
        e = e > 0.f ? e : 0.2f * e;
        float w = __expf(e - mx);
        den += w;
        acc = fmaf(w, h2[(b * NNODE + j) * 32 + f], acc);
    }
    acc += __shfl_down(acc, 32);
    den += __shfl_down(den, 32);
    if (lane < 32) g2[(b * NNODE + i) * 32 + f] = acc / den + bias2[f];
}

__global__ __launch_bounds__(256) void k_emb(const float* __restrict__ g2,
                                             float* __restrict__ emb,
                                             float* __restrict__ dout) {
    int b = blockIdx.x;
    int f = threadIdx.x & 31, g = threadIdx.x >> 5;
    __shared__ float red[8][32];
    float s = 0.f;
    for (int i = g; i < NNODE; i += 8) s += g2[(b * NNODE + i) * 32 + f];
    red[g][f] = s;
    __syncthreads();
    if (threadIdx.x < 32) {
        float t = 0.f;
        #pragma unroll
        for (int gg = 0; gg < 8; gg++) t += red[gg][f];
        t *= (1.0f / 250.0f);
        emb[b * 32 + f] = t;
        dout[16 + b * 32 + f] = t;
    }
}

__global__ __launch_bounds__(256) void k_fc(const float* __restrict__ emb,
                                            const float* __restrict__ fc1w,
                                            const float* __restrict__ fc1b,
                                            const float* __restrict__ bnfg,
                                            const float* __restrict__ bnfb,
                                            const float* __restrict__ fc2w,
                                            const float* __restrict__ fc2b,
                                            float* __restrict__ dout) {
    __shared__ float es[256];
    __shared__ float zs[1024];
    int tid = threadIdx.x;
    es[tid] = emb[tid];
    __syncthreads();
    float inv = rsqrtf(1.0f + 1e-5f);
    #pragma unroll
    for (int rep = 0; rep < 4; rep++) {
        int idx = tid + rep * 256;
        int b = idx >> 7, j = idx & 127;
        float a = fc1b[j];
        #pragma unroll
        for (int k = 0; k < 32; k++) a = fmaf(es[b * 32 + k], fc1w[k * 128 + j], a);
        a = a * (bnfg[j] * inv) + bnfb[j];
        zs[idx] = fmaxf(a, 0.f);
    }
    __syncthreads();
    if (tid < 16) {
        int b = tid >> 1, o = tid & 1;
        float a = fc2b[o];
        for (int k = 0; k < 128; k++) a = fmaf(zs[b * 128 + k], fc2w[k * 2 + o], a);
        dout[b * 2 + o] = a;
    }
}

// ---------------- launch ----------------
extern "C" void kernel_launch(void* const* d_in, const int* in_sizes, int n_in,
                              void* d_out, int out_size, void* d_ws, size_t ws_size,
                              hipStream_t stream) {
    (void)in_sizes; (void)n_in; (void)out_size; (void)ws_size;
    const float* x       = (const float*)d_in[0];
    const float* sinc_w  = (const float*)d_in[1];
    const float* conv1_w = (const float*)d_in[2];
    const float* conv1_b = (const float*)d_in[3];
    const float* bn1_g   = (const float*)d_in[4];
    const float* bn1_b   = (const float*)d_in[5];
    const float* conv2_w = (const float*)d_in[6];
    const float* conv2_b = (const float*)d_in[7];
    const float* bn2_g   = (const float*)d_in[8];
    const float* bn2_b   = (const float*)d_in[9];
    const float* gat1_W  = (const float*)d_in[10];
    const float* gat1_as = (const float*)d_in[11];
    const float* gat1_ad = (const float*)d_in[12];
    const float* gat1_bi = (const float*)d_in[13];
    const float* gat2_W  = (const float*)d_in[14];
    const float* gat2_as = (const float*)d_in[15];
    const float* gat2_ad = (const float*)d_in[16];
    const float* gat2_bi = (const float*)d_in[17];
    const float* fc1_w   = (const float*)d_in[18];
    const float* fc1_b   = (const float*)d_in[19];
    const float* bnf_g   = (const float*)d_in[20];
    const float* bnf_b   = (const float*)d_in[21];
    const float* fc2_w   = (const float*)d_in[22];
    const float* fc2_b   = (const float*)d_in[23];
    float* dout = (float*)d_out;

    float* ws = (float*)d_ws;
    unsigned short* fh  = (unsigned short*)ws;                 // 2048*1024 ush
    unsigned short* fl  = fh + (size_t)MPAD * 1024;
    unsigned short* bch = fl + (size_t)MPAD * 1024;            // 576*1024 ush x4
    unsigned short* bcl = bch + (size_t)NBPAD * 1024;
    unsigned short* bsh = bcl + (size_t)NBPAD * 1024;
    unsigned short* bsl = bsh + (size_t)NBPAD * 1024;
    float* S0   = (float*)(bsl + (size_t)NBPAD * 1024);        // 1,030,104 f
    float* wbar = S0 + 1030104;
    float* w1f  = wbar + 20540;
    float* b1f  = w1f + 288;
    float* w2f  = b1f + 32;
    float* b2f  = w2f + 9216;
    unsigned short* bpk = (unsigned short*)(b2f + 32);         // 9,216 ush
    unsigned short* Wt  = (unsigned short*)(b2f + 32 + 4608);  // 512*KPAD ush
    unsigned short* nodesb = Wt + (size_t)512 * KPAD;          // 2000*KPAD ush
    float* h1    = (float*)(nodesb + (size_t)2000 * KPAD);     // 1,024,000
    float* ssrc1 = h1 + 1024000;
    float* sdst1 = ssrc1 + 16000;
    float* smax1 = sdst1 + 16000;
    float* g1    = smax1 + 64;
    float* h2    = g1 + 1024000;
    float* s2src = h2 + 64000;
    float* s2dst = s2src + 2000;
    float* smax2 = s2dst + 2000;
    float* g2    = smax2 + 8;
    float* embp  = g2 + 64000;
    unsigned short* o1g = (unsigned short*)(embp + 256);       // 8*513*251*32 ush = 66 MB

    hipLaunchKernelGGL(k_fold, dim3(38), dim3(256), 0, stream,
                       conv1_w, conv1_b, bn1_g, bn1_b, conv2_w, conv2_b, bn2_g, bn2_b,
                       w1f, b1f, w2f, b2f);
    hipLaunchKernelGGL(k_pack, dim3(36), dim3(256), 0, stream, w2f, bpk);
    hipLaunchKernelGGL(k_wt, dim3(65, 8), dim3(256), 0, stream, gat1_W, Wt);
    hipLaunchKernelGGL(k_wbar, dim3((1027 * 20 + 255) / 256), dim3(256), 0, stream, sinc_w, wbar);
    hipLaunchKernelGGL(k_basis_bf, dim3(NBPAD * 1024 / 256), dim3(256), 0, stream,
                       bch, bcl, bsh, bsl);
    hipLaunchKernelGGL(k_frames_bf, dim3(MPAD * 1024 / 256), dim3(256), 0, stream, x, fh, fl);
    hipLaunchKernelGGL(k_dft_mfma, dim3(9, 32), dim3(256), 0, stream,
                       fh, fl, bch, bcl, bsh, bsl, S0);
    hipLaunchKernelGGL(k_sinc, dim3(250, 8), dim3(64), 0, stream, x, wbar, nodesb);
    hipLaunchKernelGGL(k_conv1, dim3(513, 8), dim3(256), 0, stream, S0, w1f, b1f, o1g);
    hipLaunchKernelGGL(k_conv2m, dim3(16, 32, 8), dim3(256), 0, stream, o1g, bpk, b2f, nodesb);
    hipLaunchKernelGGL(k_gat1b, dim3(8, 32), dim3(256), 0, stream, nodesb, Wt, h1);
    hipLaunchKernelGGL(k_scores1, dim3(500), dim3(256), 0, stream, h1, gat1_as, gat1_ad, ssrc1, sdst1);
    hipLaunchKernelGGL(k_smax1, dim3(64), dim3(64), 0, stream, ssrc1, smax1);
    hipLaunchKernelGGL(k_attn1, dim3(63, 8, 8), dim3(64), 0, stream,
                       h1, ssrc1, sdst1, smax1, gat1_bi, g1);
    hipLaunchKernelGGL(k_h2, dim3(500), dim3(256), 0, stream,
                       g1, gat2_W, gat2_as, gat2_ad, h2, s2src, s2dst);
    hipLaunchKernelGGL(k_smax2, dim3(8), dim3(64), 0, stream, s2src, smax2);
    hipLaunchKernelGGL(k_attn2, dim3(63, 8), dim3(256), 0, stream,
                       h2, s2src, s2dst, smax2, gat2_bi, g2);
    hipLaunchKernelGGL(k_emb, dim3(8), dim3(256), 0, stream, g2, embp, dout);
    hipLaunchKernelGGL(k_fc, dim3(1), dim3(256), 0, stream,
                       embp, fc1_w, fc1_b, bnf_g, bnf_b, fc2_w, fc2_b, dout);
}

// Round 7
// 513.498 us; speedup vs baseline: 2.0315x; 1.0719x over previous
//
#include <hip/hip_runtime.h>
#include <hip/hip_bf16.h>
#include <math.h>

// ---------------- constants ----------------
#define TB 8
#define TT 64000
#define NFRAMES 251
#define NROWS (TB*NFRAMES)      // 2008
#define MPAD 2048
#define NBINS 513
#define NBPAD 576
#define NNODE 250
#define NODE_DIM 4116
#define KPAD 4128

typedef __attribute__((ext_vector_type(8))) short short8;
typedef __attribute__((ext_vector_type(4))) float floatx4;

static __device__ __forceinline__ unsigned short f2bf(float x) {
    __hip_bfloat16 h = __float2bfloat16(x);
    return *(unsigned short*)&h;
}
static __device__ __forceinline__ float bf2f(unsigned short u) {
    __hip_bfloat16 h = *(__hip_bfloat16*)&u;
    return __bfloat162float(h);
}

// ---------------- small prep kernels ----------------

__global__ void k_fold(const float* __restrict__ c1w, const float* __restrict__ c1b,
                       const float* __restrict__ g1bn, const float* __restrict__ b1bn,
                       const float* __restrict__ c2w, const float* __restrict__ c2b,
                       const float* __restrict__ g2bn, const float* __restrict__ b2bn,
                       float* __restrict__ w1f, float* __restrict__ b1f,
                       float* __restrict__ w2f, float* __restrict__ b2f) {
    int idx = blockIdx.x * 256 + threadIdx.x;
    float inv = rsqrtf(1.0f + 1e-5f);
    if (idx < 9216) {
        int co = idx / 288;
        w2f[idx] = c2w[idx] * (g2bn[co] * inv);
    } else if (idx < 9216 + 288) {
        int r = idx - 9216;
        w1f[r] = c1w[r] * (g1bn[r / 9] * inv);
    } else if (idx < 9216 + 288 + 32) {
        int c = idx - 9504;
        b1f[c] = c1b[c] * (g1bn[c] * inv) + b1bn[c];
    } else if (idx < 9216 + 288 + 64) {
        int c = idx - 9536;
        b2f[c] = c2b[c] * (g2bn[c] * inv) + b2bn[c];
    }
}

// pack conv2 weights into MFMA B-fragment order, bf16.
__global__ void k_pack(const float* __restrict__ w2f, unsigned short* __restrict__ Bp) {
    int idx = blockIdx.x * 256 + threadIdx.x;
    if (idx >= 9216) return;
    int j = idx & 7, lane = (idx >> 3) & 63, ct = (idx >> 9) & 1, s = idx >> 10;
    int co = ct * 16 + (lane & 15);
    int ci = (lane >> 4) * 8 + j;
    Bp[idx] = f2bf(w2f[co * 288 + ci * 9 + s]);
}

// transpose gat1_W [4116x512] f32 -> Wt [512][KPAD] bf16 (pad rows zero)
__global__ __launch_bounds__(256) void k_wt(const float* __restrict__ W,
                                            unsigned short* __restrict__ Wt) {
    __shared__ unsigned short tile[64][65];
    int kt = blockIdx.x, nt = blockIdx.y;
    int tid = threadIdx.x;
    for (int idx = tid; idx < 4096; idx += 256) {
        int r = idx >> 6, c = idx & 63;
        int k = kt * 64 + r;
        float v = (k < NODE_DIM) ? W[k * 512 + nt * 64 + c] : 0.f;
        tile[r][c] = f2bf(v);
    }
    __syncthreads();
    for (int idx = tid; idx < 4096; idx += 256) {
        int nl = idx >> 6, kl = idx & 63;
        int k = kt * 64 + kl;
        if (k < KPAD)
            Wt[(size_t)(nt * 64 + nl) * KPAD + k] = tile[kl][nl];
    }
}

// wbar[m][c] = 0.25 * sum_{d=0..3} sinc_w[c][m-d]  (m in 0..1026)
__global__ void k_wbar(const float* __restrict__ sw, float* __restrict__ wbar) {
    int idx = blockIdx.x * 256 + threadIdx.x;
    if (idx >= 1027 * 20) return;
    int m = idx / 20, c = idx % 20;
    float s = 0.f;
    #pragma unroll
    for (int d = 0; d < 4; d++) {
        int k = m - d;
        if (k >= 0 && k < 1024) s += sw[c * 1024 + k];
    }
    wbar[idx] = 0.25f * s;
}

// DFT basis, bf16 hi/lo split; rows [NBINS..NBPAD) zero
__global__ void k_basis_bf(unsigned short* __restrict__ ch, unsigned short* __restrict__ cl,
                           unsigned short* __restrict__ sh, unsigned short* __restrict__ sl) {
    int idx = blockIdx.x * 256 + threadIdx.x;
    if (idx >= NBPAD * 1024) return;
    int k = idx >> 10, n = idx & 1023;
    float s = 0.f, c = 0.f;
    if (k < NBINS) {
        int mm = (k * n) & 1023;
        sincospif((float)mm * (1.0f / 512.0f), &s, &c);
    }
    unsigned short chv = f2bf(c), shv = f2bf(s);
    ch[idx] = chv; cl[idx] = f2bf(c - bf2f(chv));
    sh[idx] = shv; sl[idx] = f2bf(s - bf2f(shv));
}

// frames (reflect-padded) -> bf16 hi/lo, rows [NROWS..MPAD) zero
__global__ void k_frames_bf(const float* __restrict__ x,
                            unsigned short* __restrict__ fh, unsigned short* __restrict__ fl) {
    int idx = blockIdx.x * 256 + threadIdx.x;
    if (idx >= MPAD * 1024) return;
    int m = idx >> 10, n = idx & 1023;
    float v = 0.f;
    if (m < NROWS) {
        int b = m / NFRAMES, i = m - b * NFRAMES;
        int j = i * 256 + n - 512;
        if (j < 0) j = -j;
        if (j >= TT) j = 2 * TT - 2 - j;
        v = x[b * TT + j];
    }
    unsigned short h = f2bf(v);
    fh[idx] = h;
    fl[idx] = f2bf(v - bf2f(h));
}

// sinc features -> nodesb[b][u][0..19] (bf16)
__global__ __launch_bounds__(64) void k_sinc(const float* __restrict__ x,
                                             const float* __restrict__ wbar,
                                             unsigned short* __restrict__ nodesb) {
    int u = blockIdx.x, b = blockIdx.y;
    int c = threadIdx.x;
    if (c >= 20) return;
    const float* xb = x + b * TT;
    int base = 4 * u - 512;
    float acc = 0.f;
    for (int m = 0; m < 1027; m++) {
        int g = base + m;
        float xv = (g >= 0) ? xb[g] : 0.f;
        acc = fmaf(wbar[m * 20 + c], xv, acc);
    }
    nodesb[(size_t)(b * NNODE + u) * KPAD + c] = f2bf(acc);
}

// ---------------- DFT via bf16 MFMA with hi/lo split ----------------
__global__ __launch_bounds__(256) void k_dft_mfma(const unsigned short* __restrict__ fh,
                                                  const unsigned short* __restrict__ fl,
                                                  const unsigned short* __restrict__ ch,
                                                  const unsigned short* __restrict__ cl,
                                                  const unsigned short* __restrict__ sh,
                                                  const unsigned short* __restrict__ sl,
                                                  float* __restrict__ S0) {
    __shared__ __align__(16) unsigned short Ah[64 * 40];
    __shared__ __align__(16) unsigned short Al[64 * 40];
    __shared__ __align__(16) unsigned short Bch[64 * 40];
    __shared__ __align__(16) unsigned short Bcl[64 * 40];
    __shared__ __align__(16) unsigned short Bsh[64 * 40];
    __shared__ __align__(16) unsigned short Bsl[64 * 40];
    int tid = threadIdx.x;
    int N0 = blockIdx.x * 64, M0 = blockIdx.y * 64;
    int sr = tid >> 2, sc = (tid & 3) * 8;
    size_t aoff = (size_t)(M0 + sr) * 1024 + sc;
    size_t boff = (size_t)(N0 + sr) * 1024 + sc;
    int w = tid >> 6, lane = tid & 63;
    int q = lane >> 4, col = lane & 15;
    int mb = (w >> 1) * 32, nb = (w & 1) * 32;
    floatx4 aR[2][2], aI[2][2];
    #pragma unroll
    for (int mi = 0; mi < 2; mi++)
        #pragma unroll
        for (int ni = 0; ni < 2; ni++) {
            aR[mi][ni] = (floatx4){0.f, 0.f, 0.f, 0.f};
            aI[mi][ni] = (floatx4){0.f, 0.f, 0.f, 0.f};
        }

    for (int K0 = 0; K0 < 1024; K0 += 32) {
        *(short8*)&Ah[sr * 40 + sc]  = *(const short8*)(fh + aoff + K0);
        *(short8*)&Al[sr * 40 + sc]  = *(const short8*)(fl + aoff + K0);
        *(short8*)&Bch[sr * 40 + sc] = *(const short8*)(ch + boff + K0);
        *(short8*)&Bcl[sr * 40 + sc] = *(const short8*)(cl + boff + K0);
        *(short8*)&Bsh[sr * 40 + sc] = *(const short8*)(sh + boff + K0);
        *(short8*)&Bsl[sr * 40 + sc] = *(const short8*)(sl + boff + K0);
        __syncthreads();
        short8 ahv[2], alv[2], chv[2], clv[2], shv[2], slv[2];
        #pragma unroll
        for (int mi = 0; mi < 2; mi++) {
            ahv[mi] = *(const short8*)&Ah[(mb + mi * 16 + col) * 40 + q * 8];
            alv[mi] = *(const short8*)&Al[(mb + mi * 16 + col) * 40 + q * 8];
        }
        #pragma unroll
        for (int ni = 0; ni < 2; ni++) {
            chv[ni] = *(const short8*)&Bch[(nb + ni * 16 + col) * 40 + q * 8];
            clv[ni] = *(const short8*)&Bcl[(nb + ni * 16 + col) * 40 + q * 8];
            shv[ni] = *(const short8*)&Bsh[(nb + ni * 16 + col) * 40 + q * 8];
            slv[ni] = *(const short8*)&Bsl[(nb + ni * 16 + col) * 40 + q * 8];
        }
        #pragma unroll
        for (int mi = 0; mi < 2; mi++)
            #pragma unroll
            for (int ni = 0; ni < 2; ni++) {
                aR[mi][ni] = __builtin_amdgcn_mfma_f32_16x16x32_bf16(ahv[mi], chv[ni], aR[mi][ni], 0, 0, 0);
                aR[mi][ni] = __builtin_amdgcn_mfma_f32_16x16x32_bf16(ahv[mi], clv[ni], aR[mi][ni], 0, 0, 0);
                aR[mi][ni] = __builtin_amdgcn_mfma_f32_16x16x32_bf16(alv[mi], chv[ni], aR[mi][ni], 0, 0, 0);
                aI[mi][ni] = __builtin_amdgcn_mfma_f32_16x16x32_bf16(ahv[mi], shv[ni], aI[mi][ni], 0, 0, 0);
                aI[mi][ni] = __builtin_amdgcn_mfma_f32_16x16x32_bf16(ahv[mi], slv[ni], aI[mi][ni], 0, 0, 0);
                aI[mi][ni] = __builtin_amdgcn_mfma_f32_16x16x32_bf16(alv[mi], shv[ni], aI[mi][ni], 0, 0, 0);
            }
        __syncthreads();
    }
    #pragma unroll
    for (int mi = 0; mi < 2; mi++)
        #pragma unroll
        for (int ni = 0; ni < 2; ni++)
            #pragma unroll
            for (int rr = 0; rr < 4; rr++) {
                int m = M0 + mb + mi * 16 + q * 4 + rr;
                int bin = N0 + nb + ni * 16 + col;
                if (m < NROWS && bin < NBINS) {
                    float re = aR[mi][ni][rr], im = aI[mi][ni][rr];
                    int b = m / NFRAMES, i = m - b * NFRAMES;
                    S0[(b * NBINS + bin) * NFRAMES + i] =
                        logf(sqrtf(fmaf(re, re, im * im)) + 1e-9f);
                }
            }
}

// ---------------- conv1+BN+ReLU -> o1g[b][513][251][32] bf16 channels-last ----------------
__global__ __launch_bounds__(256) void k_conv1(const float* __restrict__ S0,
                                               const float* __restrict__ w1f,
                                               const float* __restrict__ b1f,
                                               unsigned short* __restrict__ o1g) {
    __shared__ float w1s[288];
    __shared__ float b1s[32];
    int tid = threadIdx.x;
    for (int i = tid; i < 288; i += 256) w1s[i] = w1f[i];
    if (tid < 32) b1s[tid] = b1f[tid];
    __syncthreads();
    int r = blockIdx.x;
    int b = blockIdx.y;
    int t = tid;
    if (t >= 251) return;
    float sv[9];
    #pragma unroll
    for (int di = 0; di < 3; di++) {
        int rr = r - 1 + di;
        #pragma unroll
        for (int dj = 0; dj < 3; dj++) {
            int tt = t - 1 + dj;
            float v = 0.f;
            if (rr >= 0 && rr < 513 && tt >= 0 && tt < 251)
                v = S0[(b * 513 + rr) * 251 + tt];
            sv[di * 3 + dj] = v;
        }
    }
    unsigned short ov[32];
    #pragma unroll
    for (int ci = 0; ci < 32; ci++) {
        float a = b1s[ci];
        const float* wp = &w1s[ci * 9];
        #pragma unroll
        for (int k = 0; k < 9; k++) a = fmaf(sv[k], wp[k], a);
        ov[ci] = f2bf(fmaxf(a, 0.f));
    }
    unsigned short* dst = o1g + ((size_t)(b * 513 + r) * 251 + t) * 32;
    #pragma unroll
    for (int i = 0; i < 4; i++)
        *(short8*)(dst + i * 8) = *(const short8*)&ov[i * 8];
}

// ---------------- conv2 (bf16 MFMA) + maxpool -> nodesb ----------------
__global__ __launch_bounds__(256) void k_conv2m(const unsigned short* __restrict__ o1g,
                                                const unsigned short* __restrict__ Bp,
                                                const float* __restrict__ b2f,
                                                unsigned short* __restrict__ nodesb) {
    __shared__ __align__(16) unsigned short o1s[18 * 18 * 32];
    __shared__ float b2s[32];
    int tid = threadIdx.x;
    int b = blockIdx.z;
    int F0 = blockIdx.y * 8;
    int T0 = blockIdx.x * 8;
    if (tid < 32) b2s[tid] = b2f[tid];
    short8 z8 = {0, 0, 0, 0, 0, 0, 0, 0};
    for (int c = tid; c < 1296; c += 256) {
        int o = c & 3, pos = c >> 2;
        int lf = pos / 18, lt = pos - lf * 18;
        int r1 = 2 * F0 - 1 + lf, t1 = 2 * T0 - 1 + lt;
        short8 v = z8;
        if (r1 >= 0 && r1 < 513 && t1 >= 0 && t1 < 251)
            v = *(const short8*)(o1g + ((size_t)(b * 513 + r1) * 251 + t1) * 32 + o * 8);
        *(short8*)&o1s[pos * 32 + o * 8] = v;
    }
    __syncthreads();

    int lane = tid & 63, w = tid >> 6;
    int q = lane >> 4, col = lane & 15;
    floatx4 acc[4][2];
    #pragma unroll
    for (int rt = 0; rt < 4; rt++)
        #pragma unroll
        for (int ct = 0; ct < 2; ct++)
            acc[rt][ct] = (floatx4){0.f, 0.f, 0.f, 0.f};

    #pragma unroll
    for (int s = 0; s < 9; s++) {
        const int di = s / 3, dj = s % 3;
        short8 bf0 = *(const short8*)&Bp[(s * 2 + 0) * 512 + lane * 8];
        short8 bf1 = *(const short8*)&Bp[(s * 2 + 1) * 512 + lane * 8];
        #pragma unroll
        for (int rt = 0; rt < 4; rt++) {
            int r = w * 4 + rt;
            short8 af = *(const short8*)&o1s[(((r + di) * 18) + (col + dj)) * 32 + q * 8];
            acc[rt][0] = __builtin_amdgcn_mfma_f32_16x16x32_bf16(af, bf0, acc[rt][0], 0, 0, 0);
            acc[rt][1] = __builtin_amdgcn_mfma_f32_16x16x32_bf16(af, bf1, acc[rt][1], 0, 0, 0);
        }
    }

    #pragma unroll
    for (int ct = 0; ct < 2; ct++) {
        int co = ct * 16 + col;
        float bb = b2s[co];
        #pragma unroll
        for (int fp2 = 0; fp2 < 2; fp2++) {
            #pragma unroll
            for (int tc2 = 0; tc2 < 2; tc2++) {
                float m0 = fmaxf(fmaxf(acc[2 * fp2][ct][2 * tc2], acc[2 * fp2][ct][2 * tc2 + 1]),
                                 fmaxf(acc[2 * fp2 + 1][ct][2 * tc2], acc[2 * fp2 + 1][ct][2 * tc2 + 1]));
                float v = fmaxf(m0 + bb, 0.f);
                int tp = T0 + 2 * q + tc2;
                if (tp < 125) {
                    int fg = F0 + 2 * w + fp2;
                    int node = 2 * tp + (co >= 16 ? 1 : 0);
                    nodesb[(size_t)(b * NNODE + node) * KPAD + 20 + (co & 15) * 256 + fg] = f2bf(v);
                }
            }
        }
    }
}

// ---------------- GAT1 GEMM (bf16 MFMA): h1 f32 + h1t bf16 [bh][f][256] ----------------
__global__ __launch_bounds__(256) void k_gat1b(const unsigned short* __restrict__ A,
                                               const unsigned short* __restrict__ Bt,
                                               float* __restrict__ C,
                                               unsigned short* __restrict__ h1t) {
    __shared__ __align__(16) unsigned short As[64 * 40];
    __shared__ __align__(16) unsigned short Bs[64 * 40];
    int tid = threadIdx.x;
    int N0 = blockIdx.x * 64, M0 = blockIdx.y * 64;
    int sr = tid >> 2, sc = (tid & 3) * 8;
    int w = tid >> 6, lane = tid & 63;
    int q = lane >> 4, col = lane & 15;
    int mb = (w >> 1) * 32, nb = (w & 1) * 32;
    floatx4 acc[2][2];
    acc[0][0] = acc[0][1] = acc[1][0] = acc[1][1] = (floatx4){0.f, 0.f, 0.f, 0.f};
    short8 z8 = {0, 0, 0, 0, 0, 0, 0, 0};
    int mA = M0 + sr;
    bool mv = mA < 2000;
    const unsigned short* pa = A + (size_t)mA * KPAD + sc;
    const unsigned short* pb = Bt + (size_t)(N0 + sr) * KPAD + sc;

    for (int K0 = 0; K0 < KPAD; K0 += 32) {
        short8 va = mv ? *(const short8*)(pa + K0) : z8;
        short8 vb = *(const short8*)(pb + K0);
        *(short8*)&As[sr * 40 + sc] = va;
        *(short8*)&Bs[sr * 40 + sc] = vb;
        __syncthreads();
        short8 a0 = *(const short8*)&As[(mb + col) * 40 + q * 8];
        short8 a1 = *(const short8*)&As[(mb + 16 + col) * 40 + q * 8];
        short8 b0 = *(const short8*)&Bs[(nb + col) * 40 + q * 8];
        short8 b1 = *(const short8*)&Bs[(nb + 16 + col) * 40 + q * 8];
        acc[0][0] = __builtin_amdgcn_mfma_f32_16x16x32_bf16(a0, b0, acc[0][0], 0, 0, 0);
        acc[0][1] = __builtin_amdgcn_mfma_f32_16x16x32_bf16(a0, b1, acc[0][1], 0, 0, 0);
        acc[1][0] = __builtin_amdgcn_mfma_f32_16x16x32_bf16(a1, b0, acc[1][0], 0, 0, 0);
        acc[1][1] = __builtin_amdgcn_mfma_f32_16x16x32_bf16(a1, b1, acc[1][1], 0, 0, 0);
        __syncthreads();
    }
    #pragma unroll
    for (int mi = 0; mi < 2; mi++)
        #pragma unroll
        for (int ni = 0; ni < 2; ni++)
            #pragma unroll
            for (int rr = 0; rr < 4; rr++) {
                int m = M0 + mb + mi * 16 + q * 4 + rr;
                if (m < 2000) {
                    int n = N0 + nb + ni * 16 + col;
                    C[m * 512 + n] = acc[mi][ni][rr];
                    int bb = m / NNODE, j = m - bb * NNODE;
                    int hh = n >> 6, f = n & 63;
                    h1t[((size_t)((bb * 8 + hh) * 64 + f)) * 256 + j] = f2bf(acc[mi][ni][rr]);
                }
            }
}

// ---------------- GAT1 scores / max ----------------
__global__ __launch_bounds__(256) void k_scores1(const float* __restrict__ h1,
                                                 const float* __restrict__ asrc,
                                                 const float* __restrict__ adst,
                                                 float* __restrict__ ssrc,
                                                 float* __restrict__ sdst) {
    int row = blockIdx.x * 4 + (threadIdx.x >> 6);
    int lane = threadIdx.x & 63;
    if (row >= 2000) return;
    for (int h = 0; h < 8; h++) {
        float v = h1[row * 512 + h * 64 + lane];
        float ps = v * asrc[h * 64 + lane];
        float pd = v * adst[h * 64 + lane];
        for (int off = 32; off > 0; off >>= 1) {
            ps += __shfl_down(ps, off);
            pd += __shfl_down(pd, off);
        }
        if (lane == 0) { ssrc[row * 8 + h] = ps; sdst[row * 8 + h] = pd; }
    }
}

__global__ __launch_bounds__(64) void k_smax1(const float* __restrict__ ssrc,
                                              float* __restrict__ smax) {
    int bh = blockIdx.x;
    int b = bh >> 3, h = bh & 7;
    int lane = threadIdx.x;
    float m = -1e30f;
    for (int n = lane; n < NNODE; n += 64) m = fmaxf(m, ssrc[(b * NNODE + n) * 8 + h]);
    for (int off = 32; off > 0; off >>= 1) m = fmaxf(m, __shfl_down(m, off));
    if (lane == 0) smax[bh] = m;
}

// ---------------- GAT1 attention weights: Pn[bh][256][256] bf16 normalized ----------------
__global__ __launch_bounds__(256) void k_attw(const float* __restrict__ ssrc,
                                              const float* __restrict__ sdst,
                                              const float* __restrict__ smax,
                                              unsigned short* __restrict__ Pn) {
    int bh = blockIdx.x;
    int b = bh >> 3, h = bh & 7;
    int tid = threadIdx.x;
    __shared__ float ss[NNODE];
    for (int j = tid; j < NNODE; j += 256) ss[j] = ssrc[(b * NNODE + j) * 8 + h];
    __syncthreads();
    unsigned short* row = Pn + ((size_t)bh * 256 + tid) * 256;
    short8 z8 = {0, 0, 0, 0, 0, 0, 0, 0};
    if (tid >= NNODE) {
        #pragma unroll
        for (int j = 0; j < 256; j += 8) *(short8*)(row + j) = z8;
        return;
    }
    float d = sdst[(b * NNODE + tid) * 8 + h];
    float e0 = d + smax[bh];
    float mx = e0 > 0.f ? e0 : 0.2f * e0;
    float den = 0.f;
    for (int j = 0; j < NNODE; j++) {
        float e = d + ss[j];
        e = e > 0.f ? e : 0.2f * e;
        den += __expf(e - mx);
    }
    float rden = 1.f / den;
    for (int j0 = 0; j0 < 256; j0 += 8) {
        unsigned short wv[8];
        #pragma unroll
        for (int jj = 0; jj < 8; jj++) {
            int j = j0 + jj;
            float wt = 0.f;
            if (j < NNODE) {
                float e = d + ss[j];
                e = e > 0.f ? e : 0.2f * e;
                wt = __expf(e - mx) * rden;
            }
            wv[jj] = f2bf(wt);
        }
        *(short8*)(row + j0) = *(const short8*)wv;
    }
}

// ---------------- GAT1 attention apply (MFMA): g1 = Pn @ h1t^T + bias, relu ----------------
__global__ __launch_bounds__(256) void k_attnv(const unsigned short* __restrict__ Pn,
                                               const unsigned short* __restrict__ h1t,
                                               const float* __restrict__ bias,
                                               float* __restrict__ g1) {
    int bh = blockIdx.x;
    int b = bh >> 3, h = bh & 7;
    int tid = threadIdx.x;
    int w = tid >> 6, lane = tid & 63;
    int q = lane >> 4, col = lane & 15;
    const unsigned short* Pb = Pn + (size_t)bh * 65536;
    const unsigned short* Hb = h1t + (size_t)bh * 16384;
    floatx4 acc[4][4];
    #pragma unroll
    for (int mi = 0; mi < 4; mi++)
        #pragma unroll
        for (int ni = 0; ni < 4; ni++)
            acc[mi][ni] = (floatx4){0.f, 0.f, 0.f, 0.f};
    for (int k0 = 0; k0 < 256; k0 += 32) {
        short8 af[4], bf[4];
        #pragma unroll
        for (int mi = 0; mi < 4; mi++)
            af[mi] = *(const short8*)(Pb + (size_t)((w * 4 + mi) * 16 + col) * 256 + k0 + q * 8);
        #pragma unroll
        for (int ni = 0; ni < 4; ni++)
            bf[ni] = *(const short8*)(Hb + (size_t)(ni * 16 + col) * 256 + k0 + q * 8);
        #pragma unroll
        for (int mi = 0; mi < 4; mi++)
            #pragma unroll
            for (int ni = 0; ni < 4; ni++)
                acc[mi][ni] = __builtin_amdgcn_mfma_f32_16x16x32_bf16(af[mi], bf[ni], acc[mi][ni], 0, 0, 0);
    }
    #pragma unroll
    for (int mi = 0; mi < 4; mi++)
        #pragma unroll
        for (int ni = 0; ni < 4; ni++)
            #pragma unroll
            for (int rr = 0; rr < 4; rr++) {
                int i = (w * 4 + mi) * 16 + q * 4 + rr;
                int f = ni * 16 + col;
                if (i < NNODE)
                    g1[(b * NNODE + i) * 512 + h * 64 + f] =
                        fmaxf(acc[mi][ni][rr] + bias[h * 64 + f], 0.f);
            }
}

// ---------------- GAT2 ----------------
__global__ __launch_bounds__(256) void k_h2(const float* __restrict__ g1,
                                            const float* __restrict__ W2,
                                            const float* __restrict__ a2src,
                                            const float* __restrict__ a2dst,
                                            float* __restrict__ h2,
                                            float* __restrict__ s2src,
                                            float* __restrict__ s2dst) {
    int row = blockIdx.x * 4 + (threadIdx.x >> 6);
    if (row >= 2000) return;
    int lane = threadIdx.x & 63;
    int o = lane & 31, half = lane >> 5;
    const float* gr = &g1[row * 512 + half * 256];
    float acc = 0.f;
    for (int k = 0; k < 256; k++) acc = fmaf(gr[k], W2[(half * 256 + k) * 32 + o], acc);
    acc += __shfl_down(acc, 32);
    float ps = acc * a2src[o], pd = acc * a2dst[o];
    for (int off = 16; off > 0; off >>= 1) {
        ps += __shfl_down(ps, off, 32);
        pd += __shfl_down(pd, off, 32);
    }
    if (lane == 0) { s2src[row] = ps; s2dst[row] = pd; }
    if (lane < 32) h2[row * 32 + o] = acc;
}

__global__ __launch_bounds__(64) void k_smax2(const float* __restrict__ s2src,
                                              float* __restrict__ smax2) {
    int b = blockIdx.x, lane = threadIdx.x;
    float m = -1e30f;
    for (int n = lane; n < NNODE; n += 64) m = fmaxf(m, s2src[b * NNODE + n]);
    for (int off = 32; off > 0; off >>= 1) m = fmaxf(m, __shfl_down(m, off));
    if (lane == 0) smax2[b] = m;
}

__global__ __launch_bounds__(256) void k_attn2(const float* __restrict__ h2,
                                               const float* __restrict__ s2src,
                                               const float* __restrict__ s2dst,
                                               const float* __restrict__ smax2,
                                               const float* __restrict__ bias2,
                                               float* __restrict__ g2) {
    int it = blockIdx.x, b = blockIdx.y;
    int tid = threadIdx.x, lane = tid & 63, wv = tid >> 6;
    __shared__ float ss[NNODE];
    for (int n = tid; n < NNODE; n += 256) ss[n] = s2src[b * NNODE + n];
    __syncthreads();
    int i = it * 4 + wv;
    if (i >= NNODE) return;
    int f = lane & 31, half = lane >> 5;
    float d = s2dst[b * NNODE + i];
    float e0 = d + smax2[b];
    float mx = e0 > 0.f ? e0 : 0.2f * e0;
    float acc = 0.f, den = 0.f;
    for (int j = half; j < NNODE; j += 2) {
        float e = d + ss[j];
        e = e > 0.f ? e : 0.2f * e;
        float w = __expf(e - mx);
        den += w;
        acc = fmaf(w, h2[(b * NNODE + j) * 32 + f], acc);
    }
    acc += __shfl_down(acc, 32);
    den += __shfl_down(den, 32);
    if (lane < 32) g2[(b * NNODE + i) * 32 + f] = acc / den + bias2[f];
}

__global__ __launch_bounds__(256) void k_emb(const float* __restrict__ g2,
                                             float* __restrict__ emb,
                                             float* __restrict__ dout) {
    int b = blockIdx.x;
    int f = threadIdx.x & 31, g = threadIdx.x >> 5;
    __shared__ float red[8][32];
    float s = 0.f;
    for (int i = g; i < NNODE; i += 8) s += g2[(b * NNODE + i) * 32 + f];
    red[g][f] = s;
    __syncthreads();
    if (threadIdx.x < 32) {
        float t = 0.f;
        #pragma unroll
        for (int gg = 0; gg < 8; gg++) t += red[gg][f];
        t *= (1.0f / 250.0f);
        emb[b * 32 + f] = t;
        dout[16 + b * 32 + f] = t;
    }
}

__global__ __launch_bounds__(256) void k_fc(const float* __restrict__ emb,
                                            const float* __restrict__ fc1w,
                                            const float* __restrict__ fc1b,
                                            const float* __restrict__ bnfg,
                                            const float* __restrict__ bnfb,
                                            const float* __restrict__ fc2w,
                                            const float* __restrict__ fc2b,
                                            float* __restrict__ dout) {
    __shared__ float es[256];
    __shared__ float zs[1024];
    int tid = threadIdx.x;
    es[tid] = emb[tid];
    __syncthreads();
    float inv = rsqrtf(1.0f + 1e-5f);
    #pragma unroll
    for (int rep = 0; rep < 4; rep++) {
        int idx = tid + rep * 256;
        int b = idx >> 7, j = idx & 127;
        float a = fc1b[j];
        #pragma unroll
        for (int k = 0; k < 32; k++) a = fmaf(es[b * 32 + k], fc1w[k * 128 + j], a);
        a = a * (bnfg[j] * inv) + bnfb[j];
        zs[idx] = fmaxf(a, 0.f);
    }
    __syncthreads();
    if (tid < 16) {
        int b = tid >> 1, o = tid & 1;
        float a = fc2b[o];
        for (int k = 0; k < 128; k++) a = fmaf(zs[b * 128 + k], fc2w[k * 2 + o], a);
        dout[b * 2 + o] = a;
    }
}

// ---------------- launch ----------------
extern "C" void kernel_launch(void* const* d_in, const int* in_sizes, int n_in,
                              void* d_out, int out_size, void* d_ws, size_t ws_size,
                              hipStream_t stream) {
    (void)in_sizes; (void)n_in; (void)out_size; (void)ws_size;
    const float* x       = (const float*)d_in[0];
    const float* sinc_w  = (const float*)d_in[1];
    const float* conv1_w = (const float*)d_in[2];
    const float* conv1_b = (const float*)d_in[3];
    const float* bn1_g   = (const float*)d_in[4];
    const float* bn1_b   = (const float*)d_in[5];
    const float* conv2_w = (const float*)d_in[6];
    const float* conv2_b = (const float*)d_in[7];
    const float* bn2_g   = (const float*)d_in[8];
    const float* bn2_b   = (const float*)d_in[9];
    const float* gat1_W  = (const float*)d_in[10];
    const float* gat1_as = (const float*)d_in[11];
    const float* gat1_ad = (const float*)d_in[12];
    const float* gat1_bi = (const float*)d_in[13];
    const float* gat2_W  = (const float*)d_in[14];
    const float* gat2_as = (const float*)d_in[15];
    const float* gat2_ad = (const float*)d_in[16];
    const float* gat2_bi = (const float*)d_in[17];
    const float* fc1_w   = (const float*)d_in[18];
    const float* fc1_b   = (const float*)d_in[19];
    const float* bnf_g   = (const float*)d_in[20];
    const float* bnf_b   = (const float*)d_in[21];
    const float* fc2_w   = (const float*)d_in[22];
    const float* fc2_b   = (const float*)d_in[23];
    float* dout = (float*)d_out;

    float* ws = (float*)d_ws;
    unsigned short* fh  = (unsigned short*)ws;                 // 2048*1024 ush
    unsigned short* fl  = fh + (size_t)MPAD * 1024;
    unsigned short* bch = fl + (size_t)MPAD * 1024;
    unsigned short* bcl = bch + (size_t)NBPAD * 1024;
    unsigned short* bsh = bcl + (size_t)NBPAD * 1024;
    unsigned short* bsl = bsh + (size_t)NBPAD * 1024;
    float* S0   = (float*)(bsl + (size_t)NBPAD * 1024);        // 1,030,104 f
    float* wbar = S0 + 1030104;
    float* w1f  = wbar + 20540;
    float* b1f  = w1f + 288;
    float* w2f  = b1f + 32;
    float* b2f  = w2f + 9216;
    unsigned short* bpk = (unsigned short*)(b2f + 32);         // 9,216 ush
    unsigned short* Wt  = (unsigned short*)(b2f + 32 + 4608);  // 512*KPAD ush
    unsigned short* nodesb = Wt + (size_t)512 * KPAD;          // 2000*KPAD ush
    float* h1    = (float*)(nodesb + (size_t)2000 * KPAD);     // 1,024,000
    float* ssrc1 = h1 + 1024000;
    float* sdst1 = ssrc1 + 16000;
    float* smax1 = sdst1 + 16000;
    float* g1    = smax1 + 64;
    float* h2    = g1 + 1024000;
    float* s2src = h2 + 64000;
    float* s2dst = s2src + 2000;
    float* smax2 = s2dst + 2000;
    float* g2    = smax2 + 8;
    float* embp  = g2 + 64000;
    unsigned short* o1g = (unsigned short*)(embp + 256);       // 8*513*251*32 ush
    unsigned short* Pn  = o1g + (size_t)8 * 513 * 251 * 32;    // 64*256*256 ush
    unsigned short* h1t = Pn + (size_t)64 * 256 * 256;         // 64*64*256 ush

    hipLaunchKernelGGL(k_fold, dim3(38), dim3(256), 0, stream,
                       conv1_w, conv1_b, bn1_g, bn1_b, conv2_w, conv2_b, bn2_g, bn2_b,
                       w1f, b1f, w2f, b2f);
    hipLaunchKernelGGL(k_pack, dim3(36), dim3(256), 0, stream, w2f, bpk);
    hipLaunchKernelGGL(k_wt, dim3(65, 8), dim3(256), 0, stream, gat1_W, Wt);
    hipLaunchKernelGGL(k_wbar, dim3((1027 * 20 + 255) / 256), dim3(256), 0, stream, sinc_w, wbar);
    hipLaunchKernelGGL(k_basis_bf, dim3(NBPAD * 1024 / 256), dim3(256), 0, stream,
                       bch, bcl, bsh, bsl);
    hipLaunchKernelGGL(k_frames_bf, dim3(MPAD * 1024 / 256), dim3(256), 0, stream, x, fh, fl);
    hipLaunchKernelGGL(k_dft_mfma, dim3(9, 32), dim3(256), 0, stream,
                       fh, fl, bch, bcl, bsh, bsl, S0);
    hipLaunchKernelGGL(k_sinc, dim3(250, 8), dim3(64), 0, stream, x, wbar, nodesb);
    hipLaunchKernelGGL(k_conv1, dim3(513, 8), dim3(256), 0, stream, S0, w1f, b1f, o1g);
    hipLaunchKernelGGL(k_conv2m, dim3(16, 32, 8), dim3(256), 0, stream, o1g, bpk, b2f, nodesb);
    hipLaunchKernelGGL(k_gat1b, dim3(8, 32), dim3(256), 0, stream, nodesb, Wt, h1, h1t);
    hipLaunchKernelGGL(k_scores1, dim3(500), dim3(256), 0, stream, h1, gat1_as, gat1_ad, ssrc1, sdst1);
    hipLaunchKernelGGL(k_smax1, dim3(64), dim3(64), 0, stream, ssrc1, smax1);
    hipLaunchKernelGGL(k_attw, dim3(64), dim3(256), 0, stream, ssrc1, sdst1, smax1, Pn);
    hipLaunchKernelGGL(k_attnv, dim3(64), dim3(256), 0, stream, Pn, h1t, gat1_bi, g1);
    hipLaunchKernelGGL(k_h2, dim3(500), dim3(256), 0, stream,
                       g1, gat2_W, gat2_as, gat2_ad, h2, s2src, s2dst);
    hipLaunchKernelGGL(k_smax2, dim3(8), dim3(64), 0, stream, s2src, smax2);
    hipLaunchKernelGGL(k_attn2, dim3(63, 8), dim3(256), 0, stream,
                       h2, s2src, s2dst, smax2, gat2_bi, g2);
    hipLaunchKernelGGL(k_emb, dim3(8), dim3(256), 0, stream, g2, embp, dout);
    hipLaunchKernelGGL(k_fc, dim3(1), dim3(256), 0, stream,
                       embp, fc1_w, fc1_b, bnf_g, bnf_b, fc2_w, fc2_b, dout);
}

// Round 8
// 451.253 us; speedup vs baseline: 2.3118x; 1.1379x over previous
//
#include <hip/hip_runtime.h>
#include <hip/hip_bf16.h>
#include <math.h>

// ---------------- constants ----------------
#define TB 8
#define TT 64000
#define NFRAMES 251
#define NROWS (TB*NFRAMES)      // 2008
#define MPAD 2048
#define NBINS 513
#define NBPAD 576
#define NNODE 250
#define NODE_DIM 4116
#define KPAD 4128

typedef __attribute__((ext_vector_type(8))) short short8;
typedef __attribute__((ext_vector_type(4))) float floatx4;

static __device__ __forceinline__ unsigned short f2bf(float x) {
    __hip_bfloat16 h = __float2bfloat16(x);
    return *(unsigned short*)&h;
}
static __device__ __forceinline__ float bf2f(unsigned short u) {
    __hip_bfloat16 h = *(__hip_bfloat16*)&u;
    return __bfloat162float(h);
}

// ---------------- small prep kernels ----------------

__global__ void k_fold(const float* __restrict__ c1w, const float* __restrict__ c1b,
                       const float* __restrict__ g1bn, const float* __restrict__ b1bn,
                       const float* __restrict__ c2w, const float* __restrict__ c2b,
                       const float* __restrict__ g2bn, const float* __restrict__ b2bn,
                       float* __restrict__ w1f, float* __restrict__ b1f,
                       float* __restrict__ w2f, float* __restrict__ b2f) {
    int idx = blockIdx.x * 256 + threadIdx.x;
    float inv = rsqrtf(1.0f + 1e-5f);
    if (idx < 9216) {
        int co = idx / 288;
        w2f[idx] = c2w[idx] * (g2bn[co] * inv);
    } else if (idx < 9216 + 288) {
        int r = idx - 9216;
        w1f[r] = c1w[r] * (g1bn[r / 9] * inv);
    } else if (idx < 9216 + 288 + 32) {
        int c = idx - 9504;
        b1f[c] = c1b[c] * (g1bn[c] * inv) + b1bn[c];
    } else if (idx < 9216 + 288 + 64) {
        int c = idx - 9536;
        b2f[c] = c2b[c] * (g2bn[c] * inv) + b2bn[c];
    }
}

// pack conv2 weights into MFMA B-fragment order, bf16.
__global__ void k_pack(const float* __restrict__ w2f, unsigned short* __restrict__ Bp) {
    int idx = blockIdx.x * 256 + threadIdx.x;
    if (idx >= 9216) return;
    int j = idx & 7, lane = (idx >> 3) & 63, ct = (idx >> 9) & 1, s = idx >> 10;
    int co = ct * 16 + (lane & 15);
    int ci = (lane >> 4) * 8 + j;
    Bp[idx] = f2bf(w2f[co * 288 + ci * 9 + s]);
}

// transpose gat1_W [4116x512] f32 -> Wt [512][KPAD] bf16 (pad rows zero)
__global__ __launch_bounds__(256) void k_wt(const float* __restrict__ W,
                                            unsigned short* __restrict__ Wt) {
    __shared__ unsigned short tile[64][65];
    int kt = blockIdx.x, nt = blockIdx.y;
    int tid = threadIdx.x;
    for (int idx = tid; idx < 4096; idx += 256) {
        int r = idx >> 6, c = idx & 63;
        int k = kt * 64 + r;
        float v = (k < NODE_DIM) ? W[k * 512 + nt * 64 + c] : 0.f;
        tile[r][c] = f2bf(v);
    }
    __syncthreads();
    for (int idx = tid; idx < 4096; idx += 256) {
        int nl = idx >> 6, kl = idx & 63;
        int k = kt * 64 + kl;
        if (k < KPAD)
            Wt[(size_t)(nt * 64 + nl) * KPAD + k] = tile[kl][nl];
    }
}

// sinc weights: 4-tap prefix-summed, transposed, padded bf16: wbt[32][1056]
__global__ void k_wbt(const float* __restrict__ sw, unsigned short* __restrict__ wbt) {
    int idx = blockIdx.x * 256 + threadIdx.x;
    if (idx >= 32 * 1056) return;
    int c = idx / 1056, m = idx - c * 1056;
    float s = 0.f;
    if (c < 20 && m < 1027) {
        #pragma unroll
        for (int d = 0; d < 4; d++) {
            int k = m - d;
            if (k >= 0 && k < 1024) s += sw[c * 1024 + k];
        }
        s *= 0.25f;
    }
    wbt[idx] = f2bf(s);
}

// DFT basis, bf16 hi/lo split; rows [NBINS..NBPAD) zero
__global__ void k_basis_bf(unsigned short* __restrict__ ch, unsigned short* __restrict__ cl,
                           unsigned short* __restrict__ sh, unsigned short* __restrict__ sl) {
    int idx = blockIdx.x * 256 + threadIdx.x;
    if (idx >= NBPAD * 1024) return;
    int k = idx >> 10, n = idx & 1023;
    float s = 0.f, c = 0.f;
    if (k < NBINS) {
        int mm = (k * n) & 1023;
        sincospif((float)mm * (1.0f / 512.0f), &s, &c);
    }
    unsigned short chv = f2bf(c), shv = f2bf(s);
    ch[idx] = chv; cl[idx] = f2bf(c - bf2f(chv));
    sh[idx] = shv; sl[idx] = f2bf(s - bf2f(shv));
}

// frames (reflect-padded) -> bf16 hi/lo, rows [NROWS..MPAD) zero
__global__ void k_frames_bf(const float* __restrict__ x,
                            unsigned short* __restrict__ fh, unsigned short* __restrict__ fl) {
    int idx = blockIdx.x * 256 + threadIdx.x;
    if (idx >= MPAD * 1024) return;
    int m = idx >> 10, n = idx & 1023;
    float v = 0.f;
    if (m < NROWS) {
        int b = m / NFRAMES, i = m - b * NFRAMES;
        int j = i * 256 + n - 512;
        if (j < 0) j = -j;
        if (j >= TT) j = 2 * TT - 2 - j;
        v = x[b * TT + j];
    }
    unsigned short h = f2bf(v);
    fh[idx] = h;
    fl[idx] = f2bf(v - bf2f(h));
}

// ---------------- sinc conv as MFMA GEMM: nodes[b][u][0..19] ----------------
// feat[u][c] = sum_m wbt[c][m] * xw[4u + m],  xw[i] = x[b][i-512] (zero-pad left)
__global__ __launch_bounds__(256) void k_sincm(const float* __restrict__ x,
                                               const unsigned short* __restrict__ wbt,
                                               unsigned short* __restrict__ nodesb) {
    __shared__ __align__(16) unsigned short xs[2080];
    int b = blockIdx.x;
    int tid = threadIdx.x;
    for (int i = tid; i < 2080; i += 256) {
        int g = i - 512;
        float v = (g >= 0 && g < TT) ? x[b * TT + g] : 0.f;
        xs[i] = f2bf(v);
    }
    __syncthreads();
    int w = tid >> 6, lane = tid & 63;
    int q = lane >> 4, col = lane & 15;
    floatx4 acc[4][2];
    #pragma unroll
    for (int mi = 0; mi < 4; mi++)
        #pragma unroll
        for (int ni = 0; ni < 2; ni++)
            acc[mi][ni] = (floatx4){0.f, 0.f, 0.f, 0.f};
    for (int K0 = 0; K0 < 1056; K0 += 32) {
        short8 af[4];
        #pragma unroll
        for (int mi = 0; mi < 4; mi++) {
            int u = w * 64 + mi * 16 + col;
            int off = 4 * u + K0 + q * 8;          // 8-byte aligned (x2 bytes)
            unsigned long long lo = *(const unsigned long long*)&xs[off];
            unsigned long long hi = *(const unsigned long long*)&xs[off + 4];
            union { unsigned long long u64[2]; short8 s8; } cv;
            cv.u64[0] = lo; cv.u64[1] = hi;
            af[mi] = cv.s8;
        }
        short8 bf[2];
        #pragma unroll
        for (int ni = 0; ni < 2; ni++) {
            int c = ni * 16 + col;
            bf[ni] = *(const short8*)(wbt + (size_t)c * 1056 + K0 + q * 8);
        }
        #pragma unroll
        for (int mi = 0; mi < 4; mi++)
            #pragma unroll
            for (int ni = 0; ni < 2; ni++)
                acc[mi][ni] = __builtin_amdgcn_mfma_f32_16x16x32_bf16(af[mi], bf[ni], acc[mi][ni], 0, 0, 0);
    }
    #pragma unroll
    for (int mi = 0; mi < 4; mi++)
        #pragma unroll
        for (int ni = 0; ni < 2; ni++)
            #pragma unroll
            for (int rr = 0; rr < 4; rr++) {
                int u = w * 64 + mi * 16 + q * 4 + rr;
                int c = ni * 16 + col;
                if (u < NNODE && c < 20)
                    nodesb[(size_t)(b * NNODE + u) * KPAD + c] = f2bf(acc[mi][ni][rr]);
            }
}

// ---------------- DFT via bf16 MFMA with hi/lo split ----------------
__global__ __launch_bounds__(256) void k_dft_mfma(const unsigned short* __restrict__ fh,
                                                  const unsigned short* __restrict__ fl,
                                                  const unsigned short* __restrict__ ch,
                                                  const unsigned short* __restrict__ cl,
                                                  const unsigned short* __restrict__ sh,
                                                  const unsigned short* __restrict__ sl,
                                                  float* __restrict__ S0) {
    __shared__ __align__(16) unsigned short Ah[64 * 40];
    __shared__ __align__(16) unsigned short Al[64 * 40];
    __shared__ __align__(16) unsigned short Bch[64 * 40];
    __shared__ __align__(16) unsigned short Bcl[64 * 40];
    __shared__ __align__(16) unsigned short Bsh[64 * 40];
    __shared__ __align__(16) unsigned short Bsl[64 * 40];
    int tid = threadIdx.x;
    int N0 = blockIdx.x * 64, M0 = blockIdx.y * 64;
    int sr = tid >> 2, sc = (tid & 3) * 8;
    size_t aoff = (size_t)(M0 + sr) * 1024 + sc;
    size_t boff = (size_t)(N0 + sr) * 1024 + sc;
    int w = tid >> 6, lane = tid & 63;
    int q = lane >> 4, col = lane & 15;
    int mb = (w >> 1) * 32, nb = (w & 1) * 32;
    floatx4 aR[2][2], aI[2][2];
    #pragma unroll
    for (int mi = 0; mi < 2; mi++)
        #pragma unroll
        for (int ni = 0; ni < 2; ni++) {
            aR[mi][ni] = (floatx4){0.f, 0.f, 0.f, 0.f};
            aI[mi][ni] = (floatx4){0.f, 0.f, 0.f, 0.f};
        }

    for (int K0 = 0; K0 < 1024; K0 += 32) {
        *(short8*)&Ah[sr * 40 + sc]  = *(const short8*)(fh + aoff + K0);
        *(short8*)&Al[sr * 40 + sc]  = *(const short8*)(fl + aoff + K0);
        *(short8*)&Bch[sr * 40 + sc] = *(const short8*)(ch + boff + K0);
        *(short8*)&Bcl[sr * 40 + sc] = *(const short8*)(cl + boff + K0);
        *(short8*)&Bsh[sr * 40 + sc] = *(const short8*)(sh + boff + K0);
        *(short8*)&Bsl[sr * 40 + sc] = *(const short8*)(sl + boff + K0);
        __syncthreads();
        short8 ahv[2], alv[2], chv[2], clv[2], shv[2], slv[2];
        #pragma unroll
        for (int mi = 0; mi < 2; mi++) {
            ahv[mi] = *(const short8*)&Ah[(mb + mi * 16 + col) * 40 + q * 8];
            alv[mi] = *(const short8*)&Al[(mb + mi * 16 + col) * 40 + q * 8];
        }
        #pragma unroll
        for (int ni = 0; ni < 2; ni++) {
            chv[ni] = *(const short8*)&Bch[(nb + ni * 16 + col) * 40 + q * 8];
            clv[ni] = *(const short8*)&Bcl[(nb + ni * 16 + col) * 40 + q * 8];
            shv[ni] = *(const short8*)&Bsh[(nb + ni * 16 + col) * 40 + q * 8];
            slv[ni] = *(const short8*)&Bsl[(nb + ni * 16 + col) * 40 + q * 8];
        }
        #pragma unroll
        for (int mi = 0; mi < 2; mi++)
            #pragma unroll
            for (int ni = 0; ni < 2; ni++) {
                aR[mi][ni] = __builtin_amdgcn_mfma_f32_16x16x32_bf16(ahv[mi], chv[ni], aR[mi][ni], 0, 0, 0);
                aR[mi][ni] = __builtin_amdgcn_mfma_f32_16x16x32_bf16(ahv[mi], clv[ni], aR[mi][ni], 0, 0, 0);
                aR[mi][ni] = __builtin_amdgcn_mfma_f32_16x16x32_bf16(alv[mi], chv[ni], aR[mi][ni], 0, 0, 0);
                aI[mi][ni] = __builtin_amdgcn_mfma_f32_16x16x32_bf16(ahv[mi], shv[ni], aI[mi][ni], 0, 0, 0);
                aI[mi][ni] = __builtin_amdgcn_mfma_f32_16x16x32_bf16(ahv[mi], slv[ni], aI[mi][ni], 0, 0, 0);
                aI[mi][ni] = __builtin_amdgcn_mfma_f32_16x16x32_bf16(alv[mi], shv[ni], aI[mi][ni], 0, 0, 0);
            }
        __syncthreads();
    }
    #pragma unroll
    for (int mi = 0; mi < 2; mi++)
        #pragma unroll
        for (int ni = 0; ni < 2; ni++)
            #pragma unroll
            for (int rr = 0; rr < 4; rr++) {
                int m = M0 + mb + mi * 16 + q * 4 + rr;
                int bin = N0 + nb + ni * 16 + col;
                if (m < NROWS && bin < NBINS) {
                    float re = aR[mi][ni][rr], im = aI[mi][ni][rr];
                    int b = m / NFRAMES, i = m - b * NFRAMES;
                    S0[(b * NBINS + bin) * NFRAMES + i] =
                        logf(sqrtf(fmaf(re, re, im * im)) + 1e-9f);
                }
            }
}

// ---------------- conv1+BN+ReLU -> o1g[b][513][251][32] bf16 channels-last ----------------
__global__ __launch_bounds__(256) void k_conv1(const float* __restrict__ S0,
                                               const float* __restrict__ w1f,
                                               const float* __restrict__ b1f,
                                               unsigned short* __restrict__ o1g) {
    __shared__ float w1s[288];
    __shared__ float b1s[32];
    int tid = threadIdx.x;
    for (int i = tid; i < 288; i += 256) w1s[i] = w1f[i];
    if (tid < 32) b1s[tid] = b1f[tid];
    __syncthreads();
    int r = blockIdx.x;
    int b = blockIdx.y;
    int t = tid;
    if (t >= 251) return;
    float sv[9];
    #pragma unroll
    for (int di = 0; di < 3; di++) {
        int rr = r - 1 + di;
        #pragma unroll
        for (int dj = 0; dj < 3; dj++) {
            int tt = t - 1 + dj;
            float v = 0.f;
            if (rr >= 0 && rr < 513 && tt >= 0 && tt < 251)
                v = S0[(b * 513 + rr) * 251 + tt];
            sv[di * 3 + dj] = v;
        }
    }
    unsigned short ov[32];
    #pragma unroll
    for (int ci = 0; ci < 32; ci++) {
        float a = b1s[ci];
        const float* wp = &w1s[ci * 9];
        #pragma unroll
        for (int k = 0; k < 9; k++) a = fmaf(sv[k], wp[k], a);
        ov[ci] = f2bf(fmaxf(a, 0.f));
    }
    unsigned short* dst = o1g + ((size_t)(b * 513 + r) * 251 + t) * 32;
    #pragma unroll
    for (int i = 0; i < 4; i++)
        *(short8*)(dst + i * 8) = *(const short8*)&ov[i * 8];
}

// ---------------- conv2 (bf16 MFMA) + maxpool -> nodesb ----------------
__global__ __launch_bounds__(256) void k_conv2m(const unsigned short* __restrict__ o1g,
                                                const unsigned short* __restrict__ Bp,
                                                const float* __restrict__ b2f,
                                                unsigned short* __restrict__ nodesb) {
    __shared__ __align__(16) unsigned short o1s[18 * 18 * 32];
    __shared__ float b2s[32];
    int tid = threadIdx.x;
    int b = blockIdx.z;
    int F0 = blockIdx.y * 8;
    int T0 = blockIdx.x * 8;
    if (tid < 32) b2s[tid] = b2f[tid];
    short8 z8 = {0, 0, 0, 0, 0, 0, 0, 0};
    for (int c = tid; c < 1296; c += 256) {
        int o = c & 3, pos = c >> 2;
        int lf = pos / 18, lt = pos - lf * 18;
        int r1 = 2 * F0 - 1 + lf, t1 = 2 * T0 - 1 + lt;
        short8 v = z8;
        if (r1 >= 0 && r1 < 513 && t1 >= 0 && t1 < 251)
            v = *(const short8*)(o1g + ((size_t)(b * 513 + r1) * 251 + t1) * 32 + o * 8);
        *(short8*)&o1s[pos * 32 + o * 8] = v;
    }
    __syncthreads();

    int lane = tid & 63, w = tid >> 6;
    int q = lane >> 4, col = lane & 15;
    floatx4 acc[4][2];
    #pragma unroll
    for (int rt = 0; rt < 4; rt++)
        #pragma unroll
        for (int ct = 0; ct < 2; ct++)
            acc[rt][ct] = (floatx4){0.f, 0.f, 0.f, 0.f};

    #pragma unroll
    for (int s = 0; s < 9; s++) {
        const int di = s / 3, dj = s % 3;
        short8 bf0 = *(const short8*)&Bp[(s * 2 + 0) * 512 + lane * 8];
        short8 bf1 = *(const short8*)&Bp[(s * 2 + 1) * 512 + lane * 8];
        #pragma unroll
        for (int rt = 0; rt < 4; rt++) {
            int r = w * 4 + rt;
            short8 af = *(const short8*)&o1s[(((r + di) * 18) + (col + dj)) * 32 + q * 8];
            acc[rt][0] = __builtin_amdgcn_mfma_f32_16x16x32_bf16(af, bf0, acc[rt][0], 0, 0, 0);
            acc[rt][1] = __builtin_amdgcn_mfma_f32_16x16x32_bf16(af, bf1, acc[rt][1], 0, 0, 0);
        }
    }

    #pragma unroll
    for (int ct = 0; ct < 2; ct++) {
        int co = ct * 16 + col;
        float bb = b2s[co];
        #pragma unroll
        for (int fp2 = 0; fp2 < 2; fp2++) {
            #pragma unroll
            for (int tc2 = 0; tc2 < 2; tc2++) {
                float m0 = fmaxf(fmaxf(acc[2 * fp2][ct][2 * tc2], acc[2 * fp2][ct][2 * tc2 + 1]),
                                 fmaxf(acc[2 * fp2 + 1][ct][2 * tc2], acc[2 * fp2 + 1][ct][2 * tc2 + 1]));
                float v = fmaxf(m0 + bb, 0.f);
                int tp = T0 + 2 * q + tc2;
                if (tp < 125) {
                    int fg = F0 + 2 * w + fp2;
                    int node = 2 * tp + (co >= 16 ? 1 : 0);
                    nodesb[(size_t)(b * NNODE + node) * KPAD + 20 + (co & 15) * 256 + fg] = f2bf(v);
                }
            }
        }
    }
}

// ---------------- GAT1 GEMM (bf16 MFMA): h1 f32 + h1t bf16 [bh][f][256] ----------------
__global__ __launch_bounds__(256) void k_gat1b(const unsigned short* __restrict__ A,
                                               const unsigned short* __restrict__ Bt,
                                               float* __restrict__ C,
                                               unsigned short* __restrict__ h1t) {
    __shared__ __align__(16) unsigned short As[64 * 40];
    __shared__ __align__(16) unsigned short Bs[64 * 40];
    int tid = threadIdx.x;
    int N0 = blockIdx.x * 64, M0 = blockIdx.y * 64;
    int sr = tid >> 2, sc = (tid & 3) * 8;
    int w = tid >> 6, lane = tid & 63;
    int q = lane >> 4, col = lane & 15;
    int mb = (w >> 1) * 32, nb = (w & 1) * 32;
    floatx4 acc[2][2];
    acc[0][0] = acc[0][1] = acc[1][0] = acc[1][1] = (floatx4){0.f, 0.f, 0.f, 0.f};
    short8 z8 = {0, 0, 0, 0, 0, 0, 0, 0};
    int mA = M0 + sr;
    bool mv = mA < 2000;
    const unsigned short* pa = A + (size_t)mA * KPAD + sc;
    const unsigned short* pb = Bt + (size_t)(N0 + sr) * KPAD + sc;

    for (int K0 = 0; K0 < KPAD; K0 += 32) {
        short8 va = mv ? *(const short8*)(pa + K0) : z8;
        short8 vb = *(const short8*)(pb + K0);
        *(short8*)&As[sr * 40 + sc] = va;
        *(short8*)&Bs[sr * 40 + sc] = vb;
        __syncthreads();
        short8 a0 = *(const short8*)&As[(mb + col) * 40 + q * 8];
        short8 a1 = *(const short8*)&As[(mb + 16 + col) * 40 + q * 8];
        short8 b0 = *(const short8*)&Bs[(nb + col) * 40 + q * 8];
        short8 b1 = *(const short8*)&Bs[(nb + 16 + col) * 40 + q * 8];
        acc[0][0] = __builtin_amdgcn_mfma_f32_16x16x32_bf16(a0, b0, acc[0][0], 0, 0, 0);
        acc[0][1] = __builtin_amdgcn_mfma_f32_16x16x32_bf16(a0, b1, acc[0][1], 0, 0, 0);
        acc[1][0] = __builtin_amdgcn_mfma_f32_16x16x32_bf16(a1, b0, acc[1][0], 0, 0, 0);
        acc[1][1] = __builtin_amdgcn_mfma_f32_16x16x32_bf16(a1, b1, acc[1][1], 0, 0, 0);
        __syncthreads();
    }
    #pragma unroll
    for (int mi = 0; mi < 2; mi++)
        #pragma unroll
        for (int ni = 0; ni < 2; ni++)
            #pragma unroll
            for (int rr = 0; rr < 4; rr++) {
                int m = M0 + mb + mi * 16 + q * 4 + rr;
                if (m < 2000) {
                    int n = N0 + nb + ni * 16 + col;
                    C[m * 512 + n] = acc[mi][ni][rr];
                    int bb = m / NNODE, j = m - bb * NNODE;
                    int hh = n >> 6, f = n & 63;
                    h1t[((size_t)((bb * 8 + hh) * 64 + f)) * 256 + j] = f2bf(acc[mi][ni][rr]);
                }
            }
}

// ---------------- GAT1 scores / max ----------------
__global__ __launch_bounds__(256) void k_scores1(const float* __restrict__ h1,
                                                 const float* __restrict__ asrc,
                                                 const float* __restrict__ adst,
                                                 float* __restrict__ ssrc,
                                                 float* __restrict__ sdst) {
    int row = blockIdx.x * 4 + (threadIdx.x >> 6);
    int lane = threadIdx.x & 63;
    if (row >= 2000) return;
    for (int h = 0; h < 8; h++) {
        float v = h1[row * 512 + h * 64 + lane];
        float ps = v * asrc[h * 64 + lane];
        float pd = v * adst[h * 64 + lane];
        for (int off = 32; off > 0; off >>= 1) {
            ps += __shfl_down(ps, off);
            pd += __shfl_down(pd, off);
        }
        if (lane == 0) { ssrc[row * 8 + h] = ps; sdst[row * 8 + h] = pd; }
    }
}

__global__ __launch_bounds__(64) void k_smax1(const float* __restrict__ ssrc,
                                              float* __restrict__ smax) {
    int bh = blockIdx.x;
    int b = bh >> 3, h = bh & 7;
    int lane = threadIdx.x;
    float m = -1e30f;
    for (int n = lane; n < NNODE; n += 64) m = fmaxf(m, ssrc[(b * NNODE + n) * 8 + h]);
    for (int off = 32; off > 0; off >>= 1) m = fmaxf(m, __shfl_down(m, off));
    if (lane == 0) smax[bh] = m;
}

// ---------------- GAT1 attention weights: Pn[bh][256][256] bf16 normalized ----------------
__global__ __launch_bounds__(256) void k_attw(const float* __restrict__ ssrc,
                                              const float* __restrict__ sdst,
                                              const float* __restrict__ smax,
                                              unsigned short* __restrict__ Pn) {
    int bh = blockIdx.x;
    int b = bh >> 3, h = bh & 7;
    int tid = threadIdx.x;
    __shared__ float ss[NNODE];
    for (int j = tid; j < NNODE; j += 256) ss[j] = ssrc[(b * NNODE + j) * 8 + h];
    __syncthreads();
    unsigned short* row = Pn + ((size_t)bh * 256 + tid) * 256;
    short8 z8 = {0, 0, 0, 0, 0, 0, 0, 0};
    if (tid >= NNODE) {
        #pragma unroll
        for (int j = 0; j < 256; j += 8) *(short8*)(row + j) = z8;
        return;
    }
    float d = sdst[(b * NNODE + tid) * 8 + h];
    float e0 = d + smax[bh];
    float mx = e0 > 0.f ? e0 : 0.2f * e0;
    float den = 0.f;
    for (int j = 0; j < NNODE; j++) {
        float e = d + ss[j];
        e = e > 0.f ? e : 0.2f * e;
        den += __expf(e - mx);
    }
    float rden = 1.f / den;
    for (int j0 = 0; j0 < 256; j0 += 8) {
        unsigned short wv[8];
        #pragma unroll
        for (int jj = 0; jj < 8; jj++) {
            int j = j0 + jj;
            float wt = 0.f;
            if (j < NNODE) {
                float e = d + ss[j];
                e = e > 0.f ? e : 0.2f * e;
                wt = __expf(e - mx) * rden;
            }
            wv[jj] = f2bf(wt);
        }
        *(short8*)(row + j0) = *(const short8*)wv;
    }
}

// ---------------- GAT1 attention apply (MFMA): g1 = Pn @ h1t^T + bias, relu ----------------
__global__ __launch_bounds__(256) void k_attnv(const unsigned short* __restrict__ Pn,
                                               const unsigned short* __restrict__ h1t,
                                               const float* __restrict__ bias,
                                               float* __restrict__ g1) {
    int bh = blockIdx.x;
    int b = bh >> 3, h = bh & 7;
    int tid = threadIdx.x;
    int w = tid >> 6, lane = tid & 63;
    int q = lane >> 4, col = lane & 15;
    const unsigned short* Pb = Pn + (size_t)bh * 65536;
    const unsigned short* Hb = h1t + (size_t)bh * 16384;
    floatx4 acc[4][4];
    #pragma unroll
    for (int mi = 0; mi < 4; mi++)
        #pragma unroll
        for (int ni = 0; ni < 4; ni++)
            acc[mi][ni] = (floatx4){0.f, 0.f, 0.f, 0.f};
    for (int k0 = 0; k0 < 256; k0 += 32) {
        short8 af[4], bf[4];
        #pragma unroll
        for (int mi = 0; mi < 4; mi++)
            af[mi] = *(const short8*)(Pb + (size_t)((w * 4 + mi) * 16 + col) * 256 + k0 + q * 8);
        #pragma unroll
        for (int ni = 0; ni < 4; ni++)
            bf[ni] = *(const short8*)(Hb + (size_t)(ni * 16 + col) * 256 + k0 + q * 8);
        #pragma unroll
        for (int mi = 0; mi < 4; mi++)
            #pragma unroll
            for (int ni = 0; ni < 4; ni++)
                acc[mi][ni] = __builtin_amdgcn_mfma_f32_16x16x32_bf16(af[mi], bf[ni], acc[mi][ni], 0, 0, 0);
    }
    #pragma unroll
    for (int mi = 0; mi < 4; mi++)
        #pragma unroll
        for (int ni = 0; ni < 4; ni++)
            #pragma unroll
            for (int rr = 0; rr < 4; rr++) {
                int i = (w * 4 + mi) * 16 + q * 4 + rr;
                int f = ni * 16 + col;
                if (i < NNODE)
                    g1[(b * NNODE + i) * 512 + h * 64 + f] =
                        fmaxf(acc[mi][ni][rr] + bias[h * 64 + f], 0.f);
            }
}

// ---------------- GAT2 ----------------
__global__ __launch_bounds__(256) void k_h2(const float* __restrict__ g1,
                                            const float* __restrict__ W2,
                                            const float* __restrict__ a2src,
                                            const float* __restrict__ a2dst,
                                            float* __restrict__ h2,
                                            float* __restrict__ s2src,
                                            float* __restrict__ s2dst) {
    int row = blockIdx.x * 4 + (threadIdx.x >> 6);
    if (row >= 2000) return;
    int lane = threadIdx.x & 63;
    int o = lane & 31, half = lane >> 5;
    const float* gr = &g1[row * 512 + half * 256];
    float acc = 0.f;
    for (int k = 0; k < 256; k++) acc = fmaf(gr[k], W2[(half * 256 + k) * 32 + o], acc);
    acc += __shfl_down(acc, 32);
    float ps = acc * a2src[o], pd = acc * a2dst[o];
    for (int off = 16; off > 0; off >>= 1) {
        ps += __shfl_down(ps, off, 32);
        pd += __shfl_down(pd, off, 32);
    }
    if (lane == 0) { s2src[row] = ps; s2dst[row] = pd; }
    if (lane < 32) h2[row * 32 + o] = acc;
}

__global__ __launch_bounds__(64) void k_smax2(const float* __restrict__ s2src,
                                              float* __restrict__ smax2) {
    int b = blockIdx.x, lane = threadIdx.x;
    float m = -1e30f;
    for (int n = lane; n < NNODE; n += 64) m = fmaxf(m, s2src[b * NNODE + n]);
    for (int off = 32; off > 0; off >>= 1) m = fmaxf(m, __shfl_down(m, off));
    if (lane == 0) smax2[b] = m;
}

__global__ __launch_bounds__(256) void k_attn2(const float* __restrict__ h2,
                                               const float* __restrict__ s2src,
                                               const float* __restrict__ s2dst,
                                               const float* __restrict__ smax2,
                                               const float* __restrict__ bias2,
                                               float* __restrict__ g2) {
    int it = blockIdx.x, b = blockIdx.y;
    int tid = threadIdx.x, lane = tid & 63, wv = tid >> 6;
    __shared__ float ss[NNODE];
    for (int n = tid; n < NNODE; n += 256) ss[n] = s2src[b * NNODE + n];
    __syncthreads();
    int i = it * 4 + wv;
    if (i >= NNODE) return;
    int f = lane & 31, half = lane >> 5;
    float d = s2dst[b * NNODE + i];
    float e0 = d + smax2[b];
    float mx = e0 > 0.f ? e0 : 0.2f * e0;
    float acc = 0.f, den = 0.f;
    for (int j = half; j < NNODE; j += 2) {
        float e = d + ss[j];
        e = e > 0.f ? e : 0.2f * e;
        float w = __expf(e - mx);
        den += w;
        acc = fmaf(w, h2[(b * NNODE + j) * 32 + f], acc);
    }
    acc += __shfl_down(acc, 32);
    den += __shfl_down(den, 32);
    if (lane < 32) g2[(b * NNODE + i) * 32 + f] = acc / den + bias2[f];
}

__global__ __launch_bounds__(256) void k_emb(const float* __restrict__ g2,
                                             float* __restrict__ emb,
                                             float* __restrict__ dout) {
    int b = blockIdx.x;
    int f = threadIdx.x & 31, g = threadIdx.x >> 5;
    __shared__ float red[8][32];
    float s = 0.f;
    for (int i = g; i < NNODE; i += 8) s += g2[(b * NNODE + i) * 32 + f];
    red[g][f] = s;
    __syncthreads();
    if (threadIdx.x < 32) {
        float t = 0.f;
        #pragma unroll
        for (int gg = 0; gg < 8; gg++) t += red[gg][f];
        t *= (1.0f / 250.0f);
        emb[b * 32 + f] = t;
        dout[16 + b * 32 + f] = t;
    }
}

__global__ __launch_bounds__(256) void k_fc(const float* __restrict__ emb,
                                            const float* __restrict__ fc1w,
                                            const float* __restrict__ fc1b,
                                            const float* __restrict__ bnfg,
                                            const float* __restrict__ bnfb,
                                            const float* __restrict__ fc2w,
                                            const float* __restrict__ fc2b,
                                            float* __restrict__ dout) {
    __shared__ float es[256];
    __shared__ float zs[1024];
    int tid = threadIdx.x;
    es[tid] = emb[tid];
    __syncthreads();
    float inv = rsqrtf(1.0f + 1e-5f);
    #pragma unroll
    for (int rep = 0; rep < 4; rep++) {
        int idx = tid + rep * 256;
        int b = idx >> 7, j = idx & 127;
        float a = fc1b[j];
        #pragma unroll
        for (int k = 0; k < 32; k++) a = fmaf(es[b * 32 + k], fc1w[k * 128 + j], a);
        a = a * (bnfg[j] * inv) + bnfb[j];
        zs[idx] = fmaxf(a, 0.f);
    }
    __syncthreads();
    if (tid < 16) {
        int b = tid >> 1, o = tid & 1;
        float a = fc2b[o];
        for (int k = 0; k < 128; k++) a = fmaf(zs[b * 128 + k], fc2w[k * 2 + o], a);
        dout[b * 2 + o] = a;
    }
}

// ---------------- launch ----------------
extern "C" void kernel_launch(void* const* d_in, const int* in_sizes, int n_in,
                              void* d_out, int out_size, void* d_ws, size_t ws_size,
                              hipStream_t stream) {
    (void)in_sizes; (void)n_in; (void)out_size; (void)ws_size;
    const float* x       = (const float*)d_in[0];
    const float* sinc_w  = (const float*)d_in[1];
    const float* conv1_w = (const float*)d_in[2];
    const float* conv1_b = (const float*)d_in[3];
    const float* bn1_g   = (const float*)d_in[4];
    const float* bn1_b   = (const float*)d_in[5];
    const float* conv2_w = (const float*)d_in[6];
    const float* conv2_b = (const float*)d_in[7];
    const float* bn2_g   = (const float*)d_in[8];
    const float* bn2_b   = (const float*)d_in[9];
    const float* gat1_W  = (const float*)d_in[10];
    const float* gat1_as = (const float*)d_in[11];
    const float* gat1_ad = (const float*)d_in[12];
    const float* gat1_bi = (const float*)d_in[13];
    const float* gat2_W  = (const float*)d_in[14];
    const float* gat2_as = (const float*)d_in[15];
    const float* gat2_ad = (const float*)d_in[16];
    const float* gat2_bi = (const float*)d_in[17];
    const float* fc1_w   = (const float*)d_in[18];
    const float* fc1_b   = (const float*)d_in[19];
    const float* bnf_g   = (const float*)d_in[20];
    const float* bnf_b   = (const float*)d_in[21];
    const float* fc2_w   = (const float*)d_in[22];
    const float* fc2_b   = (const float*)d_in[23];
    float* dout = (float*)d_out;

    float* ws = (float*)d_ws;
    unsigned short* fh  = (unsigned short*)ws;                 // 2048*1024 ush
    unsigned short* fl  = fh + (size_t)MPAD * 1024;
    unsigned short* bch = fl + (size_t)MPAD * 1024;
    unsigned short* bcl = bch + (size_t)NBPAD * 1024;
    unsigned short* bsh = bcl + (size_t)NBPAD * 1024;
    unsigned short* bsl = bsh + (size_t)NBPAD * 1024;
    float* S0   = (float*)(bsl + (size_t)NBPAD * 1024);        // 1,030,104 f
    unsigned short* wbt = (unsigned short*)(S0 + 1030104);     // 32*1056 ush = 16,896 f
    float* w1f  = (float*)(wbt + 32 * 1056);
    float* b1f  = w1f + 288;
    float* w2f  = b1f + 32;
    float* b2f  = w2f + 9216;
    unsigned short* bpk = (unsigned short*)(b2f + 32);         // 9,216 ush
    unsigned short* Wt  = (unsigned short*)(b2f + 32 + 4608);  // 512*KPAD ush
    unsigned short* nodesb = Wt + (size_t)512 * KPAD;          // 2000*KPAD ush
    float* h1    = (float*)(nodesb + (size_t)2000 * KPAD);     // 1,024,000
    float* ssrc1 = h1 + 1024000;
    float* sdst1 = ssrc1 + 16000;
    float* smax1 = sdst1 + 16000;
    float* g1    = smax1 + 64;
    float* h2    = g1 + 1024000;
    float* s2src = h2 + 64000;
    float* s2dst = s2src + 2000;
    float* smax2 = s2dst + 2000;
    float* g2    = smax2 + 8;
    float* embp  = g2 + 64000;
    unsigned short* o1g = (unsigned short*)(embp + 256);       // 8*513*251*32 ush
    unsigned short* Pn  = o1g + (size_t)8 * 513 * 251 * 32;    // 64*256*256 ush
    unsigned short* h1t = Pn + (size_t)64 * 256 * 256;         // 64*64*256 ush

    hipLaunchKernelGGL(k_fold, dim3(38), dim3(256), 0, stream,
                       conv1_w, conv1_b, bn1_g, bn1_b, conv2_w, conv2_b, bn2_g, bn2_b,
                       w1f, b1f, w2f, b2f);
    hipLaunchKernelGGL(k_pack, dim3(36), dim3(256), 0, stream, w2f, bpk);
    hipLaunchKernelGGL(k_wt, dim3(65, 8), dim3(256), 0, stream, gat1_W, Wt);
    hipLaunchKernelGGL(k_wbt, dim3((32 * 1056 + 255) / 256), dim3(256), 0, stream, sinc_w, wbt);
    hipLaunchKernelGGL(k_basis_bf, dim3(NBPAD * 1024 / 256), dim3(256), 0, stream,
                       bch, bcl, bsh, bsl);
    hipLaunchKernelGGL(k_frames_bf, dim3(MPAD * 1024 / 256), dim3(256), 0, stream, x, fh, fl);
    hipLaunchKernelGGL(k_dft_mfma, dim3(9, 32), dim3(256), 0, stream,
                       fh, fl, bch, bcl, bsh, bsl, S0);
    hipLaunchKernelGGL(k_sincm, dim3(8), dim3(256), 0, stream, x, wbt, nodesb);
    hipLaunchKernelGGL(k_conv1, dim3(513, 8), dim3(256), 0, stream, S0, w1f, b1f, o1g);
    hipLaunchKernelGGL(k_conv2m, dim3(16, 32, 8), dim3(256), 0, stream, o1g, bpk, b2f, nodesb);
    hipLaunchKernelGGL(k_gat1b, dim3(8, 32), dim3(256), 0, stream, nodesb, Wt, h1, h1t);
    hipLaunchKernelGGL(k_scores1, dim3(500), dim3(256), 0, stream, h1, gat1_as, gat1_ad, ssrc1, sdst1);
    hipLaunchKernelGGL(k_smax1, dim3(64), dim3(64), 0, stream, ssrc1, smax1);
    hipLaunchKernelGGL(k_attw, dim3(64), dim3(256), 0, stream, ssrc1, sdst1, smax1, Pn);
    hipLaunchKernelGGL(k_attnv, dim3(64), dim3(256), 0, stream, Pn, h1t, gat1_bi, g1);
    hipLaunchKernelGGL(k_h2, dim3(500), dim3(256), 0, stream,
                       g1, gat2_W, gat2_as, gat2_ad, h2, s2src, s2dst);
    hipLaunchKernelGGL(k_smax2, dim3(8), dim3(64), 0, stream, s2src, smax2);
    hipLaunchKernelGGL(k_attn2, dim3(63, 8), dim3(256), 0, stream,
                       h2, s2src, s2dst, smax2, gat2_bi, g2);
    hipLaunchKernelGGL(k_emb, dim3(8), dim3(256), 0, stream, g2, embp, dout);
    hipLaunchKernelGGL(k_fc, dim3(1), dim3(256), 0, stream,
                       embp, fc1_w, fc1_b, bnf_g, bnf_b, fc2_w, fc2_b, dout);
}

// Round 9
// 420.309 us; speedup vs baseline: 2.4820x; 1.0736x over previous
//
#include <hip/hip_runtime.h>
#include <hip/hip_bf16.h>
#include <math.h>

// ---------------- constants ----------------
#define TB 8
#define TT 64000
#define NFRAMES 251
#define NROWS (TB*NFRAMES)      // 2008
#define MPAD 2048
#define NBINS 513
#define NBPAD 576
#define NNODE 250
#define NODE_DIM 4116
#define KPAD 4128

typedef __attribute__((ext_vector_type(8))) short short8;
typedef __attribute__((ext_vector_type(4))) float floatx4;

static __device__ __forceinline__ unsigned short f2bf(float x) {
    __hip_bfloat16 h = __float2bfloat16(x);
    return *(unsigned short*)&h;
}
static __device__ __forceinline__ float bf2f(unsigned short u) {
    __hip_bfloat16 h = *(__hip_bfloat16*)&u;
    return __bfloat162float(h);
}

// ---------------- small prep kernels ----------------

__global__ void k_fold(const float* __restrict__ c1w, const float* __restrict__ c1b,
                       const float* __restrict__ g1bn, const float* __restrict__ b1bn,
                       const float* __restrict__ c2w, const float* __restrict__ c2b,
                       const float* __restrict__ g2bn, const float* __restrict__ b2bn,
                       float* __restrict__ w1f, float* __restrict__ b1f,
                       float* __restrict__ w2f, float* __restrict__ b2f) {
    int idx = blockIdx.x * 256 + threadIdx.x;
    float inv = rsqrtf(1.0f + 1e-5f);
    if (idx < 9216) {
        int co = idx / 288;
        w2f[idx] = c2w[idx] * (g2bn[co] * inv);
    } else if (idx < 9216 + 288) {
        int r = idx - 9216;
        w1f[r] = c1w[r] * (g1bn[r / 9] * inv);
    } else if (idx < 9216 + 288 + 32) {
        int c = idx - 9504;
        b1f[c] = c1b[c] * (g1bn[c] * inv) + b1bn[c];
    } else if (idx < 9216 + 288 + 64) {
        int c = idx - 9536;
        b2f[c] = c2b[c] * (g2bn[c] * inv) + b2bn[c];
    }
}

// pack conv2 weights into MFMA B-fragment order, bf16.
__global__ void k_pack(const float* __restrict__ w2f, unsigned short* __restrict__ Bp) {
    int idx = blockIdx.x * 256 + threadIdx.x;
    if (idx >= 9216) return;
    int j = idx & 7, lane = (idx >> 3) & 63, ct = (idx >> 9) & 1, s = idx >> 10;
    int co = ct * 16 + (lane & 15);
    int ci = (lane >> 4) * 8 + j;
    Bp[idx] = f2bf(w2f[co * 288 + ci * 9 + s]);
}

// transpose gat1_W [4116x512] f32 -> Wt [512][KPAD] bf16 (pad rows zero)
__global__ __launch_bounds__(256) void k_wt(const float* __restrict__ W,
                                            unsigned short* __restrict__ Wt) {
    __shared__ unsigned short tile[64][65];
    int kt = blockIdx.x, nt = blockIdx.y;
    int tid = threadIdx.x;
    for (int idx = tid; idx < 4096; idx += 256) {
        int r = idx >> 6, c = idx & 63;
        int k = kt * 64 + r;
        float v = (k < NODE_DIM) ? W[k * 512 + nt * 64 + c] : 0.f;
        tile[r][c] = f2bf(v);
    }
    __syncthreads();
    for (int idx = tid; idx < 4096; idx += 256) {
        int nl = idx >> 6, kl = idx & 63;
        int k = kt * 64 + kl;
        if (k < KPAD)
            Wt[(size_t)(nt * 64 + nl) * KPAD + k] = tile[kl][nl];
    }
}

// sinc weights: 4-tap prefix-summed, transposed, padded bf16: wbt[32][1056]
__global__ void k_wbt(const float* __restrict__ sw, unsigned short* __restrict__ wbt) {
    int idx = blockIdx.x * 256 + threadIdx.x;
    if (idx >= 32 * 1056) return;
    int c = idx / 1056, m = idx - c * 1056;
    float s = 0.f;
    if (c < 20 && m < 1027) {
        #pragma unroll
        for (int d = 0; d < 4; d++) {
            int k = m - d;
            if (k >= 0 && k < 1024) s += sw[c * 1024 + k];
        }
        s *= 0.25f;
    }
    wbt[idx] = f2bf(s);
}

// DFT basis, bf16 hi/lo split; rows [NBINS..NBPAD) zero
__global__ void k_basis_bf(unsigned short* __restrict__ ch, unsigned short* __restrict__ cl,
                           unsigned short* __restrict__ sh, unsigned short* __restrict__ sl) {
    int idx = blockIdx.x * 256 + threadIdx.x;
    if (idx >= NBPAD * 1024) return;
    int k = idx >> 10, n = idx & 1023;
    float s = 0.f, c = 0.f;
    if (k < NBINS) {
        int mm = (k * n) & 1023;
        sincospif((float)mm * (1.0f / 512.0f), &s, &c);
    }
    unsigned short chv = f2bf(c), shv = f2bf(s);
    ch[idx] = chv; cl[idx] = f2bf(c - bf2f(chv));
    sh[idx] = shv; sl[idx] = f2bf(s - bf2f(shv));
}

// frames (reflect-padded) -> bf16 hi/lo, rows [NROWS..MPAD) zero
__global__ void k_frames_bf(const float* __restrict__ x,
                            unsigned short* __restrict__ fh, unsigned short* __restrict__ fl) {
    int idx = blockIdx.x * 256 + threadIdx.x;
    if (idx >= MPAD * 1024) return;
    int m = idx >> 10, n = idx & 1023;
    float v = 0.f;
    if (m < NROWS) {
        int b = m / NFRAMES, i = m - b * NFRAMES;
        int j = i * 256 + n - 512;
        if (j < 0) j = -j;
        if (j >= TT) j = 2 * TT - 2 - j;
        v = x[b * TT + j];
    }
    unsigned short h = f2bf(v);
    fh[idx] = h;
    fl[idx] = f2bf(v - bf2f(h));
}

// ---------------- sinc conv as MFMA GEMM: nodes[b][u][0..19] ----------------
__global__ __launch_bounds__(256) void k_sincm(const float* __restrict__ x,
                                               const unsigned short* __restrict__ wbt,
                                               unsigned short* __restrict__ nodesb) {
    __shared__ __align__(16) unsigned short xs[2080];
    int b = blockIdx.x;
    int tid = threadIdx.x;
    for (int i = tid; i < 2080; i += 256) {
        int g = i - 512;
        float v = (g >= 0 && g < TT) ? x[b * TT + g] : 0.f;
        xs[i] = f2bf(v);
    }
    __syncthreads();
    int w = tid >> 6, lane = tid & 63;
    int q = lane >> 4, col = lane & 15;
    floatx4 acc[4][2];
    #pragma unroll
    for (int mi = 0; mi < 4; mi++)
        #pragma unroll
        for (int ni = 0; ni < 2; ni++)
            acc[mi][ni] = (floatx4){0.f, 0.f, 0.f, 0.f};
    for (int K0 = 0; K0 < 1056; K0 += 32) {
        short8 af[4];
        #pragma unroll
        for (int mi = 0; mi < 4; mi++) {
            int u = w * 64 + mi * 16 + col;
            int off = 4 * u + K0 + q * 8;
            unsigned long long lo = *(const unsigned long long*)&xs[off];
            unsigned long long hi = *(const unsigned long long*)&xs[off + 4];
            union { unsigned long long u64[2]; short8 s8; } cv;
            cv.u64[0] = lo; cv.u64[1] = hi;
            af[mi] = cv.s8;
        }
        short8 bf[2];
        #pragma unroll
        for (int ni = 0; ni < 2; ni++) {
            int c = ni * 16 + col;
            bf[ni] = *(const short8*)(wbt + (size_t)c * 1056 + K0 + q * 8);
        }
        #pragma unroll
        for (int mi = 0; mi < 4; mi++)
            #pragma unroll
            for (int ni = 0; ni < 2; ni++)
                acc[mi][ni] = __builtin_amdgcn_mfma_f32_16x16x32_bf16(af[mi], bf[ni], acc[mi][ni], 0, 0, 0);
    }
    #pragma unroll
    for (int mi = 0; mi < 4; mi++)
        #pragma unroll
        for (int ni = 0; ni < 2; ni++)
            #pragma unroll
            for (int rr = 0; rr < 4; rr++) {
                int u = w * 64 + mi * 16 + q * 4 + rr;
                int c = ni * 16 + col;
                if (u < NNODE && c < 20)
                    nodesb[(size_t)(b * NNODE + u) * KPAD + c] = f2bf(acc[mi][ni][rr]);
            }
}

// ---------------- DFT via bf16 MFMA with hi/lo split ----------------
__global__ __launch_bounds__(256) void k_dft_mfma(const unsigned short* __restrict__ fh,
                                                  const unsigned short* __restrict__ fl,
                                                  const unsigned short* __restrict__ ch,
                                                  const unsigned short* __restrict__ cl,
                                                  const unsigned short* __restrict__ sh,
                                                  const unsigned short* __restrict__ sl,
                                                  float* __restrict__ S0) {
    __shared__ __align__(16) unsigned short Ah[64 * 40];
    __shared__ __align__(16) unsigned short Al[64 * 40];
    __shared__ __align__(16) unsigned short Bch[64 * 40];
    __shared__ __align__(16) unsigned short Bcl[64 * 40];
    __shared__ __align__(16) unsigned short Bsh[64 * 40];
    __shared__ __align__(16) unsigned short Bsl[64 * 40];
    int tid = threadIdx.x;
    int N0 = blockIdx.x * 64, M0 = blockIdx.y * 64;
    int sr = tid >> 2, sc = (tid & 3) * 8;
    size_t aoff = (size_t)(M0 + sr) * 1024 + sc;
    size_t boff = (size_t)(N0 + sr) * 1024 + sc;
    int w = tid >> 6, lane = tid & 63;
    int q = lane >> 4, col = lane & 15;
    int mb = (w >> 1) * 32, nb = (w & 1) * 32;
    floatx4 aR[2][2], aI[2][2];
    #pragma unroll
    for (int mi = 0; mi < 2; mi++)
        #pragma unroll
        for (int ni = 0; ni < 2; ni++) {
            aR[mi][ni] = (floatx4){0.f, 0.f, 0.f, 0.f};
            aI[mi][ni] = (floatx4){0.f, 0.f, 0.f, 0.f};
        }

    for (int K0 = 0; K0 < 1024; K0 += 32) {
        *(short8*)&Ah[sr * 40 + sc]  = *(const short8*)(fh + aoff + K0);
        *(short8*)&Al[sr * 40 + sc]  = *(const short8*)(fl + aoff + K0);
        *(short8*)&Bch[sr * 40 + sc] = *(const short8*)(ch + boff + K0);
        *(short8*)&Bcl[sr * 40 + sc] = *(const short8*)(cl + boff + K0);
        *(short8*)&Bsh[sr * 40 + sc] = *(const short8*)(sh + boff + K0);
        *(short8*)&Bsl[sr * 40 + sc] = *(const short8*)(sl + boff + K0);
        __syncthreads();
        short8 ahv[2], alv[2], chv[2], clv[2], shv[2], slv[2];
        #pragma unroll
        for (int mi = 0; mi < 2; mi++) {
            ahv[mi] = *(const short8*)&Ah[(mb + mi * 16 + col) * 40 + q * 8];
            alv[mi] = *(const short8*)&Al[(mb + mi * 16 + col) * 40 + q * 8];
        }
        #pragma unroll
        for (int ni = 0; ni < 2; ni++) {
            chv[ni] = *(const short8*)&Bch[(nb + ni * 16 + col) * 40 + q * 8];
            clv[ni] = *(const short8*)&Bcl[(nb + ni * 16 + col) * 40 + q * 8];
            shv[ni] = *(const short8*)&Bsh[(nb + ni * 16 + col) * 40 + q * 8];
            slv[ni] = *(const short8*)&Bsl[(nb + ni * 16 + col) * 40 + q * 8];
        }
        #pragma unroll
        for (int mi = 0; mi < 2; mi++)
            #pragma unroll
            for (int ni = 0; ni < 2; ni++) {
                aR[mi][ni] = __builtin_amdgcn_mfma_f32_16x16x32_bf16(ahv[mi], chv[ni], aR[mi][ni], 0, 0, 0);
                aR[mi][ni] = __builtin_amdgcn_mfma_f32_16x16x32_bf16(ahv[mi], clv[ni], aR[mi][ni], 0, 0, 0);
                aR[mi][ni] = __builtin_amdgcn_mfma_f32_16x16x32_bf16(alv[mi], chv[ni], aR[mi][ni], 0, 0, 0);
                aI[mi][ni] = __builtin_amdgcn_mfma_f32_16x16x32_bf16(ahv[mi], shv[ni], aI[mi][ni], 0, 0, 0);
                aI[mi][ni] = __builtin_amdgcn_mfma_f32_16x16x32_bf16(ahv[mi], slv[ni], aI[mi][ni], 0, 0, 0);
                aI[mi][ni] = __builtin_amdgcn_mfma_f32_16x16x32_bf16(alv[mi], shv[ni], aI[mi][ni], 0, 0, 0);
            }
        __syncthreads();
    }
    #pragma unroll
    for (int mi = 0; mi < 2; mi++)
        #pragma unroll
        for (int ni = 0; ni < 2; ni++)
            #pragma unroll
            for (int rr = 0; rr < 4; rr++) {
                int m = M0 + mb + mi * 16 + q * 4 + rr;
                int bin = N0 + nb + ni * 16 + col;
                if (m < NROWS && bin < NBINS) {
                    float re = aR[mi][ni][rr], im = aI[mi][ni][rr];
                    int b = m / NFRAMES, i = m - b * NFRAMES;
                    S0[(b * NBINS + bin) * NFRAMES + i] =
                        logf(sqrtf(fmaf(re, re, im * im)) + 1e-9f);
                }
            }
}

// ---------------- conv1+BN+ReLU -> o1g[b][513][251][32] bf16 channels-last ----------------
__global__ __launch_bounds__(256) void k_conv1(const float* __restrict__ S0,
                                               const float* __restrict__ w1f,
                                               const float* __restrict__ b1f,
                                               unsigned short* __restrict__ o1g) {
    __shared__ float w1s[288];
    __shared__ float b1s[32];
    int tid = threadIdx.x;
    for (int i = tid; i < 288; i += 256) w1s[i] = w1f[i];
    if (tid < 32) b1s[tid] = b1f[tid];
    __syncthreads();
    int r = blockIdx.x;
    int b = blockIdx.y;
    int t = tid;
    if (t >= 251) return;
    float sv[9];
    #pragma unroll
    for (int di = 0; di < 3; di++) {
        int rr = r - 1 + di;
        #pragma unroll
        for (int dj = 0; dj < 3; dj++) {
            int tt = t - 1 + dj;
            float v = 0.f;
            if (rr >= 0 && rr < 513 && tt >= 0 && tt < 251)
                v = S0[(b * 513 + rr) * 251 + tt];
            sv[di * 3 + dj] = v;
        }
    }
    unsigned short ov[32];
    #pragma unroll
    for (int ci = 0; ci < 32; ci++) {
        float a = b1s[ci];
        const float* wp = &w1s[ci * 9];
        #pragma unroll
        for (int k = 0; k < 9; k++) a = fmaf(sv[k], wp[k], a);
        ov[ci] = f2bf(fmaxf(a, 0.f));
    }
    unsigned short* dst = o1g + ((size_t)(b * 513 + r) * 251 + t) * 32;
    #pragma unroll
    for (int i = 0; i < 4; i++)
        *(short8*)(dst + i * 8) = *(const short8*)&ov[i * 8];
}

// ---------------- conv2 (bf16 MFMA) + maxpool -> nodesb ----------------
__global__ __launch_bounds__(256) void k_conv2m(const unsigned short* __restrict__ o1g,
                                                const unsigned short* __restrict__ Bp,
                                                const float* __restrict__ b2f,
                                                unsigned short* __restrict__ nodesb) {
    __shared__ __align__(16) unsigned short o1s[18 * 18 * 32];
    __shared__ float b2s[32];
    int tid = threadIdx.x;
    int b = blockIdx.z;
    int F0 = blockIdx.y * 8;
    int T0 = blockIdx.x * 8;
    if (tid < 32) b2s[tid] = b2f[tid];
    short8 z8 = {0, 0, 0, 0, 0, 0, 0, 0};
    for (int c = tid; c < 1296; c += 256) {
        int o = c & 3, pos = c >> 2;
        int lf = pos / 18, lt = pos - lf * 18;
        int r1 = 2 * F0 - 1 + lf, t1 = 2 * T0 - 1 + lt;
        short8 v = z8;
        if (r1 >= 0 && r1 < 513 && t1 >= 0 && t1 < 251)
            v = *(const short8*)(o1g + ((size_t)(b * 513 + r1) * 251 + t1) * 32 + o * 8);
        *(short8*)&o1s[pos * 32 + o * 8] = v;
    }
    __syncthreads();

    int lane = tid & 63, w = tid >> 6;
    int q = lane >> 4, col = lane & 15;
    floatx4 acc[4][2];
    #pragma unroll
    for (int rt = 0; rt < 4; rt++)
        #pragma unroll
        for (int ct = 0; ct < 2; ct++)
            acc[rt][ct] = (floatx4){0.f, 0.f, 0.f, 0.f};

    #pragma unroll
    for (int s = 0; s < 9; s++) {
        const int di = s / 3, dj = s % 3;
        short8 bf0 = *(const short8*)&Bp[(s * 2 + 0) * 512 + lane * 8];
        short8 bf1 = *(const short8*)&Bp[(s * 2 + 1) * 512 + lane * 8];
        #pragma unroll
        for (int rt = 0; rt < 4; rt++) {
            int r = w * 4 + rt;
            short8 af = *(const short8*)&o1s[(((r + di) * 18) + (col + dj)) * 32 + q * 8];
            acc[rt][0] = __builtin_amdgcn_mfma_f32_16x16x32_bf16(af, bf0, acc[rt][0], 0, 0, 0);
            acc[rt][1] = __builtin_amdgcn_mfma_f32_16x16x32_bf16(af, bf1, acc[rt][1], 0, 0, 0);
        }
    }

    #pragma unroll
    for (int ct = 0; ct < 2; ct++) {
        int co = ct * 16 + col;
        float bb = b2s[co];
        #pragma unroll
        for (int fp2 = 0; fp2 < 2; fp2++) {
            #pragma unroll
            for (int tc2 = 0; tc2 < 2; tc2++) {
                float m0 = fmaxf(fmaxf(acc[2 * fp2][ct][2 * tc2], acc[2 * fp2][ct][2 * tc2 + 1]),
                                 fmaxf(acc[2 * fp2 + 1][ct][2 * tc2], acc[2 * fp2 + 1][ct][2 * tc2 + 1]));
                float v = fmaxf(m0 + bb, 0.f);
                int tp = T0 + 2 * q + tc2;
                if (tp < 125) {
                    int fg = F0 + 2 * w + fp2;
                    int node = 2 * tp + (co >= 16 ? 1 : 0);
                    nodesb[(size_t)(b * NNODE + node) * KPAD + 20 + (co & 15) * 256 + fg] = f2bf(v);
                }
            }
        }
    }
}

// ---------------- GAT1 GEMM split-K (bf16 MFMA): hpart[kc][2000][512] ----------------
__global__ __launch_bounds__(256) void k_gat1s(const unsigned short* __restrict__ A,
                                               const unsigned short* __restrict__ Bt,
                                               float* __restrict__ hpart) {
    __shared__ __align__(16) unsigned short As[64 * 40];
    __shared__ __align__(16) unsigned short Bs[64 * 40];
    int tid = threadIdx.x;
    int N0 = blockIdx.x * 64, M0 = blockIdx.y * 64;
    int kc = blockIdx.z;
    int ks = (kc == 0) ? 0 : (33 + 32 * (kc - 1));   // in 32-steps
    int ke = 33 + 32 * kc;
    if (kc == 0) ke = 33;
    int sr = tid >> 2, sc = (tid & 3) * 8;
    int w = tid >> 6, lane = tid & 63;
    int q = lane >> 4, col = lane & 15;
    int mb = (w >> 1) * 32, nb = (w & 1) * 32;
    floatx4 acc[2][2];
    acc[0][0] = acc[0][1] = acc[1][0] = acc[1][1] = (floatx4){0.f, 0.f, 0.f, 0.f};
    short8 z8 = {0, 0, 0, 0, 0, 0, 0, 0};
    int mA = M0 + sr;
    bool mv = mA < 2000;
    const unsigned short* pa = A + (size_t)mA * KPAD + sc;
    const unsigned short* pb = Bt + (size_t)(N0 + sr) * KPAD + sc;

    for (int kk = ks; kk < ke; kk++) {
        int K0 = kk * 32;
        short8 va = mv ? *(const short8*)(pa + K0) : z8;
        short8 vb = *(const short8*)(pb + K0);
        *(short8*)&As[sr * 40 + sc] = va;
        *(short8*)&Bs[sr * 40 + sc] = vb;
        __syncthreads();
        short8 a0 = *(const short8*)&As[(mb + col) * 40 + q * 8];
        short8 a1 = *(const short8*)&As[(mb + 16 + col) * 40 + q * 8];
        short8 b0 = *(const short8*)&Bs[(nb + col) * 40 + q * 8];
        short8 b1 = *(const short8*)&Bs[(nb + 16 + col) * 40 + q * 8];
        acc[0][0] = __builtin_amdgcn_mfma_f32_16x16x32_bf16(a0, b0, acc[0][0], 0, 0, 0);
        acc[0][1] = __builtin_amdgcn_mfma_f32_16x16x32_bf16(a0, b1, acc[0][1], 0, 0, 0);
        acc[1][0] = __builtin_amdgcn_mfma_f32_16x16x32_bf16(a1, b0, acc[1][0], 0, 0, 0);
        acc[1][1] = __builtin_amdgcn_mfma_f32_16x16x32_bf16(a1, b1, acc[1][1], 0, 0, 0);
        __syncthreads();
    }
    float* out = hpart + (size_t)kc * 1024000;
    #pragma unroll
    for (int mi = 0; mi < 2; mi++)
        #pragma unroll
        for (int ni = 0; ni < 2; ni++)
            #pragma unroll
            for (int rr = 0; rr < 4; rr++) {
                int m = M0 + mb + mi * 16 + q * 4 + rr;
                if (m < 2000)
                    out[m * 512 + N0 + nb + ni * 16 + col] = acc[mi][ni][rr];
            }
}

// reduce 4 partials -> h1 f32 + h1t bf16 [bh][f][256]
__global__ __launch_bounds__(256) void k_hred(const float* __restrict__ hpart,
                                              float* __restrict__ h1,
                                              unsigned short* __restrict__ h1t) {
    int idx = blockIdx.x * 256 + threadIdx.x;
    if (idx >= 1024000) return;
    float s = hpart[idx] + hpart[idx + 1024000] + hpart[idx + 2048000] + hpart[idx + 3072000];
    h1[idx] = s;
    int m = idx >> 9, n = idx & 511;
    int bb = m / NNODE, j = m - bb * NNODE;
    int hh = n >> 6, f = n & 63;
    h1t[((size_t)((bb * 8 + hh) * 64 + f)) * 256 + j] = f2bf(s);
}

// ---------------- GAT1 scores / max ----------------
__global__ __launch_bounds__(256) void k_scores1(const float* __restrict__ h1,
                                                 const float* __restrict__ asrc,
                                                 const float* __restrict__ adst,
                                                 float* __restrict__ ssrc,
                                                 float* __restrict__ sdst) {
    int row = blockIdx.x * 4 + (threadIdx.x >> 6);
    int lane = threadIdx.x & 63;
    if (row >= 2000) return;
    for (int h = 0; h < 8; h++) {
        float v = h1[row * 512 + h * 64 + lane];
        float ps = v * asrc[h * 64 + lane];
        float pd = v * adst[h * 64 + lane];
        for (int off = 32; off > 0; off >>= 1) {
            ps += __shfl_down(ps, off);
            pd += __shfl_down(pd, off);
        }
        if (lane == 0) { ssrc[row * 8 + h] = ps; sdst[row * 8 + h] = pd; }
    }
}

__global__ __launch_bounds__(64) void k_smax1(const float* __restrict__ ssrc,
                                              float* __restrict__ smax) {
    int bh = blockIdx.x;
    int b = bh >> 3, h = bh & 7;
    int lane = threadIdx.x;
    float m = -1e30f;
    for (int n = lane; n < NNODE; n += 64) m = fmaxf(m, ssrc[(b * NNODE + n) * 8 + h]);
    for (int off = 32; off > 0; off >>= 1) m = fmaxf(m, __shfl_down(m, off));
    if (lane == 0) smax[bh] = m;
}

// ---------------- GAT1 attention weights: Pn[bh][256][256] bf16 normalized ----------------
__global__ __launch_bounds__(256) void k_attw(const float* __restrict__ ssrc,
                                              const float* __restrict__ sdst,
                                              const float* __restrict__ smax,
                                              unsigned short* __restrict__ Pn) {
    int bh = blockIdx.x;
    int b = bh >> 3, h = bh & 7;
    int tid = threadIdx.x;
    __shared__ float ss[NNODE];
    for (int j = tid; j < NNODE; j += 256) ss[j] = ssrc[(b * NNODE + j) * 8 + h];
    __syncthreads();
    unsigned short* row = Pn + ((size_t)bh * 256 + tid) * 256;
    short8 z8 = {0, 0, 0, 0, 0, 0, 0, 0};
    if (tid >= NNODE) {
        #pragma unroll
        for (int j = 0; j < 256; j += 8) *(short8*)(row + j) = z8;
        return;
    }
    float d = sdst[(b * NNODE + tid) * 8 + h];
    float e0 = d + smax[bh];
    float mx = e0 > 0.f ? e0 : 0.2f * e0;
    float den = 0.f;
    for (int j = 0; j < NNODE; j++) {
        float e = d + ss[j];
        e = e > 0.f ? e : 0.2f * e;
        den += __expf(e - mx);
    }
    float rden = 1.f / den;
    for (int j0 = 0; j0 < 256; j0 += 8) {
        unsigned short wv[8];
        #pragma unroll
        for (int jj = 0; jj < 8; jj++) {
            int j = j0 + jj;
            float wt = 0.f;
            if (j < NNODE) {
                float e = d + ss[j];
                e = e > 0.f ? e : 0.2f * e;
                wt = __expf(e - mx) * rden;
            }
            wv[jj] = f2bf(wt);
        }
        *(short8*)(row + j0) = *(const short8*)wv;
    }
}

// ---------------- GAT1 attention apply (MFMA): g1 = Pn @ h1t^T + bias, relu ----------------
__global__ __launch_bounds__(256) void k_attnv(const unsigned short* __restrict__ Pn,
                                               const unsigned short* __restrict__ h1t,
                                               const float* __restrict__ bias,
                                               float* __restrict__ g1) {
    int bh = blockIdx.x;
    int b = bh >> 3, h = bh & 7;
    int tid = threadIdx.x;
    int w = tid >> 6, lane = tid & 63;
    int q = lane >> 4, col = lane & 15;
    const unsigned short* Pb = Pn + (size_t)bh * 65536;
    const unsigned short* Hb = h1t + (size_t)bh * 16384;
    floatx4 acc[4][4];
    #pragma unroll
    for (int mi = 0; mi < 4; mi++)
        #pragma unroll
        for (int ni = 0; ni < 4; ni++)
            acc[mi][ni] = (floatx4){0.f, 0.f, 0.f, 0.f};
    for (int k0 = 0; k0 < 256; k0 += 32) {
        short8 af[4], bf[4];
        #pragma unroll
        for (int mi = 0; mi < 4; mi++)
            af[mi] = *(const short8*)(Pb + (size_t)((w * 4 + mi) * 16 + col) * 256 + k0 + q * 8);
        #pragma unroll
        for (int ni = 0; ni < 4; ni++)
            bf[ni] = *(const short8*)(Hb + (size_t)(ni * 16 + col) * 256 + k0 + q * 8);
        #pragma unroll
        for (int mi = 0; mi < 4; mi++)
            #pragma unroll
            for (int ni = 0; ni < 4; ni++)
                acc[mi][ni] = __builtin_amdgcn_mfma_f32_16x16x32_bf16(af[mi], bf[ni], acc[mi][ni], 0, 0, 0);
    }
    #pragma unroll
    for (int mi = 0; mi < 4; mi++)
        #pragma unroll
        for (int ni = 0; ni < 4; ni++)
            #pragma unroll
            for (int rr = 0; rr < 4; rr++) {
                int i = (w * 4 + mi) * 16 + q * 4 + rr;
                int f = ni * 16 + col;
                if (i < NNODE)
                    g1[(b * NNODE + i) * 512 + h * 64 + f] =
                        fmaxf(acc[mi][ni][rr] + bias[h * 64 + f], 0.f);
            }
}

// ---------------- GAT2 ----------------
__global__ __launch_bounds__(256) void k_h2(const float* __restrict__ g1,
                                            const float* __restrict__ W2,
                                            const float* __restrict__ a2src,
                                            const float* __restrict__ a2dst,
                                            float* __restrict__ h2,
                                            float* __restrict__ s2src,
                                            float* __restrict__ s2dst) {
    int row = blockIdx.x * 4 + (threadIdx.x >> 6);
    if (row >= 2000) return;
    int lane = threadIdx.x & 63;
    int o = lane & 31, half = lane >> 5;
    const float* gr = &g1[row * 512 + half * 256];
    float acc = 0.f;
    for (int k = 0; k < 256; k++) acc = fmaf(gr[k], W2[(half * 256 + k) * 32 + o], acc);
    acc += __shfl_down(acc, 32);
    float ps = acc * a2src[o], pd = acc * a2dst[o];
    for (int off = 16; off > 0; off >>= 1) {
        ps += __shfl_down(ps, off, 32);
        pd += __shfl_down(pd, off, 32);
    }
    if (lane == 0) { s2src[row] = ps; s2dst[row] = pd; }
    if (lane < 32) h2[row * 32 + o] = acc;
}

__global__ __launch_bounds__(64) void k_smax2(const float* __restrict__ s2src,
                                              float* __restrict__ smax2) {
    int b = blockIdx.x, lane = threadIdx.x;
    float m = -1e30f;
    for (int n = lane; n < NNODE; n += 64) m = fmaxf(m, s2src[b * NNODE + n]);
    for (int off = 32; off > 0; off >>= 1) m = fmaxf(m, __shfl_down(m, off));
    if (lane == 0) smax2[b] = m;
}

__global__ __launch_bounds__(256) void k_attn2(const float* __restrict__ h2,
                                               const float* __restrict__ s2src,
                                               const float* __restrict__ s2dst,
                                               const float* __restrict__ smax2,
                                               const float* __restrict__ bias2,
                                               float* __restrict__ g2) {
    int it = blockIdx.x, b = blockIdx.y;
    int tid = threadIdx.x, lane = tid & 63, wv = tid >> 6;
    __shared__ float ss[NNODE];
    for (int n = tid; n < NNODE; n += 256) ss[n] = s2src[b * NNODE + n];
    __syncthreads();
    int i = it * 4 + wv;
    if (i >= NNODE) return;
    int f = lane & 31, half = lane >> 5;
    float d = s2dst[b * NNODE + i];
    float e0 = d + smax2[b];
    float mx = e0 > 0.f ? e0 : 0.2f * e0;
    float acc = 0.f, den = 0.f;
    for (int j = half; j < NNODE; j += 2) {
        float e = d + ss[j];
        e = e > 0.f ? e : 0.2f * e;
        float w = __expf(e - mx);
        den += w;
        acc = fmaf(w, h2[(b * NNODE + j) * 32 + f], acc);
    }
    acc += __shfl_down(acc, 32);
    den += __shfl_down(den, 32);
    if (lane < 32) g2[(b * NNODE + i) * 32 + f] = acc / den + bias2[f];
}

__global__ __launch_bounds__(256) void k_emb(const float* __restrict__ g2,
                                             float* __restrict__ emb,
                                             float* __restrict__ dout) {
    int b = blockIdx.x;
    int f = threadIdx.x & 31, g = threadIdx.x >> 5;
    __shared__ float red[8][32];
    float s = 0.f;
    for (int i = g; i < NNODE; i += 8) s += g2[(b * NNODE + i) * 32 + f];
    red[g][f] = s;
    __syncthreads();
    if (threadIdx.x < 32) {
        float t = 0.f;
        #pragma unroll
        for (int gg = 0; gg < 8; gg++) t += red[gg][f];
        t *= (1.0f / 250.0f);
        emb[b * 32 + f] = t;
        dout[16 + b * 32 + f] = t;
    }
}

__global__ __launch_bounds__(256) void k_fc(const float* __restrict__ emb,
                                            const float* __restrict__ fc1w,
                                            const float* __restrict__ fc1b,
                                            const float* __restrict__ bnfg,
                                            const float* __restrict__ bnfb,
                                            const float* __restrict__ fc2w,
                                            const float* __restrict__ fc2b,
                                            float* __restrict__ dout) {
    __shared__ float es[256];
    __shared__ float zs[1024];
    int tid = threadIdx.x;
    es[tid] = emb[tid];
    __syncthreads();
    float inv = rsqrtf(1.0f + 1e-5f);
    #pragma unroll
    for (int rep = 0; rep < 4; rep++) {
        int idx = tid + rep * 256;
        int b = idx >> 7, j = idx & 127;
        float a = fc1b[j];
        #pragma unroll
        for (int k = 0; k < 32; k++) a = fmaf(es[b * 32 + k], fc1w[k * 128 + j], a);
        a = a * (bnfg[j] * inv) + bnfb[j];
        zs[idx] = fmaxf(a, 0.f);
    }
    __syncthreads();
    if (tid < 16) {
        int b = tid >> 1, o = tid & 1;
        float a = fc2b[o];
        for (int k = 0; k < 128; k++) a = fmaf(zs[b * 128 + k], fc2w[k * 2 + o], a);
        dout[b * 2 + o] = a;
    }
}

// ---------------- launch ----------------
extern "C" void kernel_launch(void* const* d_in, const int* in_sizes, int n_in,
                              void* d_out, int out_size, void* d_ws, size_t ws_size,
                              hipStream_t stream) {
    (void)in_sizes; (void)n_in; (void)out_size; (void)ws_size;
    const float* x       = (const float*)d_in[0];
    const float* sinc_w  = (const float*)d_in[1];
    const float* conv1_w = (const float*)d_in[2];
    const float* conv1_b = (const float*)d_in[3];
    const float* bn1_g   = (const float*)d_in[4];
    const float* bn1_b   = (const float*)d_in[5];
    const float* conv2_w = (const float*)d_in[6];
    const float* conv2_b = (const float*)d_in[7];
    const float* bn2_g   = (const float*)d_in[8];
    const float* bn2_b   = (const float*)d_in[9];
    const float* gat1_W  = (const float*)d_in[10];
    const float* gat1_as = (const float*)d_in[11];
    const float* gat1_ad = (const float*)d_in[12];
    const float* gat1_bi = (const float*)d_in[13];
    const float* gat2_W  = (const float*)d_in[14];
    const float* gat2_as = (const float*)d_in[15];
    const float* gat2_ad = (const float*)d_in[16];
    const float* gat2_bi = (const float*)d_in[17];
    const float* fc1_w   = (const float*)d_in[18];
    const float* fc1_b   = (const float*)d_in[19];
    const float* bnf_g   = (const float*)d_in[20];
    const float* bnf_b   = (const float*)d_in[21];
    const float* fc2_w   = (const float*)d_in[22];
    const float* fc2_b   = (const float*)d_in[23];
    float* dout = (float*)d_out;

    float* ws = (float*)d_ws;
    unsigned short* fh  = (unsigned short*)ws;                 // 2048*1024 ush
    unsigned short* fl  = fh + (size_t)MPAD * 1024;
    unsigned short* bch = fl + (size_t)MPAD * 1024;
    unsigned short* bcl = bch + (size_t)NBPAD * 1024;
    unsigned short* bsh = bcl + (size_t)NBPAD * 1024;
    unsigned short* bsl = bsh + (size_t)NBPAD * 1024;
    float* S0   = (float*)(bsl + (size_t)NBPAD * 1024);        // 1,030,104 f
    unsigned short* wbt = (unsigned short*)(S0 + 1030104);     // 32*1056 ush
    float* w1f  = (float*)(wbt + 32 * 1056);
    float* b1f  = w1f + 288;
    float* w2f  = b1f + 32;
    float* b2f  = w2f + 9216;
    unsigned short* bpk = (unsigned short*)(b2f + 32);         // 9,216 ush
    unsigned short* Wt  = (unsigned short*)(b2f + 32 + 4608);  // 512*KPAD ush
    unsigned short* nodesb = Wt + (size_t)512 * KPAD;          // 2000*KPAD ush
    float* h1    = (float*)(nodesb + (size_t)2000 * KPAD);     // 1,024,000
    float* ssrc1 = h1 + 1024000;
    float* sdst1 = ssrc1 + 16000;
    float* smax1 = sdst1 + 16000;
    float* g1    = smax1 + 64;
    float* h2    = g1 + 1024000;
    float* s2src = h2 + 64000;
    float* s2dst = s2src + 2000;
    float* smax2 = s2dst + 2000;
    float* g2    = smax2 + 8;
    float* embp  = g2 + 64000;
    unsigned short* o1g = (unsigned short*)(embp + 256);       // 8*513*251*32 ush
    unsigned short* Pn  = o1g + (size_t)8 * 513 * 251 * 32;    // 64*256*256 ush
    unsigned short* h1t = Pn + (size_t)64 * 256 * 256;         // 64*64*256 ush
    float* hpart = (float*)(h1t + (size_t)64 * 64 * 256);      // 4*1,024,000 f

    hipLaunchKernelGGL(k_fold, dim3(38), dim3(256), 0, stream,
                       conv1_w, conv1_b, bn1_g, bn1_b, conv2_w, conv2_b, bn2_g, bn2_b,
                       w1f, b1f, w2f, b2f);
    hipLaunchKernelGGL(k_pack, dim3(36), dim3(256), 0, stream, w2f, bpk);
    hipLaunchKernelGGL(k_wt, dim3(65, 8), dim3(256), 0, stream, gat1_W, Wt);
    hipLaunchKernelGGL(k_wbt, dim3((32 * 1056 + 255) / 256), dim3(256), 0, stream, sinc_w, wbt);
    hipLaunchKernelGGL(k_basis_bf, dim3(NBPAD * 1024 / 256), dim3(256), 0, stream,
                       bch, bcl, bsh, bsl);
    hipLaunchKernelGGL(k_frames_bf, dim3(MPAD * 1024 / 256), dim3(256), 0, stream, x, fh, fl);
    hipLaunchKernelGGL(k_dft_mfma, dim3(9, 32), dim3(256), 0, stream,
                       fh, fl, bch, bcl, bsh, bsl, S0);
    hipLaunchKernelGGL(k_sincm, dim3(8), dim3(256), 0, stream, x, wbt, nodesb);
    hipLaunchKernelGGL(k_conv1, dim3(513, 8), dim3(256), 0, stream, S0, w1f, b1f, o1g);
    hipLaunchKernelGGL(k_conv2m, dim3(16, 32, 8), dim3(256), 0, stream, o1g, bpk, b2f, nodesb);
    hipLaunchKernelGGL(k_gat1s, dim3(8, 32, 4), dim3(256), 0, stream, nodesb, Wt, hpart);
    hipLaunchKernelGGL(k_hred, dim3(4000), dim3(256), 0, stream, hpart, h1, h1t);
    hipLaunchKernelGGL(k_scores1, dim3(500), dim3(256), 0, stream, h1, gat1_as, gat1_ad, ssrc1, sdst1);
    hipLaunchKernelGGL(k_smax1, dim3(64), dim3(64), 0, stream, ssrc1, smax1);
    hipLaunchKernelGGL(k_attw, dim3(64), dim3(256), 0, stream, ssrc1, sdst1, smax1, Pn);
    hipLaunchKernelGGL(k_attnv, dim3(64), dim3(256), 0, stream, Pn, h1t, gat1_bi, g1);
    hipLaunchKernelGGL(k_h2, dim3(500), dim3(256), 0, stream,
                       g1, gat2_W, gat2_as, gat2_ad, h2, s2src, s2dst);
    hipLaunchKernelGGL(k_smax2, dim3(8), dim3(64), 0, stream, s2src, smax2);
    hipLaunchKernelGGL(k_attn2, dim3(63, 8), dim3(256), 0, stream,
                       h2, s2src, s2dst, smax2, gat2_bi, g2);
    hipLaunchKernelGGL(k_emb, dim3(8), dim3(256), 0, stream, g2, embp, dout);
    hipLaunchKernelGGL(k_fc, dim3(1), dim3(256), 0, stream,
                       embp, fc1_w, fc1_b, bnf_g, bnf_b, fc2_w, fc2_b, dout);
}